// Round 2
// baseline (766.459 us; speedup 1.0000x reference)
//
#include <hip/hip_runtime.h>
#include <math.h>

#define N_NODES 20000
#define FCH 64
#define ZSP 10
#define E_EDGES 320000
#define RDIM 8
#define EPSC 0.25f
#define SQRT3C 1.7320508075688772f
#define INV_SQRT3C 0.57735026918962576f
#define INV_F 0.125f  /* 1/sqrt(64) */

// ---- workspace layout (float offsets) ----
#define OFF_HSUP   0                               // (N,64)
#define OFF_HVUP   (N_NODES*64)                    // (N,3,64)
#define OFF_SKS    (OFF_HVUP + N_NODES*192)        // (N,64)
#define OFF_SKV    (OFF_SKS + N_NODES*64)          // (N,3,64)
#define OFF_HSMID  (OFF_SKV + N_NODES*192)         // (N,64)   atomic
#define OFF_HVMID  (OFF_HSMID + N_NODES*64)        // (N,3,64) atomic
#define OFF_WSCP   (OFF_HVMID + N_NODES*192)       // (Z,9,64)

__device__ __forceinline__ float silu_f(float x) {
    return x / (1.0f + expf(-x));
}

__device__ __forceinline__ int species_of(int n, const int* counts) {
    int acc = 0, s = ZSP - 1;
#pragma unroll
    for (int z = 0; z < ZSP; z++) {
        int c = counts[z];
        if (n >= acc && n < acc + c) s = z;
        acc += c;
    }
    return s;
}

// K0: wscp[z][b][u] = sum_p Wsc[z][p][u] * Proj[p][b]
__global__ void k_wscproj(const float* __restrict__ Wsc, const float* __restrict__ Proj,
                          float* __restrict__ wscp) {
    int z = blockIdx.x, t = threadIdx.x;
    if (t < 9 * 64) {
        int b = t >> 6, u = t & 63;
        float acc = 0.f;
#pragma unroll
        for (int p = 0; p < 9; p++) acc += Wsc[z * 576 + p * 64 + u] * Proj[p * 9 + b];
        wscp[z * 576 + b * 64 + u] = acc;
    }
}

// K1: per-node linear_up + species skip. 8 nodes per 256-thread block.
__global__ __launch_bounds__(256) void k_node_pre(
    const float* __restrict__ ns, const float* __restrict__ nv,
    const int* __restrict__ counts,
    const float* __restrict__ Wup0, const float* __restrict__ Wup1,
    const float* __restrict__ Ws0, const float* __restrict__ Ws1,
    float* __restrict__ ws) {
    __shared__ float xs[8][64];
    __shared__ float xv[8][3][64];
    __shared__ int sid[8];
    int n0 = blockIdx.x * 8, tid = threadIdx.x;
    for (int idx = tid; idx < 8 * 64; idx += 256) {
        int n = idx >> 6, f = idx & 63;
        xs[n][f] = ns[(n0 + n) * 64 + f];
    }
    for (int idx = tid; idx < 8 * 192; idx += 256) {
        int n = idx / 192, rem = idx % 192;
        int i = rem >> 6, f = rem & 63;
        xv[n][i][f] = nv[(n0 + n) * 192 + f * 3 + i];
    }
    if (tid < 8) sid[tid] = species_of(n0 + tid, counts);
    __syncthreads();
    int g = tid & 63, r = tid >> 6;
    float* hs_up = ws + OFF_HSUP;
    float* hv_up = ws + OFF_HVUP;
    float* sks   = ws + OFF_SKS;
    float* skv   = ws + OFF_SKV;
    for (int o = 0; o < 8; o++) {
        for (int half = 0; half < 2; half++) {
            int n = r + half * 4;
            const float* x;
            const float* W;
            if (o == 0)      { x = xs[n];        W = Wup0; }
            else if (o < 4)  { x = xv[n][o - 1]; W = Wup1; }
            else if (o == 4) { x = xs[n];        W = Ws0 + sid[n] * 4096; }
            else             { x = xv[n][o - 5]; W = Ws1 + sid[n] * 4096; }
            float acc = 0.f;
#pragma unroll 8
            for (int f = 0; f < 64; f++) acc += x[f] * W[f * 64 + g];
            acc *= INV_F;
            int gn = n0 + n;
            if (o == 0)      hs_up[gn * 64 + g] = acc;
            else if (o < 4)  hv_up[gn * 192 + (o - 1) * 64 + g] = acc;
            else if (o == 4) sks[gn * 64 + g] = acc;
            else             skv[gn * 192 + (o - 5) * 64 + g] = acc;
        }
    }
}

// K2: fused radial MLP + tensor product + atomic scatter.
// 256 threads = 4 waves; each wave processes groups of 8 edges (lane = channel f).
// R1..R3 in LDS; R4 streamed from L2. Per-wave LDS activation buffer; no barriers
// needed in the loop (wave-private buffer, single instruction stream per wave).
__global__ __launch_bounds__(256) void k_edge(
    const float* __restrict__ vectors, const float* __restrict__ radial,
    const int* __restrict__ senders, const int* __restrict__ receivers,
    const float* __restrict__ R1, const float* __restrict__ R2,
    const float* __restrict__ R3, const float* __restrict__ R4,
    float* __restrict__ ws) {
    __shared__ __align__(16) float wR1[RDIM * 64];
    __shared__ __align__(16) float wR2[64 * 64];
    __shared__ __align__(16) float wR3[64 * 64];
    __shared__ __align__(16) float abuf[4][512];  // [wave][f*8+e]
    int tid = threadIdx.x;
    for (int i = tid; i < RDIM * 64; i += 256) wR1[i] = R1[i];
    for (int i = tid; i < 4096; i += 256) wR2[i] = R2[i];
    for (int i = tid; i < 4096; i += 256) wR3[i] = R3[i];
    __syncthreads();
    int w = tid >> 6, f = tid & 63;
    const float* hs_up = ws + OFF_HSUP;
    const float* hv_up = ws + OFF_HVUP;
    float* hs_mid = ws + OFF_HSMID;
    float* hv_mid = ws + OFF_HVMID;

    // total groups = E/8 = 40000 ; per block-iter = 4 waves -> 4 groups
    // grid = 625 blocks, 16 iterations each: 625*16*4*8 = 320000 edges exactly.
    for (int it = 0; it < 16; it++) {
        int group = (it * 625 + blockIdx.x) * 4 + w;
        int ebase = group * 8;

        float y1[8][3], es[8], ev[8][3], a1[8];
        int sx[8], rx[8];
#pragma unroll
        for (int j = 0; j < 8; j++) {
            int e = ebase + j;
            sx[j] = senders[e];
            rx[j] = receivers[e];
            float v0 = vectors[e * 3 + 0], v1 = vectors[e * 3 + 1], v2 = vectors[e * 3 + 2];
            float s = SQRT3C / sqrtf(v0 * v0 + v1 * v1 + v2 * v2);
            y1[j][0] = v0 * s; y1[j][1] = v1 * s; y1[j][2] = v2 * s;
        }
        // prefetch gathers (latency hidden behind MLP)
#pragma unroll
        for (int j = 0; j < 8; j++) {
            es[j]    = hs_up[sx[j] * 64 + f];
            ev[j][0] = hv_up[sx[j] * 192 + f];
            ev[j][1] = hv_up[sx[j] * 192 + 64 + f];
            ev[j][2] = hv_up[sx[j] * 192 + 128 + f];
        }
        // layer 1 (RDIM -> 64)
#pragma unroll
        for (int j = 0; j < 8; j++) {
            int e = ebase + j;
            float acc = 0.f;
#pragma unroll
            for (int k = 0; k < RDIM; k++) acc += radial[e * RDIM + k] * wR1[k * 64 + f];
            a1[j] = silu_f(acc);
        }
        float4* ab = (float4*)&abuf[w][f * 8];
        ab[0] = make_float4(a1[0], a1[1], a1[2], a1[3]);
        ab[1] = make_float4(a1[4], a1[5], a1[6], a1[7]);

        // layer 2
        float acc2[8];
#pragma unroll
        for (int j = 0; j < 8; j++) acc2[j] = 0.f;
#pragma unroll 8
        for (int k = 0; k < 64; k++) {
            float wv = wR2[k * 64 + f];
            float4 lo = *(const float4*)&abuf[w][k * 8];
            float4 hi = *(const float4*)&abuf[w][k * 8 + 4];
            acc2[0] += lo.x * wv; acc2[1] += lo.y * wv; acc2[2] += lo.z * wv; acc2[3] += lo.w * wv;
            acc2[4] += hi.x * wv; acc2[5] += hi.y * wv; acc2[6] += hi.z * wv; acc2[7] += hi.w * wv;
        }
#pragma unroll
        for (int j = 0; j < 8; j++) acc2[j] = silu_f(acc2[j]);
        ab[0] = make_float4(acc2[0], acc2[1], acc2[2], acc2[3]);
        ab[1] = make_float4(acc2[4], acc2[5], acc2[6], acc2[7]);

        // layer 3
#pragma unroll
        for (int j = 0; j < 8; j++) acc2[j] = 0.f;
#pragma unroll 8
        for (int k = 0; k < 64; k++) {
            float wv = wR3[k * 64 + f];
            float4 lo = *(const float4*)&abuf[w][k * 8];
            float4 hi = *(const float4*)&abuf[w][k * 8 + 4];
            acc2[0] += lo.x * wv; acc2[1] += lo.y * wv; acc2[2] += lo.z * wv; acc2[3] += lo.w * wv;
            acc2[4] += hi.x * wv; acc2[5] += hi.y * wv; acc2[6] += hi.z * wv; acc2[7] += hi.w * wv;
        }
#pragma unroll
        for (int j = 0; j < 8; j++) acc2[j] = silu_f(acc2[j]);
        ab[0] = make_float4(acc2[0], acc2[1], acc2[2], acc2[3]);
        ab[1] = make_float4(acc2[4], acc2[5], acc2[6], acc2[7]);

        // layer 4 (64 -> 4*64), R4 streamed from global (L1/L2 resident)
        float accw[4][8];
#pragma unroll
        for (int p = 0; p < 4; p++)
#pragma unroll
            for (int j = 0; j < 8; j++) accw[p][j] = 0.f;
#pragma unroll 2
        for (int k = 0; k < 64; k++) {
            float4 lo = *(const float4*)&abuf[w][k * 8];
            float4 hi = *(const float4*)&abuf[w][k * 8 + 4];
#pragma unroll
            for (int p = 0; p < 4; p++) {
                float wv = R4[k * 256 + p * 64 + f];
                accw[p][0] += lo.x * wv; accw[p][1] += lo.y * wv;
                accw[p][2] += lo.z * wv; accw[p][3] += lo.w * wv;
                accw[p][4] += hi.x * wv; accw[p][5] += hi.y * wv;
                accw[p][6] += hi.z * wv; accw[p][7] += hi.w * wv;
            }
        }
        // tensor product + scatter (EPS applied HERE, exactly once)
#pragma unroll
        for (int j = 0; j < 8; j++) {
            float dot = ev[j][0] * y1[j][0] + ev[j][1] * y1[j][1] + ev[j][2] * y1[j][2];
            float ms = accw[0][j] * es[j] + accw[1][j] * dot * INV_SQRT3C;
            atomicAdd(&hs_mid[rx[j] * 64 + f], EPSC * ms);
#pragma unroll
            for (int i = 0; i < 3; i++) {
                float mv = accw[2][j] * ev[j][i] + accw[3][j] * es[j] * y1[j][i] * INV_SQRT3C;
                atomicAdd(&hv_mid[rx[j] * 192 + i * 64 + f], EPSC * mv);
            }
        }
    }
}

// K3: linear_down + symmetric contraction + linear_sc + skip + readout.
__global__ __launch_bounds__(256) void k_node_post(
    const int* __restrict__ counts,
    const float* __restrict__ Wd0, const float* __restrict__ Wd1,
    const float* __restrict__ Wl0, const float* __restrict__ Wl1,
    const float* __restrict__ Wr,
    float* __restrict__ ws, float* __restrict__ out) {
    __shared__ float A[8][64];        // xm_s -> cs
    __shared__ float Bv[8][3][64];    // xm_v -> cv
    __shared__ float HS[8][64];       // hd_s -> final h_s
    __shared__ float HV[8][3][64];    // hd_v
    __shared__ int sid[8];
    int n0 = blockIdx.x * 8, tid = threadIdx.x;
    const float* hs_mid = ws + OFF_HSMID;
    const float* hv_mid = ws + OFF_HVMID;
    const float* sks = ws + OFF_SKS;
    const float* skv = ws + OFF_SKV;
    const float* wscp = ws + OFF_WSCP;

    for (int idx = tid; idx < 512; idx += 256) {
        int n = idx >> 6, f = idx & 63;
        A[n][f] = hs_mid[(n0 + n) * 64 + f];
    }
    for (int idx = tid; idx < 1536; idx += 256) {
        int n = idx / 192, rem = idx % 192;
        Bv[n][rem >> 6][rem & 63] = hv_mid[(n0 + n) * 192 + rem];
    }
    if (tid < 8) sid[tid] = species_of(n0 + tid, counts);
    __syncthreads();
    int g = tid & 63, r = tid >> 6;
    // EPS was already applied in k_edge's atomics — linear_down only scales by 1/sqrt(F).
    const float scaleBD = INV_F;
    // linear_down
    for (int o = 0; o < 4; o++) {
        for (int half = 0; half < 2; half++) {
            int n = r + half * 4;
            const float* x = (o == 0) ? A[n] : Bv[n][o - 1];
            const float* W = (o == 0) ? Wd0 : Wd1;
            float acc = 0.f;
#pragma unroll 8
            for (int f = 0; f < 64; f++) acc += x[f] * W[f * 64 + g];
            acc *= scaleBD;
            if (o == 0) HS[n][g] = acc; else HV[n][o - 1][g] = acc;
        }
    }
    __syncthreads();
    // symmetric contraction (elementwise per channel)
    for (int idx = tid; idx < 512; idx += 256) {
        int n = idx >> 6, u = idx & 63;
        float hs = HS[n][u];
        float h0 = HV[n][0][u], h1 = HV[n][1][u], h2 = HV[n][2][u];
        float vv = h0 * h0 + h1 * h1 + h2 * h2;
        const float* wv = wscp + sid[n] * 576;
        float w0 = wv[0 * 64 + u], w1 = wv[1 * 64 + u], w2 = wv[2 * 64 + u];
        float w3 = wv[3 * 64 + u], w4 = wv[4 * 64 + u];
        float w5 = wv[5 * 64 + u], w6 = wv[6 * 64 + u], w7 = wv[7 * 64 + u];
        float w8 = wv[8 * 64 + u];
        float cs = w0 * hs + w1 * hs * hs + w2 * vv + w3 * hs * hs * hs + w4 * hs * vv;
        float fv = w5 + w6 * hs + w7 * hs * hs + w8 * vv;
        A[n][u] = cs;
        Bv[n][0][u] = h0 * fv; Bv[n][1][u] = h1 * fv; Bv[n][2][u] = h2 * fv;
    }
    __syncthreads();
    float* d_hs = out + N_NODES;
    float* d_hv = out + N_NODES + N_NODES * 64;
    // linear_sc + skip + store
    for (int o = 0; o < 4; o++) {
        for (int half = 0; half < 2; half++) {
            int n = r + half * 4;
            int gn = n0 + n;
            const float* x = (o == 0) ? A[n] : Bv[n][o - 1];
            const float* W = (o == 0) ? Wl0 : Wl1;
            float acc = 0.f;
#pragma unroll 8
            for (int f = 0; f < 64; f++) acc += x[f] * W[f * 64 + g];
            acc *= INV_F;
            if (o == 0) {
                float v = acc + sks[gn * 64 + g];
                d_hs[gn * 64 + g] = v;
                HS[n][g] = v;
            } else {
                int i = o - 1;
                float v = acc + skv[gn * 192 + i * 64 + g];
                d_hv[gn * 192 + g * 3 + i] = v;
            }
        }
    }
    __syncthreads();
    // readout
    for (int half = 0; half < 2; half++) {
        int n = r + half * 4;
        float p = HS[n][g] * Wr[g];
#pragma unroll
        for (int off = 32; off > 0; off >>= 1) p += __shfl_down(p, off, 64);
        if (g == 0) out[n0 + n] = p * INV_F;
    }
}

extern "C" void kernel_launch(void* const* d_in, const int* in_sizes, int n_in,
                              void* d_out, int out_size, void* d_ws, size_t ws_size,
                              hipStream_t stream) {
    const float* vectors   = (const float*)d_in[0];
    const float* node_s    = (const float*)d_in[1];
    const float* node_v    = (const float*)d_in[2];
    const float* radial    = (const float*)d_in[3];
    const int*   senders   = (const int*)d_in[4];
    const int*   receivers = (const int*)d_in[5];
    const int*   counts    = (const int*)d_in[6];
    const float* Wup0 = (const float*)d_in[7];
    const float* Wup1 = (const float*)d_in[8];
    const float* R1   = (const float*)d_in[9];
    const float* R2   = (const float*)d_in[10];
    const float* R3   = (const float*)d_in[11];
    const float* R4   = (const float*)d_in[12];
    const float* Wd0  = (const float*)d_in[13];
    const float* Wd1  = (const float*)d_in[14];
    const float* Ws0  = (const float*)d_in[15];
    const float* Ws1  = (const float*)d_in[16];
    const float* Wsc  = (const float*)d_in[17];
    const float* Proj = (const float*)d_in[18];
    const float* Wl0  = (const float*)d_in[19];
    const float* Wl1  = (const float*)d_in[20];
    const float* Wr   = (const float*)d_in[21];
    float* ws  = (float*)d_ws;
    float* out = (float*)d_out;

    // zero atomic accumulation region (ws is poisoned 0xAA before every launch)
    hipMemsetAsync(ws + OFF_HSMID, 0, (size_t)N_NODES * 256 * sizeof(float), stream);
    k_wscproj<<<ZSP, 576, 0, stream>>>(Wsc, Proj, ws + OFF_WSCP);
    k_node_pre<<<N_NODES / 8, 256, 0, stream>>>(node_s, node_v, counts, Wup0, Wup1, Ws0, Ws1, ws);
    k_edge<<<625, 256, 0, stream>>>(vectors, radial, senders, receivers, R1, R2, R3, R4, ws);
    k_node_post<<<N_NODES / 8, 256, 0, stream>>>(counts, Wd0, Wd1, Wl0, Wl1, Wr, ws, out);
}

// Round 3
// 681.420 us; speedup vs baseline: 1.1248x; 1.1248x over previous
//
#include <hip/hip_runtime.h>
#include <math.h>

#define N_NODES 20000
#define FCH 64
#define ZSP 10
#define E_EDGES 320000
#define CHUNK 160000
#define RDIM 8
#define EPSC 0.25f
#define SQRT3C 1.7320508075688772f
#define INV_SQRT3C 0.57735026918962576f
#define INV_F 0.125f  /* 1/sqrt(64) */

// ---- workspace layout (float offsets) ----
#define OFF_HSUP   0                               // (N,64)
#define OFF_HVUP   (N_NODES*64)                    // (N,3,64)
#define OFF_SKS    (OFF_HVUP + N_NODES*192)        // (N,64)
#define OFF_SKV    (OFF_SKS + N_NODES*64)          // (N,3,64)
#define OFF_HSMID  (OFF_SKV + N_NODES*192)         // (N,64)   atomic
#define OFF_HVMID  (OFF_HSMID + N_NODES*64)        // (N,3,64) atomic
#define OFF_WSCP   (OFF_HVMID + N_NODES*192)       // (Z,9,64)
#define OFF_FRAGS  (OFF_WSCP + ZSP*576)            // 3328*8 ushort = 53248 B = 13312 floats
#define OFF_WBUF   (OFF_FRAGS + 13312)             // CHUNK*256 ushort (bf16 w, [e][f][p])

typedef __attribute__((ext_vector_type(8))) short bhalf8;
typedef __attribute__((ext_vector_type(4))) float f32x4;

__device__ __forceinline__ float silu_f(float x) {
    return x / (1.0f + expf(-x));
}

__device__ __forceinline__ unsigned short f2bf(float x) {
    unsigned int u = __float_as_uint(x);
    unsigned int r = u + 0x7FFFu + ((u >> 16) & 1u);   // RNE
    return (unsigned short)(r >> 16);
}

__device__ __forceinline__ int species_of(int n, const int* counts) {
    int acc = 0, s = ZSP - 1;
#pragma unroll
    for (int z = 0; z < ZSP; z++) {
        int c = counts[z];
        if (n >= acc && n < acc + c) s = z;
        acc += c;
    }
    return s;
}

// K0: wscp[z][b][u] = sum_p Wsc[z][p][u] * Proj[p][b]
__global__ void k_wscproj(const float* __restrict__ Wsc, const float* __restrict__ Proj,
                          float* __restrict__ wscp) {
    int z = blockIdx.x, t = threadIdx.x;
    if (t < 9 * 64) {
        int b = t >> 6, u = t & 63;
        float acc = 0.f;
#pragma unroll
        for (int p = 0; p < 9; p++) acc += Wsc[z * 576 + p * 64 + u] * Proj[p * 9 + b];
        wscp[z * 576 + b * 64 + u] = acc;
    }
}

// K-prep: build bf16 MFMA B-fragments for R1(zero-padded K8->32), R2, R3, R4.
// Frag slot fi, lane: holds B[k = s*32 + quad*8 + j][n = t*16 + (lane&15)] as 8 bf16.
// Slots: R1 t=0..3 (fi 0..3), R2 (s*4+t) fi 4..11, R3 fi 12..19, R4 (s*16+t) fi 20..51.
__global__ void k_prep(const float* __restrict__ R1, const float* __restrict__ R2,
                       const float* __restrict__ R3, const float* __restrict__ R4,
                       unsigned short* __restrict__ frags) {
    int id = blockIdx.x * 256 + threadIdx.x;
    if (id >= 3328) return;
    int lane = id & 63, fi = id >> 6;
    int quad = lane >> 4, l15 = lane & 15;
    const float* W;
    int s, t, N;
    bool r1 = false;
    if (fi < 4)       { W = R1; s = 0; t = fi; N = 64; r1 = true; }
    else if (fi < 12) { W = R2; int x = fi - 4;  s = x >> 2; t = x & 3;  N = 64; }
    else if (fi < 20) { W = R3; int x = fi - 12; s = x >> 2; t = x & 3;  N = 64; }
    else              { W = R4; int x = fi - 20; s = x >> 4; t = x & 15; N = 256; }
    unsigned int v[4];
#pragma unroll
    for (int jj = 0; jj < 4; jj++) {
        unsigned short lo, hi;
        {
            int j = jj * 2;
            int k = s * 32 + quad * 8 + j, n = t * 16 + l15;
            float val = (r1 && k >= RDIM) ? 0.f : W[k * N + n];
            lo = f2bf(val);
        }
        {
            int j = jj * 2 + 1;
            int k = s * 32 + quad * 8 + j, n = t * 16 + l15;
            float val = (r1 && k >= RDIM) ? 0.f : W[k * N + n];
            hi = f2bf(val);
        }
        v[jj] = (unsigned int)lo | ((unsigned int)hi << 16);
    }
    uint4 pk; pk.x = v[0]; pk.y = v[1]; pk.z = v[2]; pk.w = v[3];
    ((uint4*)frags)[id] = pk;
}

// K1: per-node linear_up + species skip. 8 nodes per 256-thread block.
__global__ __launch_bounds__(256) void k_node_pre(
    const float* __restrict__ ns, const float* __restrict__ nv,
    const int* __restrict__ counts,
    const float* __restrict__ Wup0, const float* __restrict__ Wup1,
    const float* __restrict__ Ws0, const float* __restrict__ Ws1,
    float* __restrict__ ws) {
    __shared__ float xs[8][64];
    __shared__ float xv[8][3][64];
    __shared__ int sid[8];
    int n0 = blockIdx.x * 8, tid = threadIdx.x;
    for (int idx = tid; idx < 8 * 64; idx += 256) {
        int n = idx >> 6, f = idx & 63;
        xs[n][f] = ns[(n0 + n) * 64 + f];
    }
    for (int idx = tid; idx < 8 * 192; idx += 256) {
        int n = idx / 192, rem = idx % 192;
        int i = rem >> 6, f = rem & 63;
        xv[n][i][f] = nv[(n0 + n) * 192 + f * 3 + i];
    }
    if (tid < 8) sid[tid] = species_of(n0 + tid, counts);
    __syncthreads();
    int g = tid & 63, r = tid >> 6;
    float* hs_up = ws + OFF_HSUP;
    float* hv_up = ws + OFF_HVUP;
    float* sks   = ws + OFF_SKS;
    float* skv   = ws + OFF_SKV;
    for (int o = 0; o < 8; o++) {
        for (int half = 0; half < 2; half++) {
            int n = r + half * 4;
            const float* x;
            const float* W;
            if (o == 0)      { x = xs[n];        W = Wup0; }
            else if (o < 4)  { x = xv[n][o - 1]; W = Wup1; }
            else if (o == 4) { x = xs[n];        W = Ws0 + sid[n] * 4096; }
            else             { x = xv[n][o - 5]; W = Ws1 + sid[n] * 4096; }
            float acc = 0.f;
#pragma unroll 8
            for (int f = 0; f < 64; f++) acc += x[f] * W[f * 64 + g];
            acc *= INV_F;
            int gn = n0 + n;
            if (o == 0)      hs_up[gn * 64 + g] = acc;
            else if (o < 4)  hv_up[gn * 192 + (o - 1) * 64 + g] = acc;
            else if (o == 4) sks[gn * 64 + g] = acc;
            else             skv[gn * 192 + (o - 5) * 64 + g] = acc;
        }
    }
}

// K2a: radial MLP via bf16 MFMA. 4 waves/block, 16 edges/wave/iter, 2 iters.
// R1/R2/R3 frags register-resident; R4 frags in LDS. Activations round-trip a
// wave-private LDS tile [16][72] bf16 (pad 72 -> 2-way bank aliasing, free).
// Output w written bf16 packed [e][f][p0p1 | p2p3] (dword stores).
__global__ __launch_bounds__(256) void k_mlp(
    const float* __restrict__ radial, const unsigned short* __restrict__ frags,
    unsigned short* __restrict__ wbuf, int e_base) {
    __shared__ unsigned short r4lds[16384];   // 32 KB
    __shared__ unsigned short act[4][16 * 72]; // 9 KB
    int tid = threadIdx.x;
    int lane = tid & 63, w = tid >> 6, quad = lane >> 4, l15 = lane & 15;

    // stage R4 frags to LDS
    const uint4* r4g = (const uint4*)(frags + 20 * 64 * 8);
    uint4* r4l = (uint4*)r4lds;
    for (int i = tid; i < 2048; i += 256) r4l[i] = r4g[i];
    // persistent B-frags
    const bhalf8* fr = (const bhalf8*)frags;
    bhalf8 r1f[4], r2f[2][4], r3f[2][4];
#pragma unroll
    for (int t = 0; t < 4; t++) r1f[t] = fr[t * 64 + lane];
#pragma unroll
    for (int s = 0; s < 2; s++)
#pragma unroll
        for (int t = 0; t < 4; t++) {
            r2f[s][t] = fr[(4 + s * 4 + t) * 64 + lane];
            r3f[s][t] = fr[(12 + s * 4 + t) * 64 + lane];
        }
    __syncthreads();

    const f32x4 z4 = {0.f, 0.f, 0.f, 0.f};
    const bhalf8* r4f = (const bhalf8*)r4lds;
    unsigned short* actw = act[w];

    for (int it = 0; it < 2; it++) {
        int el0 = (blockIdx.x * 2 + it) * 64 + w * 16;  // chunk-local edge tile base
        // ---- layer 1 (K=8 zero-padded to 32): A = radial rows ----
        bhalf8 af = {0, 0, 0, 0, 0, 0, 0, 0};
        if (quad == 0) {
            const float* rp = radial + (size_t)(e_base + el0 + l15) * 8;
            float4 ra = *(const float4*)rp;
            float4 rb = *(const float4*)(rp + 4);
            af[0] = (short)f2bf(ra.x); af[1] = (short)f2bf(ra.y);
            af[2] = (short)f2bf(ra.z); af[3] = (short)f2bf(ra.w);
            af[4] = (short)f2bf(rb.x); af[5] = (short)f2bf(rb.y);
            af[6] = (short)f2bf(rb.z); af[7] = (short)f2bf(rb.w);
        }
        {
            f32x4 acc[4];
#pragma unroll
            for (int t = 0; t < 4; t++)
                acc[t] = __builtin_amdgcn_mfma_f32_16x16x32_bf16(af, r1f[t], z4, 0, 0, 0);
#pragma unroll
            for (int t = 0; t < 4; t++)
#pragma unroll
                for (int r = 0; r < 4; r++)
                    actw[(quad * 4 + r) * 72 + t * 16 + l15] = f2bf(silu_f(acc[t][r]));
        }
        // ---- layers 2, 3 ----
#pragma unroll
        for (int layer = 0; layer < 2; layer++) {
            bhalf8 a0 = *(const bhalf8*)&actw[l15 * 72 + 0 + quad * 8];
            bhalf8 a1 = *(const bhalf8*)&actw[l15 * 72 + 32 + quad * 8];
            f32x4 acc[4];
#pragma unroll
            for (int t = 0; t < 4; t++) {
                bhalf8 b0 = layer == 0 ? r2f[0][t] : r3f[0][t];
                bhalf8 b1 = layer == 0 ? r2f[1][t] : r3f[1][t];
                acc[t] = __builtin_amdgcn_mfma_f32_16x16x32_bf16(
                    a1, b1, __builtin_amdgcn_mfma_f32_16x16x32_bf16(a0, b0, z4, 0, 0, 0), 0, 0, 0);
            }
#pragma unroll
            for (int t = 0; t < 4; t++)
#pragma unroll
                for (int r = 0; r < 4; r++)
                    actw[(quad * 4 + r) * 72 + t * 16 + l15] = f2bf(silu_f(acc[t][r]));
        }
        // ---- layer 4 (N=256, two halves of 8 tiles) ----
        {
            bhalf8 a0 = *(const bhalf8*)&actw[l15 * 72 + 0 + quad * 8];
            bhalf8 a1 = *(const bhalf8*)&actw[l15 * 72 + 32 + quad * 8];
#pragma unroll
            for (int h = 0; h < 2; h++) {
                f32x4 acc8[8];
#pragma unroll
                for (int t8 = 0; t8 < 8; t8++) {
                    int t = h * 8 + t8;
                    acc8[t8] = __builtin_amdgcn_mfma_f32_16x16x32_bf16(
                        a1, r4f[(16 + t) * 64 + lane],
                        __builtin_amdgcn_mfma_f32_16x16x32_bf16(a0, r4f[t * 64 + lane], z4, 0, 0, 0),
                        0, 0, 0);
                }
                // pack (p, p+1) pairs -> dword stores: w[e][f][p] bf16
#pragma unroll
                for (int t4 = 0; t4 < 4; t4++)
#pragma unroll
                    for (int r = 0; r < 4; r++) {
                        unsigned int lo = f2bf(acc8[t4][r]);
                        unsigned int hi = f2bf(acc8[t4 + 4][r]);
                        int el = el0 + quad * 4 + r;
                        int f = t4 * 16 + l15;
                        ((unsigned int*)wbuf)[(size_t)el * 128 + f * 2 + h] = lo | (hi << 16);
                    }
            }
        }
    }
}

// K2b: tensor product + atomic scatter. No LDS, low VGPR -> high occupancy.
__global__ __launch_bounds__(256) void k_tp(
    const float* __restrict__ vectors, const int* __restrict__ senders,
    const int* __restrict__ receivers, const unsigned short* __restrict__ wbuf,
    float* __restrict__ ws, int e_base) {
    int tid = threadIdx.x, w = tid >> 6, f = tid & 63;
    const float* hs_up = ws + OFF_HSUP;
    const float* hv_up = ws + OFF_HVUP;
    float* hs_mid = ws + OFF_HSMID;
    float* hv_mid = ws + OFF_HVMID;
    for (int it = 0; it < 10; it++) {
        int eg = ((it * 1000 + blockIdx.x) * 4 + w) * 4;  // chunk-local
        int sx[4], rx[4];
        uint2 wr[4];
        float vx[4], vy[4], vz[4], es[4], ev[4][3];
#pragma unroll
        for (int j = 0; j < 4; j++) {
            int e = e_base + eg + j;
            sx[j] = senders[e];
            rx[j] = receivers[e];
            vx[j] = vectors[e * 3 + 0];
            vy[j] = vectors[e * 3 + 1];
            vz[j] = vectors[e * 3 + 2];
            wr[j] = ((const uint2*)wbuf)[(size_t)(eg + j) * 64 + f];
        }
#pragma unroll
        for (int j = 0; j < 4; j++) {
            es[j]    = hs_up[sx[j] * 64 + f];
            ev[j][0] = hv_up[sx[j] * 192 + f];
            ev[j][1] = hv_up[sx[j] * 192 + 64 + f];
            ev[j][2] = hv_up[sx[j] * 192 + 128 + f];
        }
#pragma unroll
        for (int j = 0; j < 4; j++) {
            float s = SQRT3C * rsqrtf(vx[j] * vx[j] + vy[j] * vy[j] + vz[j] * vz[j]);
            float y0 = vx[j] * s, y1 = vy[j] * s, y2 = vz[j] * s;
            float w0 = __uint_as_float(wr[j].x << 16);
            float w1 = __uint_as_float(wr[j].x & 0xFFFF0000u);
            float w2 = __uint_as_float(wr[j].y << 16);
            float w3 = __uint_as_float(wr[j].y & 0xFFFF0000u);
            float dot = ev[j][0] * y0 + ev[j][1] * y1 + ev[j][2] * y2;
            float ms = w0 * es[j] + w1 * dot * INV_SQRT3C;
            atomicAdd(&hs_mid[rx[j] * 64 + f], EPSC * ms);
            float mv0 = w2 * ev[j][0] + w3 * es[j] * y0 * INV_SQRT3C;
            float mv1 = w2 * ev[j][1] + w3 * es[j] * y1 * INV_SQRT3C;
            float mv2 = w2 * ev[j][2] + w3 * es[j] * y2 * INV_SQRT3C;
            atomicAdd(&hv_mid[rx[j] * 192 + f], EPSC * mv0);
            atomicAdd(&hv_mid[rx[j] * 192 + 64 + f], EPSC * mv1);
            atomicAdd(&hv_mid[rx[j] * 192 + 128 + f], EPSC * mv2);
        }
    }
}

// K3: linear_down + symmetric contraction + linear_sc + skip + readout.
__global__ __launch_bounds__(256) void k_node_post(
    const int* __restrict__ counts,
    const float* __restrict__ Wd0, const float* __restrict__ Wd1,
    const float* __restrict__ Wl0, const float* __restrict__ Wl1,
    const float* __restrict__ Wr,
    float* __restrict__ ws, float* __restrict__ out) {
    __shared__ float A[8][64];
    __shared__ float Bv[8][3][64];
    __shared__ float HS[8][64];
    __shared__ float HV[8][3][64];
    __shared__ int sid[8];
    int n0 = blockIdx.x * 8, tid = threadIdx.x;
    const float* hs_mid = ws + OFF_HSMID;
    const float* hv_mid = ws + OFF_HVMID;
    const float* sks = ws + OFF_SKS;
    const float* skv = ws + OFF_SKV;
    const float* wscp = ws + OFF_WSCP;

    for (int idx = tid; idx < 512; idx += 256) {
        int n = idx >> 6, f = idx & 63;
        A[n][f] = hs_mid[(n0 + n) * 64 + f];
    }
    for (int idx = tid; idx < 1536; idx += 256) {
        int n = idx / 192, rem = idx % 192;
        Bv[n][rem >> 6][rem & 63] = hv_mid[(n0 + n) * 192 + rem];
    }
    if (tid < 8) sid[tid] = species_of(n0 + tid, counts);
    __syncthreads();
    int g = tid & 63, r = tid >> 6;
    const float scaleBD = INV_F;  // EPS already applied in k_tp atomics
    for (int o = 0; o < 4; o++) {
        for (int half = 0; half < 2; half++) {
            int n = r + half * 4;
            const float* x = (o == 0) ? A[n] : Bv[n][o - 1];
            const float* W = (o == 0) ? Wd0 : Wd1;
            float acc = 0.f;
#pragma unroll 8
            for (int f = 0; f < 64; f++) acc += x[f] * W[f * 64 + g];
            acc *= scaleBD;
            if (o == 0) HS[n][g] = acc; else HV[n][o - 1][g] = acc;
        }
    }
    __syncthreads();
    for (int idx = tid; idx < 512; idx += 256) {
        int n = idx >> 6, u = idx & 63;
        float hs = HS[n][u];
        float h0 = HV[n][0][u], h1 = HV[n][1][u], h2 = HV[n][2][u];
        float vv = h0 * h0 + h1 * h1 + h2 * h2;
        const float* wv = wscp + sid[n] * 576;
        float w0 = wv[0 * 64 + u], w1 = wv[1 * 64 + u], w2 = wv[2 * 64 + u];
        float w3 = wv[3 * 64 + u], w4 = wv[4 * 64 + u];
        float w5 = wv[5 * 64 + u], w6 = wv[6 * 64 + u], w7 = wv[7 * 64 + u];
        float w8 = wv[8 * 64 + u];
        float cs = w0 * hs + w1 * hs * hs + w2 * vv + w3 * hs * hs * hs + w4 * hs * vv;
        float fv = w5 + w6 * hs + w7 * hs * hs + w8 * vv;
        A[n][u] = cs;
        Bv[n][0][u] = h0 * fv; Bv[n][1][u] = h1 * fv; Bv[n][2][u] = h2 * fv;
    }
    __syncthreads();
    float* d_hs = out + N_NODES;
    float* d_hv = out + N_NODES + N_NODES * 64;
    for (int o = 0; o < 4; o++) {
        for (int half = 0; half < 2; half++) {
            int n = r + half * 4;
            int gn = n0 + n;
            const float* x = (o == 0) ? A[n] : Bv[n][o - 1];
            const float* W = (o == 0) ? Wl0 : Wl1;
            float acc = 0.f;
#pragma unroll 8
            for (int f = 0; f < 64; f++) acc += x[f] * W[f * 64 + g];
            acc *= INV_F;
            if (o == 0) {
                float v = acc + sks[gn * 64 + g];
                d_hs[gn * 64 + g] = v;
                HS[n][g] = v;
            } else {
                int i = o - 1;
                float v = acc + skv[gn * 192 + i * 64 + g];
                d_hv[gn * 192 + g * 3 + i] = v;
            }
        }
    }
    __syncthreads();
    for (int half = 0; half < 2; half++) {
        int n = r + half * 4;
        float p = HS[n][g] * Wr[g];
#pragma unroll
        for (int off = 32; off > 0; off >>= 1) p += __shfl_down(p, off, 64);
        if (g == 0) out[n0 + n] = p * INV_F;
    }
}

extern "C" void kernel_launch(void* const* d_in, const int* in_sizes, int n_in,
                              void* d_out, int out_size, void* d_ws, size_t ws_size,
                              hipStream_t stream) {
    const float* vectors   = (const float*)d_in[0];
    const float* node_s    = (const float*)d_in[1];
    const float* node_v    = (const float*)d_in[2];
    const float* radial    = (const float*)d_in[3];
    const int*   senders   = (const int*)d_in[4];
    const int*   receivers = (const int*)d_in[5];
    const int*   counts    = (const int*)d_in[6];
    const float* Wup0 = (const float*)d_in[7];
    const float* Wup1 = (const float*)d_in[8];
    const float* R1   = (const float*)d_in[9];
    const float* R2   = (const float*)d_in[10];
    const float* R3   = (const float*)d_in[11];
    const float* R4   = (const float*)d_in[12];
    const float* Wd0  = (const float*)d_in[13];
    const float* Wd1  = (const float*)d_in[14];
    const float* Ws0  = (const float*)d_in[15];
    const float* Ws1  = (const float*)d_in[16];
    const float* Wsc  = (const float*)d_in[17];
    const float* Proj = (const float*)d_in[18];
    const float* Wl0  = (const float*)d_in[19];
    const float* Wl1  = (const float*)d_in[20];
    const float* Wr   = (const float*)d_in[21];
    float* ws  = (float*)d_ws;
    float* out = (float*)d_out;
    unsigned short* frags = (unsigned short*)(ws + OFF_FRAGS);
    unsigned short* wbuf  = (unsigned short*)(ws + OFF_WBUF);

    hipMemsetAsync(ws + OFF_HSMID, 0, (size_t)N_NODES * 256 * sizeof(float), stream);
    k_wscproj<<<ZSP, 576, 0, stream>>>(Wsc, Proj, ws + OFF_WSCP);
    k_prep<<<13, 256, 0, stream>>>(R1, R2, R3, R4, frags);
    k_node_pre<<<N_NODES / 8, 256, 0, stream>>>(node_s, node_v, counts, Wup0, Wup1, Ws0, Ws1, ws);
    for (int c = 0; c < 2; c++) {
        int e_base = c * CHUNK;
        k_mlp<<<1250, 256, 0, stream>>>(radial, frags, wbuf, e_base);
        k_tp<<<1000, 256, 0, stream>>>(vectors, senders, receivers, wbuf, ws, e_base);
    }
    k_node_post<<<N_NODES / 8, 256, 0, stream>>>(counts, Wd0, Wd1, Wl0, Wl1, Wr, ws, out);
}

// Round 4
// 609.231 us; speedup vs baseline: 1.2581x; 1.1185x over previous
//
#include <hip/hip_runtime.h>
#include <math.h>

#define N_NODES 20000
#define FCH 64
#define ZSP 10
#define E_EDGES 320000
#define CHUNK 160000
#define RDIM 8
#define EPSC 0.25f
#define SQRT3C 1.7320508075688772f
#define INV_SQRT3C 0.57735026918962576f
#define INV_F 0.125f  /* 1/sqrt(64) */

// ---- workspace layout (float offsets) ----
#define OFF_HSUP   0                               // (N,64)
#define OFF_HVUP   (N_NODES*64)                    // (N,3,64)
#define OFF_SKS    (OFF_HVUP + N_NODES*192)        // (N,64)
#define OFF_SKV    (OFF_SKS + N_NODES*64)          // (N,3,64)
#define OFF_HSMID  (OFF_SKV + N_NODES*192)         // (N,64)
#define OFF_HVMID  (OFF_HSMID + N_NODES*64)        // (N,3,64)
#define OFF_WSCP   (OFF_HVMID + N_NODES*192)       // (Z,9,64)
#define OFF_FRAGS  (OFF_WSCP + ZSP*576)            // 3328*8 ushort = 13312 floats
#define OFF_WBUF   (OFF_FRAGS + 13312)             // CHUNK*256 ushort = CHUNK*128 floats
#define OFF_CSR    (OFF_WBUF + CHUNK*128)          // erec float4[2*CHUNK], then ints
// ints relative to csr int base (after erec):
#define CSR_CNT0   0        /* 20000, becomes cursor0 after scan */
#define CSR_CNT1   20000    /* 20000, becomes cursor1 */
#define CSR_PTR0   40000    /* 20001 */
#define CSR_PTR1   60001    /* 20001 */
#define CSR_SEID   80002    /* 2*CHUNK sorted global edge ids */

typedef __attribute__((ext_vector_type(8))) short bhalf8;
typedef __attribute__((ext_vector_type(4))) float f32x4;

__device__ __forceinline__ float silu_f(float x) {
    return x / (1.0f + expf(-x));
}

__device__ __forceinline__ unsigned short f2bf(float x) {
    unsigned int u = __float_as_uint(x);
    unsigned int r = u + 0x7FFFu + ((u >> 16) & 1u);   // RNE
    return (unsigned short)(r >> 16);
}

__device__ __forceinline__ int species_of(int n, const int* counts) {
    int acc = 0, s = ZSP - 1;
#pragma unroll
    for (int z = 0; z < ZSP; z++) {
        int c = counts[z];
        if (n >= acc && n < acc + c) s = z;
        acc += c;
    }
    return s;
}

// K0: wscp[z][b][u] = sum_p Wsc[z][p][u] * Proj[p][b]
__global__ void k_wscproj(const float* __restrict__ Wsc, const float* __restrict__ Proj,
                          float* __restrict__ wscp) {
    int z = blockIdx.x, t = threadIdx.x;
    if (t < 9 * 64) {
        int b = t >> 6, u = t & 63;
        float acc = 0.f;
#pragma unroll
        for (int p = 0; p < 9; p++) acc += Wsc[z * 576 + p * 64 + u] * Proj[p * 9 + b];
        wscp[z * 576 + b * 64 + u] = acc;
    }
}

// K-prep: build bf16 MFMA B-fragments for R1(zero-padded K8->32), R2, R3, R4.
__global__ void k_prep(const float* __restrict__ R1, const float* __restrict__ R2,
                       const float* __restrict__ R3, const float* __restrict__ R4,
                       unsigned short* __restrict__ frags) {
    int id = blockIdx.x * 256 + threadIdx.x;
    if (id >= 3328) return;
    int lane = id & 63, fi = id >> 6;
    int quad = lane >> 4, l15 = lane & 15;
    const float* W;
    int s, t, N;
    bool r1 = false;
    if (fi < 4)       { W = R1; s = 0; t = fi; N = 64; r1 = true; }
    else if (fi < 12) { W = R2; int x = fi - 4;  s = x >> 2; t = x & 3;  N = 64; }
    else if (fi < 20) { W = R3; int x = fi - 12; s = x >> 2; t = x & 3;  N = 64; }
    else              { W = R4; int x = fi - 20; s = x >> 4; t = x & 15; N = 256; }
    unsigned int v[4];
#pragma unroll
    for (int jj = 0; jj < 4; jj++) {
        unsigned short lo, hi;
        {
            int j = jj * 2;
            int k = s * 32 + quad * 8 + j, n = t * 16 + l15;
            float val = (r1 && k >= RDIM) ? 0.f : W[k * N + n];
            lo = f2bf(val);
        }
        {
            int j = jj * 2 + 1;
            int k = s * 32 + quad * 8 + j, n = t * 16 + l15;
            float val = (r1 && k >= RDIM) ? 0.f : W[k * N + n];
            hi = f2bf(val);
        }
        v[jj] = (unsigned int)lo | ((unsigned int)hi << 16);
    }
    uint4 pk; pk.x = v[0]; pk.y = v[1]; pk.z = v[2]; pk.w = v[3];
    ((uint4*)frags)[id] = pk;
}

// CSR build: histogram of receivers per chunk
__global__ __launch_bounds__(256) void k_hist(const int* __restrict__ receivers,
                                              int* __restrict__ csr) {
    int e = blockIdx.x * 256 + threadIdx.x;
    if (e < E_EDGES) {
        int base = (e < CHUNK) ? CSR_CNT0 : CSR_CNT1;
        atomicAdd(&csr[base + receivers[e]], 1);
    }
}

// CSR build: exclusive scan (one block per chunk); writes ptr and cursor(=cnt in place)
__global__ __launch_bounds__(256) void k_scan(int* __restrict__ csr) {
    __shared__ int sb[256];
    int z = blockIdx.x, t = threadIdx.x;
    int cb = z ? CSR_CNT1 : CSR_CNT0;
    int pb = z ? CSR_PTR1 : CSR_PTR0;
    int running = 0;
    for (int i0 = 0; i0 < N_NODES; i0 += 256) {
        int i = i0 + t;
        int x = (i < N_NODES) ? csr[cb + i] : 0;
        sb[t] = x;
        __syncthreads();
        for (int off = 1; off < 256; off <<= 1) {
            int v = (t >= off) ? sb[t - off] : 0;
            __syncthreads();
            sb[t] += v;
            __syncthreads();
        }
        int excl = sb[t] - x;
        if (i < N_NODES) {
            csr[pb + i] = running + excl;
            csr[cb + i] = running + excl;   // cursor
        }
        int tot = sb[255];
        __syncthreads();
        running += tot;
    }
    if (t == 0) csr[pb + N_NODES] = running;
}

// CSR build: bucket edges into sorted order; precompute Y1 + sender per slot.
__global__ __launch_bounds__(256) void k_bucket(
    const float* __restrict__ vectors, const int* __restrict__ senders,
    const int* __restrict__ receivers, int* __restrict__ csr,
    float4* __restrict__ erec) {
    int e = blockIdx.x * 256 + threadIdx.x;
    if (e >= E_EDGES) return;
    int z = (e < CHUNK) ? 0 : 1;
    int base = z ? CSR_CNT1 : CSR_CNT0;
    int pos = atomicAdd(&csr[base + receivers[e]], 1);  // within-chunk slot
    float v0 = vectors[e * 3 + 0], v1 = vectors[e * 3 + 1], v2 = vectors[e * 3 + 2];
    float s = SQRT3C * rsqrtf(v0 * v0 + v1 * v1 + v2 * v2);
    int idx = z * CHUNK + pos;
    csr[CSR_SEID + idx] = e;
    float4 r;
    r.x = v0 * s; r.y = v1 * s; r.z = v2 * s; r.w = __int_as_float(senders[e]);
    erec[idx] = r;
}

// K1: per-node linear_up + species skip. 8 nodes per 256-thread block.
__global__ __launch_bounds__(256) void k_node_pre(
    const float* __restrict__ ns, const float* __restrict__ nv,
    const int* __restrict__ counts,
    const float* __restrict__ Wup0, const float* __restrict__ Wup1,
    const float* __restrict__ Ws0, const float* __restrict__ Ws1,
    float* __restrict__ ws) {
    __shared__ float xs[8][64];
    __shared__ float xv[8][3][64];
    __shared__ int sid[8];
    int n0 = blockIdx.x * 8, tid = threadIdx.x;
    for (int idx = tid; idx < 8 * 64; idx += 256) {
        int n = idx >> 6, f = idx & 63;
        xs[n][f] = ns[(n0 + n) * 64 + f];
    }
    for (int idx = tid; idx < 8 * 192; idx += 256) {
        int n = idx / 192, rem = idx % 192;
        int i = rem >> 6, f = rem & 63;
        xv[n][i][f] = nv[(n0 + n) * 192 + f * 3 + i];
    }
    if (tid < 8) sid[tid] = species_of(n0 + tid, counts);
    __syncthreads();
    int g = tid & 63, r = tid >> 6;
    float* hs_up = ws + OFF_HSUP;
    float* hv_up = ws + OFF_HVUP;
    float* sks   = ws + OFF_SKS;
    float* skv   = ws + OFF_SKV;
    for (int o = 0; o < 8; o++) {
        for (int half = 0; half < 2; half++) {
            int n = r + half * 4;
            const float* x;
            const float* W;
            if (o == 0)      { x = xs[n];        W = Wup0; }
            else if (o < 4)  { x = xv[n][o - 1]; W = Wup1; }
            else if (o == 4) { x = xs[n];        W = Ws0 + sid[n] * 4096; }
            else             { x = xv[n][o - 5]; W = Ws1 + sid[n] * 4096; }
            float acc = 0.f;
#pragma unroll 8
            for (int f = 0; f < 64; f++) acc += x[f] * W[f * 64 + g];
            acc *= INV_F;
            int gn = n0 + n;
            if (o == 0)      hs_up[gn * 64 + g] = acc;
            else if (o < 4)  hv_up[gn * 192 + (o - 1) * 64 + g] = acc;
            else if (o == 4) sks[gn * 64 + g] = acc;
            else             skv[gn * 192 + (o - 5) * 64 + g] = acc;
        }
    }
}

// K2a: radial MLP via bf16 MFMA (unchanged from R3).
__global__ __launch_bounds__(256) void k_mlp(
    const float* __restrict__ radial, const unsigned short* __restrict__ frags,
    unsigned short* __restrict__ wbuf, int e_base) {
    __shared__ unsigned short r4lds[16384];
    __shared__ unsigned short act[4][16 * 72];
    int tid = threadIdx.x;
    int lane = tid & 63, w = tid >> 6, quad = lane >> 4, l15 = lane & 15;

    const uint4* r4g = (const uint4*)(frags + 20 * 64 * 8);
    uint4* r4l = (uint4*)r4lds;
    for (int i = tid; i < 2048; i += 256) r4l[i] = r4g[i];
    const bhalf8* fr = (const bhalf8*)frags;
    bhalf8 r1f[4], r2f[2][4], r3f[2][4];
#pragma unroll
    for (int t = 0; t < 4; t++) r1f[t] = fr[t * 64 + lane];
#pragma unroll
    for (int s = 0; s < 2; s++)
#pragma unroll
        for (int t = 0; t < 4; t++) {
            r2f[s][t] = fr[(4 + s * 4 + t) * 64 + lane];
            r3f[s][t] = fr[(12 + s * 4 + t) * 64 + lane];
        }
    __syncthreads();

    const f32x4 z4 = {0.f, 0.f, 0.f, 0.f};
    const bhalf8* r4f = (const bhalf8*)r4lds;
    unsigned short* actw = act[w];

    for (int it = 0; it < 2; it++) {
        int el0 = (blockIdx.x * 2 + it) * 64 + w * 16;
        bhalf8 af = {0, 0, 0, 0, 0, 0, 0, 0};
        if (quad == 0) {
            const float* rp = radial + (size_t)(e_base + el0 + l15) * 8;
            float4 ra = *(const float4*)rp;
            float4 rb = *(const float4*)(rp + 4);
            af[0] = (short)f2bf(ra.x); af[1] = (short)f2bf(ra.y);
            af[2] = (short)f2bf(ra.z); af[3] = (short)f2bf(ra.w);
            af[4] = (short)f2bf(rb.x); af[5] = (short)f2bf(rb.y);
            af[6] = (short)f2bf(rb.z); af[7] = (short)f2bf(rb.w);
        }
        {
            f32x4 acc[4];
#pragma unroll
            for (int t = 0; t < 4; t++)
                acc[t] = __builtin_amdgcn_mfma_f32_16x16x32_bf16(af, r1f[t], z4, 0, 0, 0);
#pragma unroll
            for (int t = 0; t < 4; t++)
#pragma unroll
                for (int r = 0; r < 4; r++)
                    actw[(quad * 4 + r) * 72 + t * 16 + l15] = f2bf(silu_f(acc[t][r]));
        }
#pragma unroll
        for (int layer = 0; layer < 2; layer++) {
            bhalf8 a0 = *(const bhalf8*)&actw[l15 * 72 + 0 + quad * 8];
            bhalf8 a1 = *(const bhalf8*)&actw[l15 * 72 + 32 + quad * 8];
            f32x4 acc[4];
#pragma unroll
            for (int t = 0; t < 4; t++) {
                bhalf8 b0 = layer == 0 ? r2f[0][t] : r3f[0][t];
                bhalf8 b1 = layer == 0 ? r2f[1][t] : r3f[1][t];
                acc[t] = __builtin_amdgcn_mfma_f32_16x16x32_bf16(
                    a1, b1, __builtin_amdgcn_mfma_f32_16x16x32_bf16(a0, b0, z4, 0, 0, 0), 0, 0, 0);
            }
#pragma unroll
            for (int t = 0; t < 4; t++)
#pragma unroll
                for (int r = 0; r < 4; r++)
                    actw[(quad * 4 + r) * 72 + t * 16 + l15] = f2bf(silu_f(acc[t][r]));
        }
        {
            bhalf8 a0 = *(const bhalf8*)&actw[l15 * 72 + 0 + quad * 8];
            bhalf8 a1 = *(const bhalf8*)&actw[l15 * 72 + 32 + quad * 8];
#pragma unroll
            for (int h = 0; h < 2; h++) {
                f32x4 acc8[8];
#pragma unroll
                for (int t8 = 0; t8 < 8; t8++) {
                    int t = h * 8 + t8;
                    acc8[t8] = __builtin_amdgcn_mfma_f32_16x16x32_bf16(
                        a1, r4f[(16 + t) * 64 + lane],
                        __builtin_amdgcn_mfma_f32_16x16x32_bf16(a0, r4f[t * 64 + lane], z4, 0, 0, 0),
                        0, 0, 0);
                }
#pragma unroll
                for (int t4 = 0; t4 < 4; t4++)
#pragma unroll
                    for (int r = 0; r < 4; r++) {
                        unsigned int lo = f2bf(acc8[t4][r]);
                        unsigned int hi = f2bf(acc8[t4 + 4][r]);
                        int el = el0 + quad * 4 + r;
                        int f = t4 * 16 + l15;
                        ((unsigned int*)wbuf)[(size_t)el * 128 + f * 2 + h] = lo | (hi << 16);
                    }
            }
        }
    }
}

// K2b: CSR gather tensor product. One wave per node, lane = channel.
// accum=0: overwrite (chunk 0). accum=1: load+add, apply EPS, store (chunk 1).
__global__ __launch_bounds__(256) void k_tp_gather(
    const unsigned short* __restrict__ wbuf, const int* __restrict__ csr,
    const float4* __restrict__ erec, float* __restrict__ ws,
    int z, int accum) {
    int tid = threadIdx.x, w = tid >> 6, f = tid & 63;
    int n = blockIdx.x * 4 + w;
    const float* hs_up = ws + OFF_HSUP;
    const float* hv_up = ws + OFF_HVUP;
    float* hs_mid = ws + OFF_HSMID;
    float* hv_mid = ws + OFF_HVMID;
    int pb = z ? CSR_PTR1 : CSR_PTR0;
    int beg = csr[pb + n], end = csr[pb + n + 1];
    int e_base = z * CHUNK;
    float ams = 0.f, am0 = 0.f, am1 = 0.f, am2 = 0.f;
    for (int i = beg; i < end; i++) {
        int idx = e_base + i;            // slot in sorted arrays
        int eid = csr[CSR_SEID + idx];   // global edge id
        float4 rc = erec[idx];
        int sx = __float_as_int(rc.w);
        uint2 wr = ((const uint2*)wbuf)[(size_t)(eid - e_base) * 64 + f];
        float es = hs_up[sx * 64 + f];
        float e0 = hv_up[sx * 192 + f];
        float e1 = hv_up[sx * 192 + 64 + f];
        float e2 = hv_up[sx * 192 + 128 + f];
        float w0 = __uint_as_float(wr.x << 16);
        float w1 = __uint_as_float(wr.x & 0xFFFF0000u);
        float w2 = __uint_as_float(wr.y << 16);
        float w3 = __uint_as_float(wr.y & 0xFFFF0000u);
        float dot = e0 * rc.x + e1 * rc.y + e2 * rc.z;
        ams += w0 * es + w1 * dot * INV_SQRT3C;
        float t3 = w3 * es * INV_SQRT3C;
        am0 += w2 * e0 + t3 * rc.x;
        am1 += w2 * e1 + t3 * rc.y;
        am2 += w2 * e2 + t3 * rc.z;
    }
    if (!accum) {
        hs_mid[n * 64 + f] = ams;
        hv_mid[n * 192 + f] = am0;
        hv_mid[n * 192 + 64 + f] = am1;
        hv_mid[n * 192 + 128 + f] = am2;
    } else {
        hs_mid[n * 64 + f] = (hs_mid[n * 64 + f] + ams) * EPSC;
        hv_mid[n * 192 + f] = (hv_mid[n * 192 + f] + am0) * EPSC;
        hv_mid[n * 192 + 64 + f] = (hv_mid[n * 192 + 64 + f] + am1) * EPSC;
        hv_mid[n * 192 + 128 + f] = (hv_mid[n * 192 + 128 + f] + am2) * EPSC;
    }
}

// K3: linear_down + symmetric contraction + linear_sc + skip + readout.
__global__ __launch_bounds__(256) void k_node_post(
    const int* __restrict__ counts,
    const float* __restrict__ Wd0, const float* __restrict__ Wd1,
    const float* __restrict__ Wl0, const float* __restrict__ Wl1,
    const float* __restrict__ Wr,
    float* __restrict__ ws, float* __restrict__ out) {
    __shared__ float A[8][64];
    __shared__ float Bv[8][3][64];
    __shared__ float HS[8][64];
    __shared__ float HV[8][3][64];
    __shared__ int sid[8];
    int n0 = blockIdx.x * 8, tid = threadIdx.x;
    const float* hs_mid = ws + OFF_HSMID;
    const float* hv_mid = ws + OFF_HVMID;
    const float* sks = ws + OFF_SKS;
    const float* skv = ws + OFF_SKV;
    const float* wscp = ws + OFF_WSCP;

    for (int idx = tid; idx < 512; idx += 256) {
        int n = idx >> 6, f = idx & 63;
        A[n][f] = hs_mid[(n0 + n) * 64 + f];
    }
    for (int idx = tid; idx < 1536; idx += 256) {
        int n = idx / 192, rem = idx % 192;
        Bv[n][rem >> 6][rem & 63] = hv_mid[(n0 + n) * 192 + rem];
    }
    if (tid < 8) sid[tid] = species_of(n0 + tid, counts);
    __syncthreads();
    int g = tid & 63, r = tid >> 6;
    const float scaleBD = INV_F;  // EPS applied in k_tp_gather's final store
    for (int o = 0; o < 4; o++) {
        for (int half = 0; half < 2; half++) {
            int n = r + half * 4;
            const float* x = (o == 0) ? A[n] : Bv[n][o - 1];
            const float* W = (o == 0) ? Wd0 : Wd1;
            float acc = 0.f;
#pragma unroll 8
            for (int f = 0; f < 64; f++) acc += x[f] * W[f * 64 + g];
            acc *= scaleBD;
            if (o == 0) HS[n][g] = acc; else HV[n][o - 1][g] = acc;
        }
    }
    __syncthreads();
    for (int idx = tid; idx < 512; idx += 256) {
        int n = idx >> 6, u = idx & 63;
        float hs = HS[n][u];
        float h0 = HV[n][0][u], h1 = HV[n][1][u], h2 = HV[n][2][u];
        float vv = h0 * h0 + h1 * h1 + h2 * h2;
        const float* wv = wscp + sid[n] * 576;
        float w0 = wv[0 * 64 + u], w1 = wv[1 * 64 + u], w2 = wv[2 * 64 + u];
        float w3 = wv[3 * 64 + u], w4 = wv[4 * 64 + u];
        float w5 = wv[5 * 64 + u], w6 = wv[6 * 64 + u], w7 = wv[7 * 64 + u];
        float w8 = wv[8 * 64 + u];
        float cs = w0 * hs + w1 * hs * hs + w2 * vv + w3 * hs * hs * hs + w4 * hs * vv;
        float fv = w5 + w6 * hs + w7 * hs * hs + w8 * vv;
        A[n][u] = cs;
        Bv[n][0][u] = h0 * fv; Bv[n][1][u] = h1 * fv; Bv[n][2][u] = h2 * fv;
    }
    __syncthreads();
    float* d_hs = out + N_NODES;
    float* d_hv = out + N_NODES + N_NODES * 64;
    for (int o = 0; o < 4; o++) {
        for (int half = 0; half < 2; half++) {
            int n = r + half * 4;
            int gn = n0 + n;
            const float* x = (o == 0) ? A[n] : Bv[n][o - 1];
            const float* W = (o == 0) ? Wl0 : Wl1;
            float acc = 0.f;
#pragma unroll 8
            for (int f = 0; f < 64; f++) acc += x[f] * W[f * 64 + g];
            acc *= INV_F;
            if (o == 0) {
                float v = acc + sks[gn * 64 + g];
                d_hs[gn * 64 + g] = v;
                HS[n][g] = v;
            } else {
                int i = o - 1;
                float v = acc + skv[gn * 192 + i * 64 + g];
                d_hv[gn * 192 + g * 3 + i] = v;
            }
        }
    }
    __syncthreads();
    for (int half = 0; half < 2; half++) {
        int n = r + half * 4;
        float p = HS[n][g] * Wr[g];
#pragma unroll
        for (int off = 32; off > 0; off >>= 1) p += __shfl_down(p, off, 64);
        if (g == 0) out[n0 + n] = p * INV_F;
    }
}

extern "C" void kernel_launch(void* const* d_in, const int* in_sizes, int n_in,
                              void* d_out, int out_size, void* d_ws, size_t ws_size,
                              hipStream_t stream) {
    const float* vectors   = (const float*)d_in[0];
    const float* node_s    = (const float*)d_in[1];
    const float* node_v    = (const float*)d_in[2];
    const float* radial    = (const float*)d_in[3];
    const int*   senders   = (const int*)d_in[4];
    const int*   receivers = (const int*)d_in[5];
    const int*   counts    = (const int*)d_in[6];
    const float* Wup0 = (const float*)d_in[7];
    const float* Wup1 = (const float*)d_in[8];
    const float* R1   = (const float*)d_in[9];
    const float* R2   = (const float*)d_in[10];
    const float* R3   = (const float*)d_in[11];
    const float* R4   = (const float*)d_in[12];
    const float* Wd0  = (const float*)d_in[13];
    const float* Wd1  = (const float*)d_in[14];
    const float* Ws0  = (const float*)d_in[15];
    const float* Ws1  = (const float*)d_in[16];
    const float* Wsc  = (const float*)d_in[17];
    const float* Proj = (const float*)d_in[18];
    const float* Wl0  = (const float*)d_in[19];
    const float* Wl1  = (const float*)d_in[20];
    const float* Wr   = (const float*)d_in[21];
    float* ws  = (float*)d_ws;
    float* out = (float*)d_out;
    unsigned short* frags = (unsigned short*)(ws + OFF_FRAGS);
    unsigned short* wbuf  = (unsigned short*)(ws + OFF_WBUF);
    float4* erec = (float4*)(ws + OFF_CSR);
    int* csr = (int*)(ws + OFF_CSR + 2 * CHUNK * 4);

    // zero CSR histogram counters only (160 KB)
    hipMemsetAsync(csr, 0, 2 * N_NODES * sizeof(int), stream);
    k_wscproj<<<ZSP, 576, 0, stream>>>(Wsc, Proj, ws + OFF_WSCP);
    k_prep<<<13, 256, 0, stream>>>(R1, R2, R3, R4, frags);
    k_hist<<<E_EDGES / 256, 256, 0, stream>>>(receivers, csr);
    k_scan<<<2, 256, 0, stream>>>(csr);
    k_node_pre<<<N_NODES / 8, 256, 0, stream>>>(node_s, node_v, counts, Wup0, Wup1, Ws0, Ws1, ws);
    k_bucket<<<E_EDGES / 256, 256, 0, stream>>>(vectors, senders, receivers, csr, erec);
    for (int c = 0; c < 2; c++) {
        k_mlp<<<1250, 256, 0, stream>>>(radial, frags, wbuf, c * CHUNK);
        k_tp_gather<<<N_NODES / 4, 256, 0, stream>>>(wbuf, csr, erec, ws, c, c);
    }
    k_node_post<<<N_NODES / 8, 256, 0, stream>>>(counts, Wd0, Wd1, Wl0, Wl1, Wr, ws, out);
}

// Round 5
// 451.640 us; speedup vs baseline: 1.6971x; 1.3489x over previous
//
#include <hip/hip_runtime.h>
#include <math.h>

#define N_NODES 20000
#define FCH 64
#define ZSP 10
#define E_EDGES 320000
#define CHUNK 160000
#define RDIM 8
#define EPSC 0.25f
#define SQRT3C 1.7320508075688772f
#define INV_SQRT3C 0.57735026918962576f
#define INV_F 0.125f  /* 1/sqrt(64) */

// ---- workspace layout (float offsets) ----
#define OFF_HSUP   0                               // (N,64)
#define OFF_HVUP   (N_NODES*64)                    // (N,3,64) planar
#define OFF_SKS    (OFF_HVUP + N_NODES*192)        // (N,64)
#define OFF_SKV    (OFF_SKS + N_NODES*64)          // (N,3,64) planar
#define OFF_HSMID  (OFF_SKV + N_NODES*192)         // (N,64)
#define OFF_HVMID  (OFF_HSMID + N_NODES*64)        // (N,3,64) planar
#define OFF_WSCP   (OFF_HVMID + N_NODES*192)       // (Z,9,64)
#define OFF_FRAGS  (OFF_WSCP + ZSP*576)            // 3328*8 ushort = 13312 floats
#define OFF_WBUF   (OFF_FRAGS + 13312)             // CHUNK*256 ushort = CHUNK*128 floats
#define OFF_CSR    (OFF_WBUF + CHUNK*128)          // erec float4[2*CHUNK], then ints
#define OFF_WF     (OFF_CSR + 2*CHUNK*4 + 400004)  // 416 slots * 512 ushort = 106496 floats
// ints relative to csr int base (after erec):
#define CSR_CNT0   0
#define CSR_CNT1   20000
#define CSR_PTR0   40000
#define CSR_PTR1   60001
#define CSR_SEID   80002

typedef __attribute__((ext_vector_type(8))) short bhalf8;
typedef __attribute__((ext_vector_type(4))) float f32x4;

__device__ __forceinline__ float silu_f(float x) {
    return x / (1.0f + expf(-x));
}

__device__ __forceinline__ unsigned short f2bf(float x) {
    unsigned int u = __float_as_uint(x);
    unsigned int r = u + 0x7FFFu + ((u >> 16) & 1u);   // RNE
    return (unsigned short)(r >> 16);
}

// split fp32 -> bf16 hi (trunc) + bf16 lo (trunc of residual); err ~2^-16 rel
__device__ __forceinline__ void split_f32(float x, short& h, short& l) {
    unsigned int u = __float_as_uint(x);
    unsigned int hb = u & 0xFFFF0000u;
    h = (short)(u >> 16);
    float r = x - __uint_as_float(hb);
    l = (short)(__float_as_uint(r) >> 16);
}

__device__ __forceinline__ int species_of(int n, const int* counts) {
    int acc = 0, s = ZSP - 1;
#pragma unroll
    for (int z = 0; z < ZSP; z++) {
        int c = counts[z];
        if (n >= acc && n < acc + c) s = z;
        acc += c;
    }
    return s;
}

// K0: wscp[z][b][u] = sum_p Wsc[z][p][u] * Proj[p][b]
__global__ void k_wscproj(const float* __restrict__ Wsc, const float* __restrict__ Proj,
                          float* __restrict__ wscp) {
    int z = blockIdx.x, t = threadIdx.x;
    if (t < 9 * 64) {
        int b = t >> 6, u = t & 63;
        float acc = 0.f;
#pragma unroll
        for (int p = 0; p < 9; p++) acc += Wsc[z * 576 + p * 64 + u] * Proj[p * 9 + b];
        wscp[z * 576 + b * 64 + u] = acc;
    }
}

// K-prep: bf16 MFMA B-fragments for R1(zero-pad K8->32), R2, R3, R4 (MLP path).
__global__ void k_prep(const float* __restrict__ R1, const float* __restrict__ R2,
                       const float* __restrict__ R3, const float* __restrict__ R4,
                       unsigned short* __restrict__ frags) {
    int id = blockIdx.x * 256 + threadIdx.x;
    if (id >= 3328) return;
    int lane = id & 63, fi = id >> 6;
    int quad = lane >> 4, l15 = lane & 15;
    const float* W;
    int s, t, N;
    bool r1 = false;
    if (fi < 4)       { W = R1; s = 0; t = fi; N = 64; r1 = true; }
    else if (fi < 12) { W = R2; int x = fi - 4;  s = x >> 2; t = x & 3;  N = 64; }
    else if (fi < 20) { W = R3; int x = fi - 12; s = x >> 2; t = x & 3;  N = 64; }
    else              { W = R4; int x = fi - 20; s = x >> 4; t = x & 15; N = 256; }
    unsigned int v[4];
#pragma unroll
    for (int jj = 0; jj < 4; jj++) {
        unsigned short lo, hi;
        {
            int j = jj * 2;
            int k = s * 32 + quad * 8 + j, n = t * 16 + l15;
            float val = (r1 && k >= RDIM) ? 0.f : W[k * N + n];
            lo = f2bf(val);
        }
        {
            int j = jj * 2 + 1;
            int k = s * 32 + quad * 8 + j, n = t * 16 + l15;
            float val = (r1 && k >= RDIM) ? 0.f : W[k * N + n];
            hi = f2bf(val);
        }
        v[jj] = (unsigned int)lo | ((unsigned int)hi << 16);
    }
    uint4 pk; pk.x = v[0]; pk.y = v[1]; pk.z = v[2]; pk.w = v[3];
    ((uint4*)frags)[id] = pk;
}

// K-prep2: split-bf16 (hi/lo) B-fragments for the 26 node-side 64x64 matrices.
// mat: 0=Wup0 1=Wup1 2..11=Ws0[z] 12..21=Ws1[z] 22=Wd0 23=Wd1 24=Wl0 25=Wl1
// slot(mat,part,s,t) = mat*16 + part*8 + s*4 + t ; each slot 64 lanes x 8 bf16.
__global__ void k_prep2(const float* __restrict__ Wup0, const float* __restrict__ Wup1,
                        const float* __restrict__ Ws0, const float* __restrict__ Ws1,
                        const float* __restrict__ Wd0, const float* __restrict__ Wd1,
                        const float* __restrict__ Wl0, const float* __restrict__ Wl1,
                        unsigned short* __restrict__ wf) {
    int id = blockIdx.x * 256 + threadIdx.x;
    if (id >= 416 * 64) return;
    int lane = id & 63, slot = id >> 6;
    int t = slot & 3, s = (slot >> 2) & 1, part = (slot >> 3) & 1, mat = slot >> 4;
    int quad = lane >> 4, l15 = lane & 15;
    const float* W;
    if (mat == 0)       W = Wup0;
    else if (mat == 1)  W = Wup1;
    else if (mat < 12)  W = Ws0 + (mat - 2) * 4096;
    else if (mat < 22)  W = Ws1 + (mat - 12) * 4096;
    else if (mat == 22) W = Wd0;
    else if (mat == 23) W = Wd1;
    else if (mat == 24) W = Wl0;
    else                W = Wl1;
    unsigned int v[4];
#pragma unroll
    for (int jj = 0; jj < 4; jj++) {
        unsigned short pk2[2];
#pragma unroll
        for (int o = 0; o < 2; o++) {
            int j = jj * 2 + o;
            int k = s * 32 + quad * 8 + j, n = t * 16 + l15;
            float x = W[k * 64 + n];
            short h, l;
            split_f32(x, h, l);
            pk2[o] = part == 0 ? (unsigned short)h : (unsigned short)l;
        }
        v[jj] = (unsigned int)pk2[0] | ((unsigned int)pk2[1] << 16);
    }
    uint4 pk; pk.x = v[0]; pk.y = v[1]; pk.z = v[2]; pk.w = v[3];
    ((uint4*)wf)[id] = pk;
}

// CSR build: histogram of receivers per chunk
__global__ __launch_bounds__(256) void k_hist(const int* __restrict__ receivers,
                                              int* __restrict__ csr) {
    int e = blockIdx.x * 256 + threadIdx.x;
    if (e < E_EDGES) {
        int base = (e < CHUNK) ? CSR_CNT0 : CSR_CNT1;
        atomicAdd(&csr[base + receivers[e]], 1);
    }
}

// CSR build: exclusive scan (one block per chunk)
__global__ __launch_bounds__(256) void k_scan(int* __restrict__ csr) {
    __shared__ int sb[256];
    int z = blockIdx.x, t = threadIdx.x;
    int cb = z ? CSR_CNT1 : CSR_CNT0;
    int pb = z ? CSR_PTR1 : CSR_PTR0;
    int running = 0;
    for (int i0 = 0; i0 < N_NODES; i0 += 256) {
        int i = i0 + t;
        int x = (i < N_NODES) ? csr[cb + i] : 0;
        sb[t] = x;
        __syncthreads();
        for (int off = 1; off < 256; off <<= 1) {
            int v = (t >= off) ? sb[t - off] : 0;
            __syncthreads();
            sb[t] += v;
            __syncthreads();
        }
        int excl = sb[t] - x;
        if (i < N_NODES) {
            csr[pb + i] = running + excl;
            csr[cb + i] = running + excl;   // cursor
        }
        int tot = sb[255];
        __syncthreads();
        running += tot;
    }
    if (t == 0) csr[pb + N_NODES] = running;
}

// CSR build: bucket edges; precompute Y1 + sender per slot.
__global__ __launch_bounds__(256) void k_bucket(
    const float* __restrict__ vectors, const int* __restrict__ senders,
    const int* __restrict__ receivers, int* __restrict__ csr,
    float4* __restrict__ erec) {
    int e = blockIdx.x * 256 + threadIdx.x;
    if (e >= E_EDGES) return;
    int z = (e < CHUNK) ? 0 : 1;
    int base = z ? CSR_CNT1 : CSR_CNT0;
    int pos = atomicAdd(&csr[base + receivers[e]], 1);
    float v0 = vectors[e * 3 + 0], v1 = vectors[e * 3 + 1], v2 = vectors[e * 3 + 2];
    float s = SQRT3C * rsqrtf(v0 * v0 + v1 * v1 + v2 * v2);
    int idx = z * CHUNK + pos;
    csr[CSR_SEID + idx] = e;
    float4 r;
    r.x = v0 * s; r.y = v1 * s; r.z = v2 * s; r.w = __int_as_float(senders[e]);
    erec[idx] = r;
}

// K1: linear_up + species skip via split-bf16 MFMA.
// 1 block = one 16-node tile, 4 waves: w0 scalar paths (Wup0,Ws0), w1..3 = vector
// component i=w-1 (Wup1, Ws1). Species blocks (2000) are 16-aligned.
__global__ __launch_bounds__(256) void k_node_pre(
    const float* __restrict__ ns, const float* __restrict__ nv,
    const int* __restrict__ counts, const unsigned short* __restrict__ wf,
    float* __restrict__ ws) {
    int tid = threadIdx.x, w = tid >> 6, lane = tid & 63;
    int q = lane >> 4, l15 = lane & 15;
    int nw = blockIdx.x * 16;
    int sid = species_of(nw, counts);
    const f32x4 z4 = {0.f, 0.f, 0.f, 0.f};

    bhalf8 Ah[2], Al[2];
    if (w == 0) {
#pragma unroll
        for (int s = 0; s < 2; s++) {
            const float* rp = ns + (size_t)(nw + l15) * 64 + s * 32 + q * 8;
            float4 a = *(const float4*)rp, b = *(const float4*)(rp + 4);
            float x[8] = {a.x, a.y, a.z, a.w, b.x, b.y, b.z, b.w};
#pragma unroll
            for (int j = 0; j < 8; j++) { short h, l; split_f32(x[j], h, l); Ah[s][j] = h; Al[s][j] = l; }
        }
    } else {
        int i = w - 1;
#pragma unroll
        for (int s = 0; s < 2; s++) {
            const float* rp = nv + (size_t)(nw + l15) * 192 + i;
#pragma unroll
            for (int j = 0; j < 8; j++) {
                float x = rp[(s * 32 + q * 8 + j) * 3];
                short h, l; split_f32(x, h, l); Ah[s][j] = h; Al[s][j] = l;
            }
        }
    }

    const bhalf8* wfv = (const bhalf8*)wf;
    float* hs_up = ws + OFF_HSUP;
    float* hv_up = ws + OFF_HVUP;
    float* sks   = ws + OFF_SKS;
    float* skv   = ws + OFF_SKV;

#pragma unroll
    for (int m = 0; m < 2; m++) {
        int mat = (w == 0) ? (m == 0 ? 0 : 2 + sid) : (m == 0 ? 1 : 12 + sid);
        float* dst; int stride, off;
        if (w == 0) { dst = m == 0 ? hs_up : sks; stride = 64; off = 0; }
        else        { dst = m == 0 ? hv_up : skv; stride = 192; off = (w - 1) * 64; }
#pragma unroll
        for (int t = 0; t < 4; t++) {
            f32x4 acc = z4;
#pragma unroll
            for (int s = 0; s < 2; s++) {
                bhalf8 bh = wfv[(size_t)(mat * 16 + 0 + s * 4 + t) * 64 + lane];
                bhalf8 bl = wfv[(size_t)(mat * 16 + 8 + s * 4 + t) * 64 + lane];
                acc = __builtin_amdgcn_mfma_f32_16x16x32_bf16(Ah[s], bh, acc, 0, 0, 0);
                acc = __builtin_amdgcn_mfma_f32_16x16x32_bf16(Al[s], bh, acc, 0, 0, 0);
                acc = __builtin_amdgcn_mfma_f32_16x16x32_bf16(Ah[s], bl, acc, 0, 0, 0);
            }
#pragma unroll
            for (int r = 0; r < 4; r++)
                dst[(size_t)(nw + q * 4 + r) * stride + off + t * 16 + l15] = acc[r] * INV_F;
        }
    }
}

// K2a: radial MLP via bf16 MFMA (unchanged from R3).
__global__ __launch_bounds__(256) void k_mlp(
    const float* __restrict__ radial, const unsigned short* __restrict__ frags,
    unsigned short* __restrict__ wbuf, int e_base) {
    __shared__ unsigned short r4lds[16384];
    __shared__ unsigned short act[4][16 * 72];
    int tid = threadIdx.x;
    int lane = tid & 63, w = tid >> 6, quad = lane >> 4, l15 = lane & 15;

    const uint4* r4g = (const uint4*)(frags + 20 * 64 * 8);
    uint4* r4l = (uint4*)r4lds;
    for (int i = tid; i < 2048; i += 256) r4l[i] = r4g[i];
    const bhalf8* fr = (const bhalf8*)frags;
    bhalf8 r1f[4], r2f[2][4], r3f[2][4];
#pragma unroll
    for (int t = 0; t < 4; t++) r1f[t] = fr[t * 64 + lane];
#pragma unroll
    for (int s = 0; s < 2; s++)
#pragma unroll
        for (int t = 0; t < 4; t++) {
            r2f[s][t] = fr[(4 + s * 4 + t) * 64 + lane];
            r3f[s][t] = fr[(12 + s * 4 + t) * 64 + lane];
        }
    __syncthreads();

    const f32x4 z4 = {0.f, 0.f, 0.f, 0.f};
    const bhalf8* r4f = (const bhalf8*)r4lds;
    unsigned short* actw = act[w];

    for (int it = 0; it < 2; it++) {
        int el0 = (blockIdx.x * 2 + it) * 64 + w * 16;
        bhalf8 af = {0, 0, 0, 0, 0, 0, 0, 0};
        if (quad == 0) {
            const float* rp = radial + (size_t)(e_base + el0 + l15) * 8;
            float4 ra = *(const float4*)rp;
            float4 rb = *(const float4*)(rp + 4);
            af[0] = (short)f2bf(ra.x); af[1] = (short)f2bf(ra.y);
            af[2] = (short)f2bf(ra.z); af[3] = (short)f2bf(ra.w);
            af[4] = (short)f2bf(rb.x); af[5] = (short)f2bf(rb.y);
            af[6] = (short)f2bf(rb.z); af[7] = (short)f2bf(rb.w);
        }
        {
            f32x4 acc[4];
#pragma unroll
            for (int t = 0; t < 4; t++)
                acc[t] = __builtin_amdgcn_mfma_f32_16x16x32_bf16(af, r1f[t], z4, 0, 0, 0);
#pragma unroll
            for (int t = 0; t < 4; t++)
#pragma unroll
                for (int r = 0; r < 4; r++)
                    actw[(quad * 4 + r) * 72 + t * 16 + l15] = f2bf(silu_f(acc[t][r]));
        }
#pragma unroll
        for (int layer = 0; layer < 2; layer++) {
            bhalf8 a0 = *(const bhalf8*)&actw[l15 * 72 + 0 + quad * 8];
            bhalf8 a1 = *(const bhalf8*)&actw[l15 * 72 + 32 + quad * 8];
            f32x4 acc[4];
#pragma unroll
            for (int t = 0; t < 4; t++) {
                bhalf8 b0 = layer == 0 ? r2f[0][t] : r3f[0][t];
                bhalf8 b1 = layer == 0 ? r2f[1][t] : r3f[1][t];
                acc[t] = __builtin_amdgcn_mfma_f32_16x16x32_bf16(
                    a1, b1, __builtin_amdgcn_mfma_f32_16x16x32_bf16(a0, b0, z4, 0, 0, 0), 0, 0, 0);
            }
#pragma unroll
            for (int t = 0; t < 4; t++)
#pragma unroll
                for (int r = 0; r < 4; r++)
                    actw[(quad * 4 + r) * 72 + t * 16 + l15] = f2bf(silu_f(acc[t][r]));
        }
        {
            bhalf8 a0 = *(const bhalf8*)&actw[l15 * 72 + 0 + quad * 8];
            bhalf8 a1 = *(const bhalf8*)&actw[l15 * 72 + 32 + quad * 8];
#pragma unroll
            for (int h = 0; h < 2; h++) {
                f32x4 acc8[8];
#pragma unroll
                for (int t8 = 0; t8 < 8; t8++) {
                    int t = h * 8 + t8;
                    acc8[t8] = __builtin_amdgcn_mfma_f32_16x16x32_bf16(
                        a1, r4f[(16 + t) * 64 + lane],
                        __builtin_amdgcn_mfma_f32_16x16x32_bf16(a0, r4f[t * 64 + lane], z4, 0, 0, 0),
                        0, 0, 0);
                }
#pragma unroll
                for (int t4 = 0; t4 < 4; t4++)
#pragma unroll
                    for (int r = 0; r < 4; r++) {
                        unsigned int lo = f2bf(acc8[t4][r]);
                        unsigned int hi = f2bf(acc8[t4 + 4][r]);
                        int el = el0 + quad * 4 + r;
                        int f = t4 * 16 + l15;
                        ((unsigned int*)wbuf)[(size_t)el * 128 + f * 2 + h] = lo | (hi << 16);
                    }
            }
        }
    }
}

// K2b: CSR gather tensor product (unchanged from R4).
__global__ __launch_bounds__(256) void k_tp_gather(
    const unsigned short* __restrict__ wbuf, const int* __restrict__ csr,
    const float4* __restrict__ erec, float* __restrict__ ws,
    int z, int accum) {
    int tid = threadIdx.x, w = tid >> 6, f = tid & 63;
    int n = blockIdx.x * 4 + w;
    const float* hs_up = ws + OFF_HSUP;
    const float* hv_up = ws + OFF_HVUP;
    float* hs_mid = ws + OFF_HSMID;
    float* hv_mid = ws + OFF_HVMID;
    int pb = z ? CSR_PTR1 : CSR_PTR0;
    int beg = csr[pb + n], end = csr[pb + n + 1];
    int e_base = z * CHUNK;
    float ams = 0.f, am0 = 0.f, am1 = 0.f, am2 = 0.f;
    for (int i = beg; i < end; i++) {
        int idx = e_base + i;
        int eid = csr[CSR_SEID + idx];
        float4 rc = erec[idx];
        int sx = __float_as_int(rc.w);
        uint2 wr = ((const uint2*)wbuf)[(size_t)(eid - e_base) * 64 + f];
        float es = hs_up[sx * 64 + f];
        float e0 = hv_up[sx * 192 + f];
        float e1 = hv_up[sx * 192 + 64 + f];
        float e2 = hv_up[sx * 192 + 128 + f];
        float w0 = __uint_as_float(wr.x << 16);
        float w1 = __uint_as_float(wr.x & 0xFFFF0000u);
        float w2 = __uint_as_float(wr.y << 16);
        float w3 = __uint_as_float(wr.y & 0xFFFF0000u);
        float dot = e0 * rc.x + e1 * rc.y + e2 * rc.z;
        ams += w0 * es + w1 * dot * INV_SQRT3C;
        float t3 = w3 * es * INV_SQRT3C;
        am0 += w2 * e0 + t3 * rc.x;
        am1 += w2 * e1 + t3 * rc.y;
        am2 += w2 * e2 + t3 * rc.z;
    }
    if (!accum) {
        hs_mid[n * 64 + f] = ams;
        hv_mid[n * 192 + f] = am0;
        hv_mid[n * 192 + 64 + f] = am1;
        hv_mid[n * 192 + 128 + f] = am2;
    } else {
        hs_mid[n * 64 + f] = (hs_mid[n * 64 + f] + ams) * EPSC;
        hv_mid[n * 192 + f] = (hv_mid[n * 192 + f] + am0) * EPSC;
        hv_mid[n * 192 + 64 + f] = (hv_mid[n * 192 + 64 + f] + am1) * EPSC;
        hv_mid[n * 192 + 128 + f] = (hv_mid[n * 192 + 128 + f] + am2) * EPSC;
    }
}

// K3: linear_down + contraction + linear_sc + skip + readout via split-bf16 MFMA.
// 1 block = one 16-node tile, 4 waves: w0 scalar path, w1..3 vector component.
__global__ __launch_bounds__(256) void k_node_post(
    const int* __restrict__ counts, const unsigned short* __restrict__ wf,
    const float* __restrict__ Wr, float* __restrict__ ws, float* __restrict__ out) {
    __shared__ float T[4][16][68];
    int tid = threadIdx.x, w = tid >> 6, lane = tid & 63;
    int q = lane >> 4, l15 = lane & 15;
    int nw = blockIdx.x * 16;
    int sid = species_of(nw, counts);
    const f32x4 z4 = {0.f, 0.f, 0.f, 0.f};
    const bhalf8* wfv = (const bhalf8*)wf;
    const float* hs_mid = ws + OFF_HSMID;
    const float* hv_mid = ws + OFF_HVMID;
    const float* sks = ws + OFF_SKS;
    const float* skv = ws + OFF_SKV;
    const float* wscp = ws + OFF_WSCP;

    // Phase 1: linear_down (one row-set per wave)
    {
        const float* src = (w == 0) ? hs_mid + (size_t)nw * 64
                                    : hv_mid + (size_t)nw * 192 + (w - 1) * 64;
        int rstride = (w == 0) ? 64 : 192;
        bhalf8 Ah[2], Al[2];
#pragma unroll
        for (int s = 0; s < 2; s++) {
            const float* rp = src + (size_t)l15 * rstride + s * 32 + q * 8;
            float4 a = *(const float4*)rp, b = *(const float4*)(rp + 4);
            float x[8] = {a.x, a.y, a.z, a.w, b.x, b.y, b.z, b.w};
#pragma unroll
            for (int j = 0; j < 8; j++) { short h, l; split_f32(x[j], h, l); Ah[s][j] = h; Al[s][j] = l; }
        }
        int mat = (w == 0) ? 22 : 23;
#pragma unroll
        for (int t = 0; t < 4; t++) {
            f32x4 acc = z4;
#pragma unroll
            for (int s = 0; s < 2; s++) {
                bhalf8 bh = wfv[(size_t)(mat * 16 + 0 + s * 4 + t) * 64 + lane];
                bhalf8 bl = wfv[(size_t)(mat * 16 + 8 + s * 4 + t) * 64 + lane];
                acc = __builtin_amdgcn_mfma_f32_16x16x32_bf16(Ah[s], bh, acc, 0, 0, 0);
                acc = __builtin_amdgcn_mfma_f32_16x16x32_bf16(Al[s], bh, acc, 0, 0, 0);
                acc = __builtin_amdgcn_mfma_f32_16x16x32_bf16(Ah[s], bl, acc, 0, 0, 0);
            }
#pragma unroll
            for (int r = 0; r < 4; r++)
                T[w][q * 4 + r][t * 16 + l15] = acc[r] * INV_F;
        }
    }
    __syncthreads();

    // Phase 2: symmetric contraction, elementwise per (row, col)
    {
        int col = tid & 63, rg = tid >> 6;
        float wv[9];
#pragma unroll
        for (int b = 0; b < 9; b++) wv[b] = wscp[sid * 576 + b * 64 + col];
#pragma unroll
        for (int rr = 0; rr < 4; rr++) {
            int row = rg * 4 + rr;
            float hs = T[0][row][col];
            float h0 = T[1][row][col], h1 = T[2][row][col], h2 = T[3][row][col];
            float vv = h0 * h0 + h1 * h1 + h2 * h2;
            float cs = wv[0] * hs + wv[1] * hs * hs + wv[2] * vv
                     + wv[3] * hs * hs * hs + wv[4] * hs * vv;
            float fv = wv[5] + wv[6] * hs + wv[7] * hs * hs + wv[8] * vv;
            T[0][row][col] = cs;
            T[1][row][col] = h0 * fv;
            T[2][row][col] = h1 * fv;
            T[3][row][col] = h2 * fv;
        }
    }
    __syncthreads();

    // Phase 3: linear_sc + skip + store (+ readout on w0)
    {
        bhalf8 Ah[2], Al[2];
#pragma unroll
        for (int s = 0; s < 2; s++) {
            const float* rp = &T[w][l15][s * 32 + q * 8];
            float4 a = *(const float4*)rp, b = *(const float4*)(rp + 4);
            float x[8] = {a.x, a.y, a.z, a.w, b.x, b.y, b.z, b.w};
#pragma unroll
            for (int j = 0; j < 8; j++) { short h, l; split_f32(x[j], h, l); Ah[s][j] = h; Al[s][j] = l; }
        }
        int mat = (w == 0) ? 24 : 25;
        float* d_hs = out + N_NODES;
        float* d_hv = out + N_NODES + N_NODES * 64;
        float p[4] = {0.f, 0.f, 0.f, 0.f};
#pragma unroll
        for (int t = 0; t < 4; t++) {
            f32x4 acc = z4;
#pragma unroll
            for (int s = 0; s < 2; s++) {
                bhalf8 bh = wfv[(size_t)(mat * 16 + 0 + s * 4 + t) * 64 + lane];
                bhalf8 bl = wfv[(size_t)(mat * 16 + 8 + s * 4 + t) * 64 + lane];
                acc = __builtin_amdgcn_mfma_f32_16x16x32_bf16(Ah[s], bh, acc, 0, 0, 0);
                acc = __builtin_amdgcn_mfma_f32_16x16x32_bf16(Al[s], bh, acc, 0, 0, 0);
                acc = __builtin_amdgcn_mfma_f32_16x16x32_bf16(Ah[s], bl, acc, 0, 0, 0);
            }
            int col = t * 16 + l15;
            if (w == 0) {
                float wr = Wr[col];
#pragma unroll
                for (int r = 0; r < 4; r++) {
                    int gn = nw + q * 4 + r;
                    float v = acc[r] * INV_F + sks[(size_t)gn * 64 + col];
                    d_hs[(size_t)gn * 64 + col] = v;
                    p[r] += v * wr;
                }
            } else {
                int i = w - 1;
#pragma unroll
                for (int r = 0; r < 4; r++) {
                    int gn = nw + q * 4 + r;
                    float v = acc[r] * INV_F + skv[(size_t)gn * 192 + i * 64 + col];
                    d_hv[(size_t)gn * 192 + col * 3 + i] = v;
                }
            }
        }
        if (w == 0) {
#pragma unroll
            for (int r = 0; r < 4; r++) {
#pragma unroll
                for (int off = 1; off < 16; off <<= 1) p[r] += __shfl_xor(p[r], off, 64);
                if (l15 == 0) out[nw + q * 4 + r] = p[r] * INV_F;
            }
        }
    }
}

extern "C" void kernel_launch(void* const* d_in, const int* in_sizes, int n_in,
                              void* d_out, int out_size, void* d_ws, size_t ws_size,
                              hipStream_t stream) {
    const float* vectors   = (const float*)d_in[0];
    const float* node_s    = (const float*)d_in[1];
    const float* node_v    = (const float*)d_in[2];
    const float* radial    = (const float*)d_in[3];
    const int*   senders   = (const int*)d_in[4];
    const int*   receivers = (const int*)d_in[5];
    const int*   counts    = (const int*)d_in[6];
    const float* Wup0 = (const float*)d_in[7];
    const float* Wup1 = (const float*)d_in[8];
    const float* R1   = (const float*)d_in[9];
    const float* R2   = (const float*)d_in[10];
    const float* R3   = (const float*)d_in[11];
    const float* R4   = (const float*)d_in[12];
    const float* Wd0  = (const float*)d_in[13];
    const float* Wd1  = (const float*)d_in[14];
    const float* Ws0  = (const float*)d_in[15];
    const float* Ws1  = (const float*)d_in[16];
    const float* Wsc  = (const float*)d_in[17];
    const float* Proj = (const float*)d_in[18];
    const float* Wl0  = (const float*)d_in[19];
    const float* Wl1  = (const float*)d_in[20];
    const float* Wr   = (const float*)d_in[21];
    float* ws  = (float*)d_ws;
    float* out = (float*)d_out;
    unsigned short* frags = (unsigned short*)(ws + OFF_FRAGS);
    unsigned short* wbuf  = (unsigned short*)(ws + OFF_WBUF);
    float4* erec = (float4*)(ws + OFF_CSR);
    int* csr = (int*)(ws + OFF_CSR + 2 * CHUNK * 4);
    unsigned short* wf = (unsigned short*)(ws + OFF_WF);

    hipMemsetAsync(csr, 0, 2 * N_NODES * sizeof(int), stream);
    k_wscproj<<<ZSP, 576, 0, stream>>>(Wsc, Proj, ws + OFF_WSCP);
    k_prep<<<13, 256, 0, stream>>>(R1, R2, R3, R4, frags);
    k_prep2<<<104, 256, 0, stream>>>(Wup0, Wup1, Ws0, Ws1, Wd0, Wd1, Wl0, Wl1, wf);
    k_hist<<<E_EDGES / 256, 256, 0, stream>>>(receivers, csr);
    k_scan<<<2, 256, 0, stream>>>(csr);
    k_node_pre<<<N_NODES / 16, 256, 0, stream>>>(node_s, node_v, counts, wf, ws);
    k_bucket<<<E_EDGES / 256, 256, 0, stream>>>(vectors, senders, receivers, csr, erec);
    for (int c = 0; c < 2; c++) {
        k_mlp<<<1250, 256, 0, stream>>>(radial, frags, wbuf, c * CHUNK);
        k_tp_gather<<<N_NODES / 4, 256, 0, stream>>>(wbuf, csr, erec, ws, c, c);
    }
    k_node_post<<<N_NODES / 16, 256, 0, stream>>>(counts, wf, Wr, ws, out);
}

// Round 6
// 370.709 us; speedup vs baseline: 2.0676x; 1.2183x over previous
//
#include <hip/hip_runtime.h>
#include <math.h>

#define N_NODES 20000
#define FCH 64
#define ZSP 10
#define E_EDGES 320000
#define CHUNK 160000
#define RDIM 8
#define EPSC 0.25f
#define SQRT3C 1.7320508075688772f
#define INV_SQRT3C 0.57735026918962576f
#define INV_F 0.125f  /* 1/sqrt(64) */

// ---- workspace layout (float offsets) ----
#define OFF_HSUP   0                               // (N,64)
#define OFF_HVUP   (N_NODES*64)                    // (N,3,64) planar
#define OFF_SKS    (OFF_HVUP + N_NODES*192)        // (N,64)
#define OFF_SKV    (OFF_SKS + N_NODES*64)          // (N,3,64) planar
#define OFF_HSMID  (OFF_SKV + N_NODES*192)         // (N,64)
#define OFF_HVMID  (OFF_HSMID + N_NODES*64)        // (N,3,64) planar
#define OFF_WSCP   (OFF_HVMID + N_NODES*192)       // (Z,9,64)
#define OFF_FRAGS  (OFF_WSCP + ZSP*576)            // 3328*8 ushort = 13312 floats
#define OFF_WBUF   (OFF_FRAGS + 13312)             // CHUNK*256 ushort = CHUNK*128 floats
#define OFF_CSR    (OFF_WBUF + CHUNK*128)          // erec float4[2*CHUNK], then ints
#define OFF_WF     (OFF_CSR + 2*CHUNK*4 + 400260)  // 416 slots * 512 ushort
// ints relative to csr int base (after erec):
#define CSR_CNT0   0
#define CSR_CNT1   20000
#define CSR_PTR0   40000
#define CSR_PTR1   60001
#define CSR_SEID   80002
#define CSR_AUX    400002   /* 2*128 block totals */

typedef __attribute__((ext_vector_type(8))) short bhalf8;
typedef __attribute__((ext_vector_type(4))) float f32x4;

__device__ __forceinline__ float silu_f(float x) {
    return x / (1.0f + expf(-x));
}

__device__ __forceinline__ unsigned short f2bf(float x) {
    unsigned int u = __float_as_uint(x);
    unsigned int r = u + 0x7FFFu + ((u >> 16) & 1u);   // RNE
    return (unsigned short)(r >> 16);
}

// split fp32 -> bf16 hi (trunc) + bf16 lo (trunc of residual); err ~2^-16 rel
__device__ __forceinline__ void split_f32(float x, short& h, short& l) {
    unsigned int u = __float_as_uint(x);
    unsigned int hb = u & 0xFFFF0000u;
    h = (short)(u >> 16);
    float r = x - __uint_as_float(hb);
    l = (short)(__float_as_uint(r) >> 16);
}

__device__ __forceinline__ int species_of(int n, const int* counts) {
    int acc = 0, s = ZSP - 1;
#pragma unroll
    for (int z = 0; z < ZSP; z++) {
        int c = counts[z];
        if (n >= acc && n < acc + c) s = z;
        acc += c;
    }
    return s;
}

// K0: wscp[z][b][u] = sum_p Wsc[z][p][u] * Proj[p][b]
__global__ void k_wscproj(const float* __restrict__ Wsc, const float* __restrict__ Proj,
                          float* __restrict__ wscp) {
    int z = blockIdx.x, t = threadIdx.x;
    if (t < 9 * 64) {
        int b = t >> 6, u = t & 63;
        float acc = 0.f;
#pragma unroll
        for (int p = 0; p < 9; p++) acc += Wsc[z * 576 + p * 64 + u] * Proj[p * 9 + b];
        wscp[z * 576 + b * 64 + u] = acc;
    }
}

// K-prep: bf16 MFMA B-fragments for R1(zero-pad K8->32), R2, R3, R4 (MLP path).
__global__ void k_prep(const float* __restrict__ R1, const float* __restrict__ R2,
                       const float* __restrict__ R3, const float* __restrict__ R4,
                       unsigned short* __restrict__ frags) {
    int id = blockIdx.x * 256 + threadIdx.x;
    if (id >= 3328) return;
    int lane = id & 63, fi = id >> 6;
    int quad = lane >> 4, l15 = lane & 15;
    const float* W;
    int s, t, N;
    bool r1 = false;
    if (fi < 4)       { W = R1; s = 0; t = fi; N = 64; r1 = true; }
    else if (fi < 12) { W = R2; int x = fi - 4;  s = x >> 2; t = x & 3;  N = 64; }
    else if (fi < 20) { W = R3; int x = fi - 12; s = x >> 2; t = x & 3;  N = 64; }
    else              { W = R4; int x = fi - 20; s = x >> 4; t = x & 15; N = 256; }
    unsigned int v[4];
#pragma unroll
    for (int jj = 0; jj < 4; jj++) {
        unsigned short lo, hi;
        {
            int j = jj * 2;
            int k = s * 32 + quad * 8 + j, n = t * 16 + l15;
            float val = (r1 && k >= RDIM) ? 0.f : W[k * N + n];
            lo = f2bf(val);
        }
        {
            int j = jj * 2 + 1;
            int k = s * 32 + quad * 8 + j, n = t * 16 + l15;
            float val = (r1 && k >= RDIM) ? 0.f : W[k * N + n];
            hi = f2bf(val);
        }
        v[jj] = (unsigned int)lo | ((unsigned int)hi << 16);
    }
    uint4 pk; pk.x = v[0]; pk.y = v[1]; pk.z = v[2]; pk.w = v[3];
    ((uint4*)frags)[id] = pk;
}

// K-prep2: split-bf16 (hi/lo) B-fragments for the 26 node-side 64x64 matrices.
__global__ void k_prep2(const float* __restrict__ Wup0, const float* __restrict__ Wup1,
                        const float* __restrict__ Ws0, const float* __restrict__ Ws1,
                        const float* __restrict__ Wd0, const float* __restrict__ Wd1,
                        const float* __restrict__ Wl0, const float* __restrict__ Wl1,
                        unsigned short* __restrict__ wf) {
    int id = blockIdx.x * 256 + threadIdx.x;
    if (id >= 416 * 64) return;
    int lane = id & 63, slot = id >> 6;
    int t = slot & 3, s = (slot >> 2) & 1, part = (slot >> 3) & 1, mat = slot >> 4;
    int quad = lane >> 4, l15 = lane & 15;
    const float* W;
    if (mat == 0)       W = Wup0;
    else if (mat == 1)  W = Wup1;
    else if (mat < 12)  W = Ws0 + (mat - 2) * 4096;
    else if (mat < 22)  W = Ws1 + (mat - 12) * 4096;
    else if (mat == 22) W = Wd0;
    else if (mat == 23) W = Wd1;
    else if (mat == 24) W = Wl0;
    else                W = Wl1;
    unsigned int v[4];
#pragma unroll
    for (int jj = 0; jj < 4; jj++) {
        unsigned short pk2[2];
#pragma unroll
        for (int o = 0; o < 2; o++) {
            int j = jj * 2 + o;
            int k = s * 32 + quad * 8 + j, n = t * 16 + l15;
            float x = W[k * 64 + n];
            short h, l;
            split_f32(x, h, l);
            pk2[o] = part == 0 ? (unsigned short)h : (unsigned short)l;
        }
        v[jj] = (unsigned int)pk2[0] | ((unsigned int)pk2[1] << 16);
    }
    uint4 pk; pk.x = v[0]; pk.y = v[1]; pk.z = v[2]; pk.w = v[3];
    ((uint4*)wf)[id] = pk;
}

// CSR build: histogram of receivers per chunk
__global__ __launch_bounds__(256) void k_hist(const int* __restrict__ receivers,
                                              int* __restrict__ csr) {
    int e = blockIdx.x * 256 + threadIdx.x;
    if (e < E_EDGES) {
        int base = (e < CHUNK) ? CSR_CNT0 : CSR_CNT1;
        atomicAdd(&csr[base + receivers[e]], 1);
    }
}

// 3-phase parallel scan. Phase 1: per-block (256) exclusive scan + block total.
__global__ __launch_bounds__(256) void k_scan1(int* __restrict__ csr) {
    __shared__ int sb[256];
    int z = blockIdx.y, b = blockIdx.x, t = threadIdx.x;
    int i = b * 256 + t;
    int cb = z ? CSR_CNT1 : CSR_CNT0;
    int pb = z ? CSR_PTR1 : CSR_PTR0;
    int x = (i < N_NODES) ? csr[cb + i] : 0;
    sb[t] = x;
    __syncthreads();
#pragma unroll
    for (int off = 1; off < 256; off <<= 1) {
        int v = (t >= off) ? sb[t - off] : 0;
        __syncthreads();
        sb[t] += v;
        __syncthreads();
    }
    if (i < N_NODES) csr[pb + i] = sb[t] - x;      // block-local exclusive
    if (t == 255) csr[CSR_AUX + z * 128 + b] = sb[255];
}

// Phase 2: scan the 79 block totals per chunk (one block of 128 per chunk).
__global__ __launch_bounds__(128) void k_scan2(int* __restrict__ csr) {
    __shared__ int sb[128];
    int z = blockIdx.x, t = threadIdx.x;
    int pb = z ? CSR_PTR1 : CSR_PTR0;
    int x = (t < 79) ? csr[CSR_AUX + z * 128 + t] : 0;
    sb[t] = x;
    __syncthreads();
#pragma unroll
    for (int off = 1; off < 128; off <<= 1) {
        int v = (t >= off) ? sb[t - off] : 0;
        __syncthreads();
        sb[t] += v;
        __syncthreads();
    }
    csr[CSR_AUX + z * 128 + t] = sb[t] - x;
    if (t == 127) csr[pb + N_NODES] = sb[127];
}

// Phase 3: add block offsets; write final ptr and cursor.
__global__ __launch_bounds__(256) void k_scan3(int* __restrict__ csr) {
    int z = blockIdx.y, b = blockIdx.x, t = threadIdx.x;
    int i = b * 256 + t;
    if (i >= N_NODES) return;
    int cb = z ? CSR_CNT1 : CSR_CNT0;
    int pb = z ? CSR_PTR1 : CSR_PTR0;
    int v = csr[pb + i] + csr[CSR_AUX + z * 128 + b];
    csr[pb + i] = v;
    csr[cb + i] = v;   // cursor for bucketing
}

// CSR build: bucket edges; precompute Y1 + sender per slot.
__global__ __launch_bounds__(256) void k_bucket(
    const float* __restrict__ vectors, const int* __restrict__ senders,
    const int* __restrict__ receivers, int* __restrict__ csr,
    float4* __restrict__ erec) {
    int e = blockIdx.x * 256 + threadIdx.x;
    if (e >= E_EDGES) return;
    int z = (e < CHUNK) ? 0 : 1;
    int base = z ? CSR_CNT1 : CSR_CNT0;
    int pos = atomicAdd(&csr[base + receivers[e]], 1);
    float v0 = vectors[e * 3 + 0], v1 = vectors[e * 3 + 1], v2 = vectors[e * 3 + 2];
    float s = SQRT3C * rsqrtf(v0 * v0 + v1 * v1 + v2 * v2);
    int idx = z * CHUNK + pos;
    csr[CSR_SEID + idx] = e;
    float4 r;
    r.x = v0 * s; r.y = v1 * s; r.z = v2 * s; r.w = __int_as_float(senders[e]);
    erec[idx] = r;
}

// K1: linear_up + species skip via split-bf16 MFMA.
__global__ __launch_bounds__(256) void k_node_pre(
    const float* __restrict__ ns, const float* __restrict__ nv,
    const int* __restrict__ counts, const unsigned short* __restrict__ wf,
    float* __restrict__ ws) {
    int tid = threadIdx.x, w = tid >> 6, lane = tid & 63;
    int q = lane >> 4, l15 = lane & 15;
    int nw = blockIdx.x * 16;
    int sid = species_of(nw, counts);
    const f32x4 z4 = {0.f, 0.f, 0.f, 0.f};

    bhalf8 Ah[2], Al[2];
    if (w == 0) {
#pragma unroll
        for (int s = 0; s < 2; s++) {
            const float* rp = ns + (size_t)(nw + l15) * 64 + s * 32 + q * 8;
            float4 a = *(const float4*)rp, b = *(const float4*)(rp + 4);
            float x[8] = {a.x, a.y, a.z, a.w, b.x, b.y, b.z, b.w};
#pragma unroll
            for (int j = 0; j < 8; j++) { short h, l; split_f32(x[j], h, l); Ah[s][j] = h; Al[s][j] = l; }
        }
    } else {
        int i = w - 1;
#pragma unroll
        for (int s = 0; s < 2; s++) {
            const float* rp = nv + (size_t)(nw + l15) * 192 + i;
#pragma unroll
            for (int j = 0; j < 8; j++) {
                float x = rp[(s * 32 + q * 8 + j) * 3];
                short h, l; split_f32(x, h, l); Ah[s][j] = h; Al[s][j] = l;
            }
        }
    }

    const bhalf8* wfv = (const bhalf8*)wf;
    float* hs_up = ws + OFF_HSUP;
    float* hv_up = ws + OFF_HVUP;
    float* sks   = ws + OFF_SKS;
    float* skv   = ws + OFF_SKV;

#pragma unroll
    for (int m = 0; m < 2; m++) {
        int mat = (w == 0) ? (m == 0 ? 0 : 2 + sid) : (m == 0 ? 1 : 12 + sid);
        float* dst; int stride, off;
        if (w == 0) { dst = m == 0 ? hs_up : sks; stride = 64; off = 0; }
        else        { dst = m == 0 ? hv_up : skv; stride = 192; off = (w - 1) * 64; }
#pragma unroll
        for (int t = 0; t < 4; t++) {
            f32x4 acc = z4;
#pragma unroll
            for (int s = 0; s < 2; s++) {
                bhalf8 bh = wfv[(size_t)(mat * 16 + 0 + s * 4 + t) * 64 + lane];
                bhalf8 bl = wfv[(size_t)(mat * 16 + 8 + s * 4 + t) * 64 + lane];
                acc = __builtin_amdgcn_mfma_f32_16x16x32_bf16(Ah[s], bh, acc, 0, 0, 0);
                acc = __builtin_amdgcn_mfma_f32_16x16x32_bf16(Al[s], bh, acc, 0, 0, 0);
                acc = __builtin_amdgcn_mfma_f32_16x16x32_bf16(Ah[s], bl, acc, 0, 0, 0);
            }
#pragma unroll
            for (int r = 0; r < 4; r++)
                dst[(size_t)(nw + q * 4 + r) * stride + off + t * 16 + l15] = acc[r] * INV_F;
        }
    }
}

// K2a: radial MLP via bf16 MFMA, processing edges in CSR-SORTED slot order.
// Radial rows gathered via seid (5 MB L2-resident); wbuf written sequentially
// in sorted-slot order so k_tp_gather streams it.
__global__ __launch_bounds__(256) void k_mlp(
    const float* __restrict__ radial, const unsigned short* __restrict__ frags,
    const int* __restrict__ csr, unsigned short* __restrict__ wbuf, int e_base) {
    __shared__ unsigned short r4lds[16384];
    __shared__ unsigned short act[4][16 * 72];
    int tid = threadIdx.x;
    int lane = tid & 63, w = tid >> 6, quad = lane >> 4, l15 = lane & 15;

    const uint4* r4g = (const uint4*)(frags + 20 * 64 * 8);
    uint4* r4l = (uint4*)r4lds;
    for (int i = tid; i < 2048; i += 256) r4l[i] = r4g[i];
    const bhalf8* fr = (const bhalf8*)frags;
    bhalf8 r1f[4], r2f[2][4], r3f[2][4];
#pragma unroll
    for (int t = 0; t < 4; t++) r1f[t] = fr[t * 64 + lane];
#pragma unroll
    for (int s = 0; s < 2; s++)
#pragma unroll
        for (int t = 0; t < 4; t++) {
            r2f[s][t] = fr[(4 + s * 4 + t) * 64 + lane];
            r3f[s][t] = fr[(12 + s * 4 + t) * 64 + lane];
        }
    __syncthreads();

    const f32x4 z4 = {0.f, 0.f, 0.f, 0.f};
    const bhalf8* r4f = (const bhalf8*)r4lds;
    unsigned short* actw = act[w];

    for (int it = 0; it < 2; it++) {
        int el0 = (blockIdx.x * 2 + it) * 64 + w * 16;   // chunk-local sorted slot base
        bhalf8 af = {0, 0, 0, 0, 0, 0, 0, 0};
        if (quad == 0) {
            int eid = csr[CSR_SEID + e_base + el0 + l15];  // global edge id
            const float* rp = radial + (size_t)eid * 8;
            float4 ra = *(const float4*)rp;
            float4 rb = *(const float4*)(rp + 4);
            af[0] = (short)f2bf(ra.x); af[1] = (short)f2bf(ra.y);
            af[2] = (short)f2bf(ra.z); af[3] = (short)f2bf(ra.w);
            af[4] = (short)f2bf(rb.x); af[5] = (short)f2bf(rb.y);
            af[6] = (short)f2bf(rb.z); af[7] = (short)f2bf(rb.w);
        }
        {
            f32x4 acc[4];
#pragma unroll
            for (int t = 0; t < 4; t++)
                acc[t] = __builtin_amdgcn_mfma_f32_16x16x32_bf16(af, r1f[t], z4, 0, 0, 0);
#pragma unroll
            for (int t = 0; t < 4; t++)
#pragma unroll
                for (int r = 0; r < 4; r++)
                    actw[(quad * 4 + r) * 72 + t * 16 + l15] = f2bf(silu_f(acc[t][r]));
        }
#pragma unroll
        for (int layer = 0; layer < 2; layer++) {
            bhalf8 a0 = *(const bhalf8*)&actw[l15 * 72 + 0 + quad * 8];
            bhalf8 a1 = *(const bhalf8*)&actw[l15 * 72 + 32 + quad * 8];
            f32x4 acc[4];
#pragma unroll
            for (int t = 0; t < 4; t++) {
                bhalf8 b0 = layer == 0 ? r2f[0][t] : r3f[0][t];
                bhalf8 b1 = layer == 0 ? r2f[1][t] : r3f[1][t];
                acc[t] = __builtin_amdgcn_mfma_f32_16x16x32_bf16(
                    a1, b1, __builtin_amdgcn_mfma_f32_16x16x32_bf16(a0, b0, z4, 0, 0, 0), 0, 0, 0);
            }
#pragma unroll
            for (int t = 0; t < 4; t++)
#pragma unroll
                for (int r = 0; r < 4; r++)
                    actw[(quad * 4 + r) * 72 + t * 16 + l15] = f2bf(silu_f(acc[t][r]));
        }
        {
            bhalf8 a0 = *(const bhalf8*)&actw[l15 * 72 + 0 + quad * 8];
            bhalf8 a1 = *(const bhalf8*)&actw[l15 * 72 + 32 + quad * 8];
#pragma unroll
            for (int h = 0; h < 2; h++) {
                f32x4 acc8[8];
#pragma unroll
                for (int t8 = 0; t8 < 8; t8++) {
                    int t = h * 8 + t8;
                    acc8[t8] = __builtin_amdgcn_mfma_f32_16x16x32_bf16(
                        a1, r4f[(16 + t) * 64 + lane],
                        __builtin_amdgcn_mfma_f32_16x16x32_bf16(a0, r4f[t * 64 + lane], z4, 0, 0, 0),
                        0, 0, 0);
                }
#pragma unroll
                for (int t4 = 0; t4 < 4; t4++)
#pragma unroll
                    for (int r = 0; r < 4; r++) {
                        unsigned int lo = f2bf(acc8[t4][r]);
                        unsigned int hi = f2bf(acc8[t4 + 4][r]);
                        int el = el0 + quad * 4 + r;
                        int f = t4 * 16 + l15;
                        ((unsigned int*)wbuf)[(size_t)el * 128 + f * 2 + h] = lo | (hi << 16);
                    }
            }
        }
    }
}

// K2b: CSR gather tensor product; wbuf is in sorted-slot order -> streamed.
__global__ __launch_bounds__(256) void k_tp_gather(
    const unsigned short* __restrict__ wbuf, const int* __restrict__ csr,
    const float4* __restrict__ erec, float* __restrict__ ws,
    int z, int accum) {
    int tid = threadIdx.x, w = tid >> 6, f = tid & 63;
    int n = blockIdx.x * 4 + w;
    const float* hs_up = ws + OFF_HSUP;
    const float* hv_up = ws + OFF_HVUP;
    float* hs_mid = ws + OFF_HSMID;
    float* hv_mid = ws + OFF_HVMID;
    int pb = z ? CSR_PTR1 : CSR_PTR0;
    int beg = csr[pb + n], end = csr[pb + n + 1];
    int e_base = z * CHUNK;
    float ams = 0.f, am0 = 0.f, am1 = 0.f, am2 = 0.f;
    for (int i = beg; i < end; i++) {
        int idx = e_base + i;
        float4 rc = erec[idx];
        int sx = __float_as_int(rc.w);
        uint2 wr = ((const uint2*)wbuf)[(size_t)i * 64 + f];
        float es = hs_up[sx * 64 + f];
        float e0 = hv_up[sx * 192 + f];
        float e1 = hv_up[sx * 192 + 64 + f];
        float e2 = hv_up[sx * 192 + 128 + f];
        float w0 = __uint_as_float(wr.x << 16);
        float w1 = __uint_as_float(wr.x & 0xFFFF0000u);
        float w2 = __uint_as_float(wr.y << 16);
        float w3 = __uint_as_float(wr.y & 0xFFFF0000u);
        float dot = e0 * rc.x + e1 * rc.y + e2 * rc.z;
        ams += w0 * es + w1 * dot * INV_SQRT3C;
        float t3 = w3 * es * INV_SQRT3C;
        am0 += w2 * e0 + t3 * rc.x;
        am1 += w2 * e1 + t3 * rc.y;
        am2 += w2 * e2 + t3 * rc.z;
    }
    if (!accum) {
        hs_mid[n * 64 + f] = ams;
        hv_mid[n * 192 + f] = am0;
        hv_mid[n * 192 + 64 + f] = am1;
        hv_mid[n * 192 + 128 + f] = am2;
    } else {
        hs_mid[n * 64 + f] = (hs_mid[n * 64 + f] + ams) * EPSC;
        hv_mid[n * 192 + f] = (hv_mid[n * 192 + f] + am0) * EPSC;
        hv_mid[n * 192 + 64 + f] = (hv_mid[n * 192 + 64 + f] + am1) * EPSC;
        hv_mid[n * 192 + 128 + f] = (hv_mid[n * 192 + 128 + f] + am2) * EPSC;
    }
}

// K3: linear_down + contraction + linear_sc + skip + readout via split-bf16 MFMA.
__global__ __launch_bounds__(256) void k_node_post(
    const int* __restrict__ counts, const unsigned short* __restrict__ wf,
    const float* __restrict__ Wr, float* __restrict__ ws, float* __restrict__ out) {
    __shared__ float T[4][16][68];
    int tid = threadIdx.x, w = tid >> 6, lane = tid & 63;
    int q = lane >> 4, l15 = lane & 15;
    int nw = blockIdx.x * 16;
    int sid = species_of(nw, counts);
    const f32x4 z4 = {0.f, 0.f, 0.f, 0.f};
    const bhalf8* wfv = (const bhalf8*)wf;
    const float* hs_mid = ws + OFF_HSMID;
    const float* hv_mid = ws + OFF_HVMID;
    const float* sks = ws + OFF_SKS;
    const float* skv = ws + OFF_SKV;
    const float* wscp = ws + OFF_WSCP;

    // Phase 1: linear_down
    {
        const float* src = (w == 0) ? hs_mid + (size_t)nw * 64
                                    : hv_mid + (size_t)nw * 192 + (w - 1) * 64;
        int rstride = (w == 0) ? 64 : 192;
        bhalf8 Ah[2], Al[2];
#pragma unroll
        for (int s = 0; s < 2; s++) {
            const float* rp = src + (size_t)l15 * rstride + s * 32 + q * 8;
            float4 a = *(const float4*)rp, b = *(const float4*)(rp + 4);
            float x[8] = {a.x, a.y, a.z, a.w, b.x, b.y, b.z, b.w};
#pragma unroll
            for (int j = 0; j < 8; j++) { short h, l; split_f32(x[j], h, l); Ah[s][j] = h; Al[s][j] = l; }
        }
        int mat = (w == 0) ? 22 : 23;
#pragma unroll
        for (int t = 0; t < 4; t++) {
            f32x4 acc = z4;
#pragma unroll
            for (int s = 0; s < 2; s++) {
                bhalf8 bh = wfv[(size_t)(mat * 16 + 0 + s * 4 + t) * 64 + lane];
                bhalf8 bl = wfv[(size_t)(mat * 16 + 8 + s * 4 + t) * 64 + lane];
                acc = __builtin_amdgcn_mfma_f32_16x16x32_bf16(Ah[s], bh, acc, 0, 0, 0);
                acc = __builtin_amdgcn_mfma_f32_16x16x32_bf16(Al[s], bh, acc, 0, 0, 0);
                acc = __builtin_amdgcn_mfma_f32_16x16x32_bf16(Ah[s], bl, acc, 0, 0, 0);
            }
#pragma unroll
            for (int r = 0; r < 4; r++)
                T[w][q * 4 + r][t * 16 + l15] = acc[r] * INV_F;
        }
    }
    __syncthreads();

    // Phase 2: symmetric contraction
    {
        int col = tid & 63, rg = tid >> 6;
        float wv[9];
#pragma unroll
        for (int b = 0; b < 9; b++) wv[b] = wscp[sid * 576 + b * 64 + col];
#pragma unroll
        for (int rr = 0; rr < 4; rr++) {
            int row = rg * 4 + rr;
            float hs = T[0][row][col];
            float h0 = T[1][row][col], h1 = T[2][row][col], h2 = T[3][row][col];
            float vv = h0 * h0 + h1 * h1 + h2 * h2;
            float cs = wv[0] * hs + wv[1] * hs * hs + wv[2] * vv
                     + wv[3] * hs * hs * hs + wv[4] * hs * vv;
            float fv = wv[5] + wv[6] * hs + wv[7] * hs * hs + wv[8] * vv;
            T[0][row][col] = cs;
            T[1][row][col] = h0 * fv;
            T[2][row][col] = h1 * fv;
            T[3][row][col] = h2 * fv;
        }
    }
    __syncthreads();

    // Phase 3: linear_sc + skip + store (+ readout on w0)
    {
        bhalf8 Ah[2], Al[2];
#pragma unroll
        for (int s = 0; s < 2; s++) {
            const float* rp = &T[w][l15][s * 32 + q * 8];
            float4 a = *(const float4*)rp, b = *(const float4*)(rp + 4);
            float x[8] = {a.x, a.y, a.z, a.w, b.x, b.y, b.z, b.w};
#pragma unroll
            for (int j = 0; j < 8; j++) { short h, l; split_f32(x[j], h, l); Ah[s][j] = h; Al[s][j] = l; }
        }
        int mat = (w == 0) ? 24 : 25;
        float* d_hs = out + N_NODES;
        float* d_hv = out + N_NODES + N_NODES * 64;
        float p[4] = {0.f, 0.f, 0.f, 0.f};
#pragma unroll
        for (int t = 0; t < 4; t++) {
            f32x4 acc = z4;
#pragma unroll
            for (int s = 0; s < 2; s++) {
                bhalf8 bh = wfv[(size_t)(mat * 16 + 0 + s * 4 + t) * 64 + lane];
                bhalf8 bl = wfv[(size_t)(mat * 16 + 8 + s * 4 + t) * 64 + lane];
                acc = __builtin_amdgcn_mfma_f32_16x16x32_bf16(Ah[s], bh, acc, 0, 0, 0);
                acc = __builtin_amdgcn_mfma_f32_16x16x32_bf16(Al[s], bh, acc, 0, 0, 0);
                acc = __builtin_amdgcn_mfma_f32_16x16x32_bf16(Ah[s], bl, acc, 0, 0, 0);
            }
            int col = t * 16 + l15;
            if (w == 0) {
                float wr = Wr[col];
#pragma unroll
                for (int r = 0; r < 4; r++) {
                    int gn = nw + q * 4 + r;
                    float v = acc[r] * INV_F + sks[(size_t)gn * 64 + col];
                    d_hs[(size_t)gn * 64 + col] = v;
                    p[r] += v * wr;
                }
            } else {
                int i = w - 1;
#pragma unroll
                for (int r = 0; r < 4; r++) {
                    int gn = nw + q * 4 + r;
                    float v = acc[r] * INV_F + skv[(size_t)gn * 192 + i * 64 + col];
                    d_hv[(size_t)gn * 192 + col * 3 + i] = v;
                }
            }
        }
        if (w == 0) {
#pragma unroll
            for (int r = 0; r < 4; r++) {
#pragma unroll
                for (int off = 1; off < 16; off <<= 1) p[r] += __shfl_xor(p[r], off, 64);
                if (l15 == 0) out[nw + q * 4 + r] = p[r] * INV_F;
            }
        }
    }
}

extern "C" void kernel_launch(void* const* d_in, const int* in_sizes, int n_in,
                              void* d_out, int out_size, void* d_ws, size_t ws_size,
                              hipStream_t stream) {
    const float* vectors   = (const float*)d_in[0];
    const float* node_s    = (const float*)d_in[1];
    const float* node_v    = (const float*)d_in[2];
    const float* radial    = (const float*)d_in[3];
    const int*   senders   = (const int*)d_in[4];
    const int*   receivers = (const int*)d_in[5];
    const int*   counts    = (const int*)d_in[6];
    const float* Wup0 = (const float*)d_in[7];
    const float* Wup1 = (const float*)d_in[8];
    const float* R1   = (const float*)d_in[9];
    const float* R2   = (const float*)d_in[10];
    const float* R3   = (const float*)d_in[11];
    const float* R4   = (const float*)d_in[12];
    const float* Wd0  = (const float*)d_in[13];
    const float* Wd1  = (const float*)d_in[14];
    const float* Ws0  = (const float*)d_in[15];
    const float* Ws1  = (const float*)d_in[16];
    const float* Wsc  = (const float*)d_in[17];
    const float* Proj = (const float*)d_in[18];
    const float* Wl0  = (const float*)d_in[19];
    const float* Wl1  = (const float*)d_in[20];
    const float* Wr   = (const float*)d_in[21];
    float* ws  = (float*)d_ws;
    float* out = (float*)d_out;
    unsigned short* frags = (unsigned short*)(ws + OFF_FRAGS);
    unsigned short* wbuf  = (unsigned short*)(ws + OFF_WBUF);
    float4* erec = (float4*)(ws + OFF_CSR);
    int* csr = (int*)(ws + OFF_CSR + 2 * CHUNK * 4);
    unsigned short* wf = (unsigned short*)(ws + OFF_WF);

    hipMemsetAsync(csr, 0, 2 * N_NODES * sizeof(int), stream);
    k_wscproj<<<ZSP, 576, 0, stream>>>(Wsc, Proj, ws + OFF_WSCP);
    k_prep<<<13, 256, 0, stream>>>(R1, R2, R3, R4, frags);
    k_prep2<<<104, 256, 0, stream>>>(Wup0, Wup1, Ws0, Ws1, Wd0, Wd1, Wl0, Wl1, wf);
    k_hist<<<E_EDGES / 256, 256, 0, stream>>>(receivers, csr);
    k_scan1<<<dim3(79, 2), 256, 0, stream>>>(csr);
    k_scan2<<<2, 128, 0, stream>>>(csr);
    k_scan3<<<dim3(79, 2), 256, 0, stream>>>(csr);
    k_bucket<<<E_EDGES / 256, 256, 0, stream>>>(vectors, senders, receivers, csr, erec);
    k_node_pre<<<N_NODES / 16, 256, 0, stream>>>(node_s, node_v, counts, wf, ws);
    for (int c = 0; c < 2; c++) {
        k_mlp<<<1250, 256, 0, stream>>>(radial, frags, csr, wbuf, c * CHUNK);
        k_tp_gather<<<N_NODES / 4, 256, 0, stream>>>(wbuf, csr, erec, ws, c, c);
    }
    k_node_post<<<N_NODES / 16, 256, 0, stream>>>(counts, wf, Wr, ws, out);
}

// Round 7
// 349.059 us; speedup vs baseline: 2.1958x; 1.0620x over previous
//
#include <hip/hip_runtime.h>
#include <hip/hip_bf16.h>
#include <math.h>

#define N_NODES 20000
#define FCH 64
#define ZSP 10
#define E_EDGES 320000
#define CHUNK 160000
#define RDIM 8
#define EPSC 0.25f
#define SQRT3C 1.7320508075688772f
#define INV_SQRT3C 0.57735026918962576f
#define INV_F 0.125f  /* 1/sqrt(64) */

// ---- workspace layout (float offsets) ----
#define OFF_HSUP   0                               // (N,64)
#define OFF_HVUP   (N_NODES*64)                    // (N,3,64) planar
#define OFF_SKS    (OFF_HVUP + N_NODES*192)        // (N,64)
#define OFF_SKV    (OFF_SKS + N_NODES*64)          // (N,3,64) planar
#define OFF_HSMID  (OFF_SKV + N_NODES*192)         // (N,64)
#define OFF_HVMID  (OFF_HSMID + N_NODES*64)        // (N,3,64) planar
#define OFF_WSCP   (OFF_HVMID + N_NODES*192)       // (Z,9,64)
#define OFF_FRAGS  (OFF_WSCP + ZSP*576)            // 3328*8 ushort = 13312 floats
#define OFF_WBUF   (OFF_FRAGS + 13312)             // CHUNK*256 ushort = CHUNK*128 floats
#define OFF_CSR    (OFF_WBUF + CHUNK*128)          // erec float4[2*CHUNK], then ints
#define OFF_WF     (OFF_CSR + 2*CHUNK*4 + 400260)  // 416 slots * 512 ushort
// ints relative to csr int base (after erec):
#define CSR_CNT0   0
#define CSR_CNT1   20000
#define CSR_PTR0   40000
#define CSR_PTR1   60001
#define CSR_SEID   80002
#define CSR_AUX    400002   /* 2*128 block totals */

typedef __attribute__((ext_vector_type(8))) short bhalf8;
typedef __attribute__((ext_vector_type(4))) float f32x4;

// fast silu: v_exp_f32 + v_rcp_f32 (err ~1ulp, negligible vs bf16 quantization)
__device__ __forceinline__ float silu_f(float x) {
    float e = __builtin_amdgcn_exp2f(x * -1.442695040888963f);
    return x * __builtin_amdgcn_rcpf(1.0f + e);
}

__device__ __forceinline__ unsigned short f2bf(float x) {
    unsigned int u = __float_as_uint(x);
    unsigned int r = u + 0x7FFFu + ((u >> 16) & 1u);   // RNE
    return (unsigned short)(r >> 16);
}

// packed pair -> one dword (lo in low 16); v_cvt_pk_bf16_f32 on gfx950
__device__ __forceinline__ unsigned int pack_bf2(float lo, float hi) {
    __hip_bfloat162 b = __float22bfloat162_rn(make_float2(lo, hi));
    return *(unsigned int*)&b;
}

// split fp32 -> bf16 hi (trunc) + bf16 lo (trunc of residual); err ~2^-16 rel
__device__ __forceinline__ void split_f32(float x, short& h, short& l) {
    unsigned int u = __float_as_uint(x);
    unsigned int hb = u & 0xFFFF0000u;
    h = (short)(u >> 16);
    float r = x - __uint_as_float(hb);
    l = (short)(__float_as_uint(r) >> 16);
}

__device__ __forceinline__ int species_of(int n, const int* counts) {
    int acc = 0, s = ZSP - 1;
#pragma unroll
    for (int z = 0; z < ZSP; z++) {
        int c = counts[z];
        if (n >= acc && n < acc + c) s = z;
        acc += c;
    }
    return s;
}

// K0: wscp[z][b][u] = sum_p Wsc[z][p][u] * Proj[p][b]
__global__ void k_wscproj(const float* __restrict__ Wsc, const float* __restrict__ Proj,
                          float* __restrict__ wscp) {
    int z = blockIdx.x, t = threadIdx.x;
    if (t < 9 * 64) {
        int b = t >> 6, u = t & 63;
        float acc = 0.f;
#pragma unroll
        for (int p = 0; p < 9; p++) acc += Wsc[z * 576 + p * 64 + u] * Proj[p * 9 + b];
        wscp[z * 576 + b * 64 + u] = acc;
    }
}

// K-prep: bf16 MFMA B-fragments for R1(zero-pad K8->32), R2, R3, R4 (MLP path).
__global__ void k_prep(const float* __restrict__ R1, const float* __restrict__ R2,
                       const float* __restrict__ R3, const float* __restrict__ R4,
                       unsigned short* __restrict__ frags) {
    int id = blockIdx.x * 256 + threadIdx.x;
    if (id >= 3328) return;
    int lane = id & 63, fi = id >> 6;
    int quad = lane >> 4, l15 = lane & 15;
    const float* W;
    int s, t, N;
    bool r1 = false;
    if (fi < 4)       { W = R1; s = 0; t = fi; N = 64; r1 = true; }
    else if (fi < 12) { W = R2; int x = fi - 4;  s = x >> 2; t = x & 3;  N = 64; }
    else if (fi < 20) { W = R3; int x = fi - 12; s = x >> 2; t = x & 3;  N = 64; }
    else              { W = R4; int x = fi - 20; s = x >> 4; t = x & 15; N = 256; }
    unsigned int v[4];
#pragma unroll
    for (int jj = 0; jj < 4; jj++) {
        unsigned short lo, hi;
        {
            int j = jj * 2;
            int k = s * 32 + quad * 8 + j, n = t * 16 + l15;
            float val = (r1 && k >= RDIM) ? 0.f : W[k * N + n];
            lo = f2bf(val);
        }
        {
            int j = jj * 2 + 1;
            int k = s * 32 + quad * 8 + j, n = t * 16 + l15;
            float val = (r1 && k >= RDIM) ? 0.f : W[k * N + n];
            hi = f2bf(val);
        }
        v[jj] = (unsigned int)lo | ((unsigned int)hi << 16);
    }
    uint4 pk; pk.x = v[0]; pk.y = v[1]; pk.z = v[2]; pk.w = v[3];
    ((uint4*)frags)[id] = pk;
}

// K-prep2: split-bf16 (hi/lo) B-fragments for the 26 node-side 64x64 matrices.
__global__ void k_prep2(const float* __restrict__ Wup0, const float* __restrict__ Wup1,
                        const float* __restrict__ Ws0, const float* __restrict__ Ws1,
                        const float* __restrict__ Wd0, const float* __restrict__ Wd1,
                        const float* __restrict__ Wl0, const float* __restrict__ Wl1,
                        unsigned short* __restrict__ wf) {
    int id = blockIdx.x * 256 + threadIdx.x;
    if (id >= 416 * 64) return;
    int lane = id & 63, slot = id >> 6;
    int t = slot & 3, s = (slot >> 2) & 1, part = (slot >> 3) & 1, mat = slot >> 4;
    int quad = lane >> 4, l15 = lane & 15;
    const float* W;
    if (mat == 0)       W = Wup0;
    else if (mat == 1)  W = Wup1;
    else if (mat < 12)  W = Ws0 + (mat - 2) * 4096;
    else if (mat < 22)  W = Ws1 + (mat - 12) * 4096;
    else if (mat == 22) W = Wd0;
    else if (mat == 23) W = Wd1;
    else if (mat == 24) W = Wl0;
    else                W = Wl1;
    unsigned int v[4];
#pragma unroll
    for (int jj = 0; jj < 4; jj++) {
        unsigned short pk2[2];
#pragma unroll
        for (int o = 0; o < 2; o++) {
            int j = jj * 2 + o;
            int k = s * 32 + quad * 8 + j, n = t * 16 + l15;
            float x = W[k * 64 + n];
            short h, l;
            split_f32(x, h, l);
            pk2[o] = part == 0 ? (unsigned short)h : (unsigned short)l;
        }
        v[jj] = (unsigned int)pk2[0] | ((unsigned int)pk2[1] << 16);
    }
    uint4 pk; pk.x = v[0]; pk.y = v[1]; pk.z = v[2]; pk.w = v[3];
    ((uint4*)wf)[id] = pk;
}

// CSR build: histogram of receivers per chunk
__global__ __launch_bounds__(256) void k_hist(const int* __restrict__ receivers,
                                              int* __restrict__ csr) {
    int e = blockIdx.x * 256 + threadIdx.x;
    if (e < E_EDGES) {
        int base = (e < CHUNK) ? CSR_CNT0 : CSR_CNT1;
        atomicAdd(&csr[base + receivers[e]], 1);
    }
}

// 3-phase parallel scan. Phase 1: per-block (256) exclusive scan + block total.
__global__ __launch_bounds__(256) void k_scan1(int* __restrict__ csr) {
    __shared__ int sb[256];
    int z = blockIdx.y, b = blockIdx.x, t = threadIdx.x;
    int i = b * 256 + t;
    int cb = z ? CSR_CNT1 : CSR_CNT0;
    int pb = z ? CSR_PTR1 : CSR_PTR0;
    int x = (i < N_NODES) ? csr[cb + i] : 0;
    sb[t] = x;
    __syncthreads();
#pragma unroll
    for (int off = 1; off < 256; off <<= 1) {
        int v = (t >= off) ? sb[t - off] : 0;
        __syncthreads();
        sb[t] += v;
        __syncthreads();
    }
    if (i < N_NODES) csr[pb + i] = sb[t] - x;      // block-local exclusive
    if (t == 255) csr[CSR_AUX + z * 128 + b] = sb[255];
}

// Phase 2: scan the 79 block totals per chunk.
__global__ __launch_bounds__(128) void k_scan2(int* __restrict__ csr) {
    __shared__ int sb[128];
    int z = blockIdx.x, t = threadIdx.x;
    int pb = z ? CSR_PTR1 : CSR_PTR0;
    int x = (t < 79) ? csr[CSR_AUX + z * 128 + t] : 0;
    sb[t] = x;
    __syncthreads();
#pragma unroll
    for (int off = 1; off < 128; off <<= 1) {
        int v = (t >= off) ? sb[t - off] : 0;
        __syncthreads();
        sb[t] += v;
        __syncthreads();
    }
    csr[CSR_AUX + z * 128 + t] = sb[t] - x;
    if (t == 127) csr[pb + N_NODES] = sb[127];
}

// Phase 3: add block offsets; write final ptr and cursor.
__global__ __launch_bounds__(256) void k_scan3(int* __restrict__ csr) {
    int z = blockIdx.y, b = blockIdx.x, t = threadIdx.x;
    int i = b * 256 + t;
    if (i >= N_NODES) return;
    int cb = z ? CSR_CNT1 : CSR_CNT0;
    int pb = z ? CSR_PTR1 : CSR_PTR0;
    int v = csr[pb + i] + csr[CSR_AUX + z * 128 + b];
    csr[pb + i] = v;
    csr[cb + i] = v;   // cursor for bucketing
}

// CSR build: bucket edges; precompute Y1 + sender per slot.
__global__ __launch_bounds__(256) void k_bucket(
    const float* __restrict__ vectors, const int* __restrict__ senders,
    const int* __restrict__ receivers, int* __restrict__ csr,
    float4* __restrict__ erec) {
    int e = blockIdx.x * 256 + threadIdx.x;
    if (e >= E_EDGES) return;
    int z = (e < CHUNK) ? 0 : 1;
    int base = z ? CSR_CNT1 : CSR_CNT0;
    int pos = atomicAdd(&csr[base + receivers[e]], 1);
    float v0 = vectors[e * 3 + 0], v1 = vectors[e * 3 + 1], v2 = vectors[e * 3 + 2];
    float s = SQRT3C * rsqrtf(v0 * v0 + v1 * v1 + v2 * v2);
    int idx = z * CHUNK + pos;
    csr[CSR_SEID + idx] = e;
    float4 r;
    r.x = v0 * s; r.y = v1 * s; r.z = v2 * s; r.w = __int_as_float(senders[e]);
    erec[idx] = r;
}

// K1: linear_up + species skip via split-bf16 MFMA.
__global__ __launch_bounds__(256) void k_node_pre(
    const float* __restrict__ ns, const float* __restrict__ nv,
    const int* __restrict__ counts, const unsigned short* __restrict__ wf,
    float* __restrict__ ws) {
    int tid = threadIdx.x, w = tid >> 6, lane = tid & 63;
    int q = lane >> 4, l15 = lane & 15;
    int nw = blockIdx.x * 16;
    int sid = species_of(nw, counts);
    const f32x4 z4 = {0.f, 0.f, 0.f, 0.f};

    bhalf8 Ah[2], Al[2];
    if (w == 0) {
#pragma unroll
        for (int s = 0; s < 2; s++) {
            const float* rp = ns + (size_t)(nw + l15) * 64 + s * 32 + q * 8;
            float4 a = *(const float4*)rp, b = *(const float4*)(rp + 4);
            float x[8] = {a.x, a.y, a.z, a.w, b.x, b.y, b.z, b.w};
#pragma unroll
            for (int j = 0; j < 8; j++) { short h, l; split_f32(x[j], h, l); Ah[s][j] = h; Al[s][j] = l; }
        }
    } else {
        int i = w - 1;
#pragma unroll
        for (int s = 0; s < 2; s++) {
            const float* rp = nv + (size_t)(nw + l15) * 192 + i;
#pragma unroll
            for (int j = 0; j < 8; j++) {
                float x = rp[(s * 32 + q * 8 + j) * 3];
                short h, l; split_f32(x, h, l); Ah[s][j] = h; Al[s][j] = l;
            }
        }
    }

    const bhalf8* wfv = (const bhalf8*)wf;
    float* hs_up = ws + OFF_HSUP;
    float* hv_up = ws + OFF_HVUP;
    float* sks   = ws + OFF_SKS;
    float* skv   = ws + OFF_SKV;

#pragma unroll
    for (int m = 0; m < 2; m++) {
        int mat = (w == 0) ? (m == 0 ? 0 : 2 + sid) : (m == 0 ? 1 : 12 + sid);
        float* dst; int stride, off;
        if (w == 0) { dst = m == 0 ? hs_up : sks; stride = 64; off = 0; }
        else        { dst = m == 0 ? hv_up : skv; stride = 192; off = (w - 1) * 64; }
#pragma unroll
        for (int t = 0; t < 4; t++) {
            f32x4 acc = z4;
#pragma unroll
            for (int s = 0; s < 2; s++) {
                bhalf8 bh = wfv[(size_t)(mat * 16 + 0 + s * 4 + t) * 64 + lane];
                bhalf8 bl = wfv[(size_t)(mat * 16 + 8 + s * 4 + t) * 64 + lane];
                acc = __builtin_amdgcn_mfma_f32_16x16x32_bf16(Ah[s], bh, acc, 0, 0, 0);
                acc = __builtin_amdgcn_mfma_f32_16x16x32_bf16(Al[s], bh, acc, 0, 0, 0);
                acc = __builtin_amdgcn_mfma_f32_16x16x32_bf16(Ah[s], bl, acc, 0, 0, 0);
            }
#pragma unroll
            for (int r = 0; r < 4; r++)
                dst[(size_t)(nw + q * 4 + r) * stride + off + t * 16 + l15] = acc[r] * INV_F;
        }
    }
}

// K2a: radial MLP via bf16 MFMA, CSR-sorted order. Fast silu, packed bf16
// converts, coalesced uint2 wbuf stores (h=0 dwords buffered in registers).
__global__ __launch_bounds__(256) void k_mlp(
    const float* __restrict__ radial, const unsigned short* __restrict__ frags,
    const int* __restrict__ csr, unsigned short* __restrict__ wbuf, int e_base) {
    __shared__ unsigned short r4lds[16384];
    __shared__ unsigned short act[4][16 * 72];
    int tid = threadIdx.x;
    int lane = tid & 63, w = tid >> 6, quad = lane >> 4, l15 = lane & 15;

    const uint4* r4g = (const uint4*)(frags + 20 * 64 * 8);
    uint4* r4l = (uint4*)r4lds;
    for (int i = tid; i < 2048; i += 256) r4l[i] = r4g[i];
    const bhalf8* fr = (const bhalf8*)frags;
    bhalf8 r1f[4], r2f[2][4], r3f[2][4];
#pragma unroll
    for (int t = 0; t < 4; t++) r1f[t] = fr[t * 64 + lane];
#pragma unroll
    for (int s = 0; s < 2; s++)
#pragma unroll
        for (int t = 0; t < 4; t++) {
            r2f[s][t] = fr[(4 + s * 4 + t) * 64 + lane];
            r3f[s][t] = fr[(12 + s * 4 + t) * 64 + lane];
        }
    __syncthreads();

    const f32x4 z4 = {0.f, 0.f, 0.f, 0.f};
    const bhalf8* r4f = (const bhalf8*)r4lds;
    unsigned short* actw = act[w];

    for (int it = 0; it < 2; it++) {
        int el0 = (blockIdx.x * 2 + it) * 64 + w * 16;   // chunk-local sorted slot base
        bhalf8 af = {0, 0, 0, 0, 0, 0, 0, 0};
        if (quad == 0) {
            int eid = csr[CSR_SEID + e_base + el0 + l15];  // global edge id
            const float* rp = radial + (size_t)eid * 8;
            float4 ra = *(const float4*)rp;
            float4 rb = *(const float4*)(rp + 4);
            af[0] = (short)f2bf(ra.x); af[1] = (short)f2bf(ra.y);
            af[2] = (short)f2bf(ra.z); af[3] = (short)f2bf(ra.w);
            af[4] = (short)f2bf(rb.x); af[5] = (short)f2bf(rb.y);
            af[6] = (short)f2bf(rb.z); af[7] = (short)f2bf(rb.w);
        }
        {
            f32x4 acc[4];
#pragma unroll
            for (int t = 0; t < 4; t++)
                acc[t] = __builtin_amdgcn_mfma_f32_16x16x32_bf16(af, r1f[t], z4, 0, 0, 0);
#pragma unroll
            for (int t = 0; t < 4; t++)
#pragma unroll
                for (int r = 0; r < 4; r++)
                    actw[(quad * 4 + r) * 72 + t * 16 + l15] = f2bf(silu_f(acc[t][r]));
        }
#pragma unroll
        for (int layer = 0; layer < 2; layer++) {
            bhalf8 a0 = *(const bhalf8*)&actw[l15 * 72 + 0 + quad * 8];
            bhalf8 a1 = *(const bhalf8*)&actw[l15 * 72 + 32 + quad * 8];
            f32x4 acc[4];
#pragma unroll
            for (int t = 0; t < 4; t++) {
                bhalf8 b0 = layer == 0 ? r2f[0][t] : r3f[0][t];
                bhalf8 b1 = layer == 0 ? r2f[1][t] : r3f[1][t];
                acc[t] = __builtin_amdgcn_mfma_f32_16x16x32_bf16(
                    a1, b1, __builtin_amdgcn_mfma_f32_16x16x32_bf16(a0, b0, z4, 0, 0, 0), 0, 0, 0);
            }
#pragma unroll
            for (int t = 0; t < 4; t++)
#pragma unroll
                for (int r = 0; r < 4; r++)
                    actw[(quad * 4 + r) * 72 + t * 16 + l15] = f2bf(silu_f(acc[t][r]));
        }
        // ---- layer 4 (N=256): h=0 packed into regs, h=1 -> coalesced uint2 stores ----
        {
            bhalf8 a0 = *(const bhalf8*)&actw[l15 * 72 + 0 + quad * 8];
            bhalf8 a1 = *(const bhalf8*)&actw[l15 * 72 + 32 + quad * 8];
            unsigned int d0[16];
#pragma unroll
            for (int h = 0; h < 2; h++) {
                f32x4 acc8[8];
#pragma unroll
                for (int t8 = 0; t8 < 8; t8++) {
                    int t = h * 8 + t8;
                    acc8[t8] = __builtin_amdgcn_mfma_f32_16x16x32_bf16(
                        a1, r4f[(16 + t) * 64 + lane],
                        __builtin_amdgcn_mfma_f32_16x16x32_bf16(a0, r4f[t * 64 + lane], z4, 0, 0, 0),
                        0, 0, 0);
                }
#pragma unroll
                for (int t4 = 0; t4 < 4; t4++)
#pragma unroll
                    for (int r = 0; r < 4; r++) {
                        unsigned int d = pack_bf2(acc8[t4][r], acc8[t4 + 4][r]);
                        if (h == 0) {
                            d0[t4 * 4 + r] = d;
                        } else {
                            int el = el0 + quad * 4 + r;
                            int f = t4 * 16 + l15;
                            uint2 pk; pk.x = d0[t4 * 4 + r]; pk.y = d;
                            ((uint2*)wbuf)[(size_t)el * 64 + f] = pk;
                        }
                    }
            }
        }
    }
}

// K2b: CSR gather tensor product; wbuf is in sorted-slot order -> streamed.
__global__ __launch_bounds__(256) void k_tp_gather(
    const unsigned short* __restrict__ wbuf, const int* __restrict__ csr,
    const float4* __restrict__ erec, float* __restrict__ ws,
    int z, int accum) {
    int tid = threadIdx.x, w = tid >> 6, f = tid & 63;
    int n = blockIdx.x * 4 + w;
    const float* hs_up = ws + OFF_HSUP;
    const float* hv_up = ws + OFF_HVUP;
    float* hs_mid = ws + OFF_HSMID;
    float* hv_mid = ws + OFF_HVMID;
    int pb = z ? CSR_PTR1 : CSR_PTR0;
    int beg = csr[pb + n], end = csr[pb + n + 1];
    int e_base = z * CHUNK;
    float ams = 0.f, am0 = 0.f, am1 = 0.f, am2 = 0.f;
    for (int i = beg; i < end; i++) {
        int idx = e_base + i;
        float4 rc = erec[idx];
        int sx = __float_as_int(rc.w);
        uint2 wr = ((const uint2*)wbuf)[(size_t)i * 64 + f];
        float es = hs_up[sx * 64 + f];
        float e0 = hv_up[sx * 192 + f];
        float e1 = hv_up[sx * 192 + 64 + f];
        float e2 = hv_up[sx * 192 + 128 + f];
        float w0 = __uint_as_float(wr.x << 16);
        float w1 = __uint_as_float(wr.x & 0xFFFF0000u);
        float w2 = __uint_as_float(wr.y << 16);
        float w3 = __uint_as_float(wr.y & 0xFFFF0000u);
        float dot = e0 * rc.x + e1 * rc.y + e2 * rc.z;
        ams += w0 * es + w1 * dot * INV_SQRT3C;
        float t3 = w3 * es * INV_SQRT3C;
        am0 += w2 * e0 + t3 * rc.x;
        am1 += w2 * e1 + t3 * rc.y;
        am2 += w2 * e2 + t3 * rc.z;
    }
    if (!accum) {
        hs_mid[n * 64 + f] = ams;
        hv_mid[n * 192 + f] = am0;
        hv_mid[n * 192 + 64 + f] = am1;
        hv_mid[n * 192 + 128 + f] = am2;
    } else {
        hs_mid[n * 64 + f] = (hs_mid[n * 64 + f] + ams) * EPSC;
        hv_mid[n * 192 + f] = (hv_mid[n * 192 + f] + am0) * EPSC;
        hv_mid[n * 192 + 64 + f] = (hv_mid[n * 192 + 64 + f] + am1) * EPSC;
        hv_mid[n * 192 + 128 + f] = (hv_mid[n * 192 + 128 + f] + am2) * EPSC;
    }
}

// K3: linear_down + contraction + linear_sc + skip + readout via split-bf16 MFMA.
__global__ __launch_bounds__(256) void k_node_post(
    const int* __restrict__ counts, const unsigned short* __restrict__ wf,
    const float* __restrict__ Wr, float* __restrict__ ws, float* __restrict__ out) {
    __shared__ float T[4][16][68];
    int tid = threadIdx.x, w = tid >> 6, lane = tid & 63;
    int q = lane >> 4, l15 = lane & 15;
    int nw = blockIdx.x * 16;
    int sid = species_of(nw, counts);
    const f32x4 z4 = {0.f, 0.f, 0.f, 0.f};
    const bhalf8* wfv = (const bhalf8*)wf;
    const float* hs_mid = ws + OFF_HSMID;
    const float* hv_mid = ws + OFF_HVMID;
    const float* sks = ws + OFF_SKS;
    const float* skv = ws + OFF_SKV;
    const float* wscp = ws + OFF_WSCP;

    // Phase 1: linear_down
    {
        const float* src = (w == 0) ? hs_mid + (size_t)nw * 64
                                    : hv_mid + (size_t)nw * 192 + (w - 1) * 64;
        int rstride = (w == 0) ? 64 : 192;
        bhalf8 Ah[2], Al[2];
#pragma unroll
        for (int s = 0; s < 2; s++) {
            const float* rp = src + (size_t)l15 * rstride + s * 32 + q * 8;
            float4 a = *(const float4*)rp, b = *(const float4*)(rp + 4);
            float x[8] = {a.x, a.y, a.z, a.w, b.x, b.y, b.z, b.w};
#pragma unroll
            for (int j = 0; j < 8; j++) { short h, l; split_f32(x[j], h, l); Ah[s][j] = h; Al[s][j] = l; }
        }
        int mat = (w == 0) ? 22 : 23;
#pragma unroll
        for (int t = 0; t < 4; t++) {
            f32x4 acc = z4;
#pragma unroll
            for (int s = 0; s < 2; s++) {
                bhalf8 bh = wfv[(size_t)(mat * 16 + 0 + s * 4 + t) * 64 + lane];
                bhalf8 bl = wfv[(size_t)(mat * 16 + 8 + s * 4 + t) * 64 + lane];
                acc = __builtin_amdgcn_mfma_f32_16x16x32_bf16(Ah[s], bh, acc, 0, 0, 0);
                acc = __builtin_amdgcn_mfma_f32_16x16x32_bf16(Al[s], bh, acc, 0, 0, 0);
                acc = __builtin_amdgcn_mfma_f32_16x16x32_bf16(Ah[s], bl, acc, 0, 0, 0);
            }
#pragma unroll
            for (int r = 0; r < 4; r++)
                T[w][q * 4 + r][t * 16 + l15] = acc[r] * INV_F;
        }
    }
    __syncthreads();

    // Phase 2: symmetric contraction
    {
        int col = tid & 63, rg = tid >> 6;
        float wv[9];
#pragma unroll
        for (int b = 0; b < 9; b++) wv[b] = wscp[sid * 576 + b * 64 + col];
#pragma unroll
        for (int rr = 0; rr < 4; rr++) {
            int row = rg * 4 + rr;
            float hs = T[0][row][col];
            float h0 = T[1][row][col], h1 = T[2][row][col], h2 = T[3][row][col];
            float vv = h0 * h0 + h1 * h1 + h2 * h2;
            float cs = wv[0] * hs + wv[1] * hs * hs + wv[2] * vv
                     + wv[3] * hs * hs * hs + wv[4] * hs * vv;
            float fv = wv[5] + wv[6] * hs + wv[7] * hs * hs + wv[8] * vv;
            T[0][row][col] = cs;
            T[1][row][col] = h0 * fv;
            T[2][row][col] = h1 * fv;
            T[3][row][col] = h2 * fv;
        }
    }
    __syncthreads();

    // Phase 3: linear_sc + skip + store (+ readout on w0)
    {
        bhalf8 Ah[2], Al[2];
#pragma unroll
        for (int s = 0; s < 2; s++) {
            const float* rp = &T[w][l15][s * 32 + q * 8];
            float4 a = *(const float4*)rp, b = *(const float4*)(rp + 4);
            float x[8] = {a.x, a.y, a.z, a.w, b.x, b.y, b.z, b.w};
#pragma unroll
            for (int j = 0; j < 8; j++) { short h, l; split_f32(x[j], h, l); Ah[s][j] = h; Al[s][j] = l; }
        }
        int mat = (w == 0) ? 24 : 25;
        float* d_hs = out + N_NODES;
        float* d_hv = out + N_NODES + N_NODES * 64;
        float p[4] = {0.f, 0.f, 0.f, 0.f};
#pragma unroll
        for (int t = 0; t < 4; t++) {
            f32x4 acc = z4;
#pragma unroll
            for (int s = 0; s < 2; s++) {
                bhalf8 bh = wfv[(size_t)(mat * 16 + 0 + s * 4 + t) * 64 + lane];
                bhalf8 bl = wfv[(size_t)(mat * 16 + 8 + s * 4 + t) * 64 + lane];
                acc = __builtin_amdgcn_mfma_f32_16x16x32_bf16(Ah[s], bh, acc, 0, 0, 0);
                acc = __builtin_amdgcn_mfma_f32_16x16x32_bf16(Al[s], bh, acc, 0, 0, 0);
                acc = __builtin_amdgcn_mfma_f32_16x16x32_bf16(Ah[s], bl, acc, 0, 0, 0);
            }
            int col = t * 16 + l15;
            if (w == 0) {
                float wr = Wr[col];
#pragma unroll
                for (int r = 0; r < 4; r++) {
                    int gn = nw + q * 4 + r;
                    float v = acc[r] * INV_F + sks[(size_t)gn * 64 + col];
                    d_hs[(size_t)gn * 64 + col] = v;
                    p[r] += v * wr;
                }
            } else {
                int i = w - 1;
#pragma unroll
                for (int r = 0; r < 4; r++) {
                    int gn = nw + q * 4 + r;
                    float v = acc[r] * INV_F + skv[(size_t)gn * 192 + i * 64 + col];
                    d_hv[(size_t)gn * 192 + col * 3 + i] = v;
                }
            }
        }
        if (w == 0) {
#pragma unroll
            for (int r = 0; r < 4; r++) {
#pragma unroll
                for (int off = 1; off < 16; off <<= 1) p[r] += __shfl_xor(p[r], off, 64);
                if (l15 == 0) out[nw + q * 4 + r] = p[r] * INV_F;
            }
        }
    }
}

extern "C" void kernel_launch(void* const* d_in, const int* in_sizes, int n_in,
                              void* d_out, int out_size, void* d_ws, size_t ws_size,
                              hipStream_t stream) {
    const float* vectors   = (const float*)d_in[0];
    const float* node_s    = (const float*)d_in[1];
    const float* node_v    = (const float*)d_in[2];
    const float* radial    = (const float*)d_in[3];
    const int*   senders   = (const int*)d_in[4];
    const int*   receivers = (const int*)d_in[5];
    const int*   counts    = (const int*)d_in[6];
    const float* Wup0 = (const float*)d_in[7];
    const float* Wup1 = (const float*)d_in[8];
    const float* R1   = (const float*)d_in[9];
    const float* R2   = (const float*)d_in[10];
    const float* R3   = (const float*)d_in[11];
    const float* R4   = (const float*)d_in[12];
    const float* Wd0  = (const float*)d_in[13];
    const float* Wd1  = (const float*)d_in[14];
    const float* Ws0  = (const float*)d_in[15];
    const float* Ws1  = (const float*)d_in[16];
    const float* Wsc  = (const float*)d_in[17];
    const float* Proj = (const float*)d_in[18];
    const float* Wl0  = (const float*)d_in[19];
    const float* Wl1  = (const float*)d_in[20];
    const float* Wr   = (const float*)d_in[21];
    float* ws  = (float*)d_ws;
    float* out = (float*)d_out;
    unsigned short* frags = (unsigned short*)(ws + OFF_FRAGS);
    unsigned short* wbuf  = (unsigned short*)(ws + OFF_WBUF);
    float4* erec = (float4*)(ws + OFF_CSR);
    int* csr = (int*)(ws + OFF_CSR + 2 * CHUNK * 4);
    unsigned short* wf = (unsigned short*)(ws + OFF_WF);

    hipMemsetAsync(csr, 0, 2 * N_NODES * sizeof(int), stream);
    k_wscproj<<<ZSP, 576, 0, stream>>>(Wsc, Proj, ws + OFF_WSCP);
    k_prep<<<13, 256, 0, stream>>>(R1, R2, R3, R4, frags);
    k_prep2<<<104, 256, 0, stream>>>(Wup0, Wup1, Ws0, Ws1, Wd0, Wd1, Wl0, Wl1, wf);
    k_hist<<<E_EDGES / 256, 256, 0, stream>>>(receivers, csr);
    k_scan1<<<dim3(79, 2), 256, 0, stream>>>(csr);
    k_scan2<<<2, 128, 0, stream>>>(csr);
    k_scan3<<<dim3(79, 2), 256, 0, stream>>>(csr);
    k_bucket<<<E_EDGES / 256, 256, 0, stream>>>(vectors, senders, receivers, csr, erec);
    k_node_pre<<<N_NODES / 16, 256, 0, stream>>>(node_s, node_v, counts, wf, ws);
    for (int c = 0; c < 2; c++) {
        k_mlp<<<1250, 256, 0, stream>>>(radial, frags, csr, wbuf, c * CHUNK);
        k_tp_gather<<<N_NODES / 4, 256, 0, stream>>>(wbuf, csr, erec, ws, c, c);
    }
    k_node_post<<<N_NODES / 16, 256, 0, stream>>>(counts, wf, Wr, ws, out);
}

// Round 8
// 340.104 us; speedup vs baseline: 2.2536x; 1.0263x over previous
//
#include <hip/hip_runtime.h>
#include <hip/hip_bf16.h>
#include <math.h>

#define N_NODES 20000
#define FCH 64
#define ZSP 10
#define E_EDGES 320000
#define CHUNK 160000
#define RDIM 8
#define EPSC 0.25f
#define SQRT3C 1.7320508075688772f
#define INV_SQRT3C 0.57735026918962576f
#define INV_F 0.125f  /* 1/sqrt(64) */

// ---- workspace layout (float offsets) ----
#define OFF_HSUP   0                               // (N,64)
#define OFF_HVUP   (N_NODES*64)                    // (N,3,64) planar
#define OFF_SKS    (OFF_HVUP + N_NODES*192)        // (N,64)
#define OFF_SKV    (OFF_SKS + N_NODES*64)          // (N,3,64) planar
#define OFF_HSMID  (OFF_SKV + N_NODES*192)         // (N,64)
#define OFF_HVMID  (OFF_HSMID + N_NODES*64)        // (N,3,64) planar
#define OFF_WSCP   (OFF_HVMID + N_NODES*192)       // (Z,9,64)
#define OFF_FRAGS  (OFF_WSCP + ZSP*576)            // 3328*8 ushort = 13312 floats
#define OFF_WBUF   (OFF_FRAGS + 13312)             // CHUNK*256 ushort = CHUNK*128 floats
#define OFF_CSR    (OFF_WBUF + CHUNK*128)          // erec float4[2*CHUNK], then ints
#define OFF_WF     (OFF_CSR + 2*CHUNK*4 + 400260)  // 416 slots * 512 ushort
// ints relative to csr int base (after erec):
#define CSR_CNT0   0
#define CSR_CNT1   20000
#define CSR_PTR0   40000
#define CSR_PTR1   60001
#define CSR_SEID   80002
#define CSR_AUX    400002   /* 2*128 block totals */

// k_setup gid ranges
#define SU_WSC   5760                  /* 10*576 */
#define SU_PREP  (SU_WSC + 3328)
#define SU_PREP2 (SU_PREP + 26624)     /* 416*64 */
#define SU_HIST  (SU_PREP2 + E_EDGES)

typedef __attribute__((ext_vector_type(8))) short bhalf8;
typedef __attribute__((ext_vector_type(4))) float f32x4;

// fast silu: v_exp_f32 + v_rcp_f32 (err ~1ulp, negligible vs bf16 quantization)
__device__ __forceinline__ float silu_f(float x) {
    float e = __builtin_amdgcn_exp2f(x * -1.442695040888963f);
    return x * __builtin_amdgcn_rcpf(1.0f + e);
}

__device__ __forceinline__ unsigned short f2bf(float x) {
    unsigned int u = __float_as_uint(x);
    unsigned int r = u + 0x7FFFu + ((u >> 16) & 1u);   // RNE
    return (unsigned short)(r >> 16);
}

// packed pair -> one dword (lo in low 16); v_cvt_pk_bf16_f32 on gfx950
__device__ __forceinline__ unsigned int pack_bf2(float lo, float hi) {
    __hip_bfloat162 b = __float22bfloat162_rn(make_float2(lo, hi));
    return *(unsigned int*)&b;
}

// split fp32 -> bf16 hi (trunc) + bf16 lo (trunc of residual); err ~2^-16 rel
__device__ __forceinline__ void split_f32(float x, short& h, short& l) {
    unsigned int u = __float_as_uint(x);
    unsigned int hb = u & 0xFFFF0000u;
    h = (short)(u >> 16);
    float r = x - __uint_as_float(hb);
    l = (short)(__float_as_uint(r) >> 16);
}

__device__ __forceinline__ int species_of(int n, const int* counts) {
    int acc = 0, s = ZSP - 1;
#pragma unroll
    for (int z = 0; z < ZSP; z++) {
        int c = counts[z];
        if (n >= acc && n < acc + c) s = z;
        acc += c;
    }
    return s;
}

// K-setup: fused wscproj + prep(MLP frags) + prep2(node frags) + hist.
// All four are independent; gid-range split.
__global__ __launch_bounds__(256) void k_setup(
    const float* __restrict__ Wsc, const float* __restrict__ Proj, float* __restrict__ wscp,
    const float* __restrict__ R1, const float* __restrict__ R2,
    const float* __restrict__ R3, const float* __restrict__ R4,
    unsigned short* __restrict__ frags,
    const float* __restrict__ Wup0, const float* __restrict__ Wup1,
    const float* __restrict__ Ws0, const float* __restrict__ Ws1,
    const float* __restrict__ Wd0, const float* __restrict__ Wd1,
    const float* __restrict__ Wl0, const float* __restrict__ Wl1,
    unsigned short* __restrict__ wf,
    const int* __restrict__ receivers, int* __restrict__ csr) {
    int gid = blockIdx.x * 256 + threadIdx.x;
    if (gid < SU_WSC) {
        int z = gid / 576, t = gid % 576;
        int b = t >> 6, u = t & 63;
        float acc = 0.f;
#pragma unroll
        for (int p = 0; p < 9; p++) acc += Wsc[z * 576 + p * 64 + u] * Proj[p * 9 + b];
        wscp[z * 576 + b * 64 + u] = acc;
    } else if (gid < SU_PREP) {
        int id = gid - SU_WSC;
        int lane = id & 63, fi = id >> 6;
        int quad = lane >> 4, l15 = lane & 15;
        const float* W;
        int s, t, N;
        bool r1 = false;
        if (fi < 4)       { W = R1; s = 0; t = fi; N = 64; r1 = true; }
        else if (fi < 12) { W = R2; int x = fi - 4;  s = x >> 2; t = x & 3;  N = 64; }
        else if (fi < 20) { W = R3; int x = fi - 12; s = x >> 2; t = x & 3;  N = 64; }
        else              { W = R4; int x = fi - 20; s = x >> 4; t = x & 15; N = 256; }
        unsigned int v[4];
#pragma unroll
        for (int jj = 0; jj < 4; jj++) {
            unsigned short pk2[2];
#pragma unroll
            for (int o = 0; o < 2; o++) {
                int j = jj * 2 + o;
                int k = s * 32 + quad * 8 + j, n = t * 16 + l15;
                float val = (r1 && k >= RDIM) ? 0.f : W[k * N + n];
                pk2[o] = f2bf(val);
            }
            v[jj] = (unsigned int)pk2[0] | ((unsigned int)pk2[1] << 16);
        }
        uint4 pk; pk.x = v[0]; pk.y = v[1]; pk.z = v[2]; pk.w = v[3];
        ((uint4*)frags)[id] = pk;
    } else if (gid < SU_PREP2) {
        int id = gid - SU_PREP;
        int lane = id & 63, slot = id >> 6;
        int t = slot & 3, s = (slot >> 2) & 1, part = (slot >> 3) & 1, mat = slot >> 4;
        int quad = lane >> 4, l15 = lane & 15;
        const float* W;
        if (mat == 0)       W = Wup0;
        else if (mat == 1)  W = Wup1;
        else if (mat < 12)  W = Ws0 + (mat - 2) * 4096;
        else if (mat < 22)  W = Ws1 + (mat - 12) * 4096;
        else if (mat == 22) W = Wd0;
        else if (mat == 23) W = Wd1;
        else if (mat == 24) W = Wl0;
        else                W = Wl1;
        unsigned int v[4];
#pragma unroll
        for (int jj = 0; jj < 4; jj++) {
            unsigned short pk2[2];
#pragma unroll
            for (int o = 0; o < 2; o++) {
                int j = jj * 2 + o;
                int k = s * 32 + quad * 8 + j, n = t * 16 + l15;
                float x = W[k * 64 + n];
                short h, l;
                split_f32(x, h, l);
                pk2[o] = part == 0 ? (unsigned short)h : (unsigned short)l;
            }
            v[jj] = (unsigned int)pk2[0] | ((unsigned int)pk2[1] << 16);
        }
        uint4 pk; pk.x = v[0]; pk.y = v[1]; pk.z = v[2]; pk.w = v[3];
        ((uint4*)wf)[id] = pk;
    } else if (gid < SU_HIST) {
        int e = gid - SU_PREP2;
        int base = (e < CHUNK) ? CSR_CNT0 : CSR_CNT1;
        atomicAdd(&csr[base + receivers[e]], 1);
    }
}

// 3-phase parallel scan. Phase 1: per-block (256) exclusive scan + block total.
__global__ __launch_bounds__(256) void k_scan1(int* __restrict__ csr) {
    __shared__ int sb[256];
    int z = blockIdx.y, b = blockIdx.x, t = threadIdx.x;
    int i = b * 256 + t;
    int cb = z ? CSR_CNT1 : CSR_CNT0;
    int pb = z ? CSR_PTR1 : CSR_PTR0;
    int x = (i < N_NODES) ? csr[cb + i] : 0;
    sb[t] = x;
    __syncthreads();
#pragma unroll
    for (int off = 1; off < 256; off <<= 1) {
        int v = (t >= off) ? sb[t - off] : 0;
        __syncthreads();
        sb[t] += v;
        __syncthreads();
    }
    if (i < N_NODES) csr[pb + i] = sb[t] - x;      // block-local exclusive
    if (t == 255) csr[CSR_AUX + z * 128 + b] = sb[255];
}

// Phase 2: scan the 79 block totals per chunk.
__global__ __launch_bounds__(128) void k_scan2(int* __restrict__ csr) {
    __shared__ int sb[128];
    int z = blockIdx.x, t = threadIdx.x;
    int pb = z ? CSR_PTR1 : CSR_PTR0;
    int x = (t < 79) ? csr[CSR_AUX + z * 128 + t] : 0;
    sb[t] = x;
    __syncthreads();
#pragma unroll
    for (int off = 1; off < 128; off <<= 1) {
        int v = (t >= off) ? sb[t - off] : 0;
        __syncthreads();
        sb[t] += v;
        __syncthreads();
    }
    csr[CSR_AUX + z * 128 + t] = sb[t] - x;
    if (t == 127) csr[pb + N_NODES] = sb[127];
}

// Phase 3: add block offsets; write final ptr and cursor.
__global__ __launch_bounds__(256) void k_scan3(int* __restrict__ csr) {
    int z = blockIdx.y, b = blockIdx.x, t = threadIdx.x;
    int i = b * 256 + t;
    if (i >= N_NODES) return;
    int cb = z ? CSR_CNT1 : CSR_CNT0;
    int pb = z ? CSR_PTR1 : CSR_PTR0;
    int v = csr[pb + i] + csr[CSR_AUX + z * 128 + b];
    csr[pb + i] = v;
    csr[cb + i] = v;   // cursor for bucketing
}

// CSR build: bucket edges; precompute Y1 + sender per slot.
__global__ __launch_bounds__(256) void k_bucket(
    const float* __restrict__ vectors, const int* __restrict__ senders,
    const int* __restrict__ receivers, int* __restrict__ csr,
    float4* __restrict__ erec) {
    int e = blockIdx.x * 256 + threadIdx.x;
    if (e >= E_EDGES) return;
    int z = (e < CHUNK) ? 0 : 1;
    int base = z ? CSR_CNT1 : CSR_CNT0;
    int pos = atomicAdd(&csr[base + receivers[e]], 1);
    float v0 = vectors[e * 3 + 0], v1 = vectors[e * 3 + 1], v2 = vectors[e * 3 + 2];
    float s = SQRT3C * rsqrtf(v0 * v0 + v1 * v1 + v2 * v2);
    int idx = z * CHUNK + pos;
    csr[CSR_SEID + idx] = e;
    float4 r;
    r.x = v0 * s; r.y = v1 * s; r.z = v2 * s; r.w = __int_as_float(senders[e]);
    erec[idx] = r;
}

// K1: linear_up + species skip via split-bf16 MFMA.
__global__ __launch_bounds__(256) void k_node_pre(
    const float* __restrict__ ns, const float* __restrict__ nv,
    const int* __restrict__ counts, const unsigned short* __restrict__ wf,
    float* __restrict__ ws) {
    int tid = threadIdx.x, w = tid >> 6, lane = tid & 63;
    int q = lane >> 4, l15 = lane & 15;
    int nw = blockIdx.x * 16;
    int sid = species_of(nw, counts);
    const f32x4 z4 = {0.f, 0.f, 0.f, 0.f};

    bhalf8 Ah[2], Al[2];
    if (w == 0) {
#pragma unroll
        for (int s = 0; s < 2; s++) {
            const float* rp = ns + (size_t)(nw + l15) * 64 + s * 32 + q * 8;
            float4 a = *(const float4*)rp, b = *(const float4*)(rp + 4);
            float x[8] = {a.x, a.y, a.z, a.w, b.x, b.y, b.z, b.w};
#pragma unroll
            for (int j = 0; j < 8; j++) { short h, l; split_f32(x[j], h, l); Ah[s][j] = h; Al[s][j] = l; }
        }
    } else {
        int i = w - 1;
#pragma unroll
        for (int s = 0; s < 2; s++) {
            const float* rp = nv + (size_t)(nw + l15) * 192 + i;
#pragma unroll
            for (int j = 0; j < 8; j++) {
                float x = rp[(s * 32 + q * 8 + j) * 3];
                short h, l; split_f32(x, h, l); Ah[s][j] = h; Al[s][j] = l;
            }
        }
    }

    const bhalf8* wfv = (const bhalf8*)wf;
    float* hs_up = ws + OFF_HSUP;
    float* hv_up = ws + OFF_HVUP;
    float* sks   = ws + OFF_SKS;
    float* skv   = ws + OFF_SKV;

#pragma unroll
    for (int m = 0; m < 2; m++) {
        int mat = (w == 0) ? (m == 0 ? 0 : 2 + sid) : (m == 0 ? 1 : 12 + sid);
        float* dst; int stride, off;
        if (w == 0) { dst = m == 0 ? hs_up : sks; stride = 64; off = 0; }
        else        { dst = m == 0 ? hv_up : skv; stride = 192; off = (w - 1) * 64; }
#pragma unroll
        for (int t = 0; t < 4; t++) {
            f32x4 acc = z4;
#pragma unroll
            for (int s = 0; s < 2; s++) {
                bhalf8 bh = wfv[(size_t)(mat * 16 + 0 + s * 4 + t) * 64 + lane];
                bhalf8 bl = wfv[(size_t)(mat * 16 + 8 + s * 4 + t) * 64 + lane];
                acc = __builtin_amdgcn_mfma_f32_16x16x32_bf16(Ah[s], bh, acc, 0, 0, 0);
                acc = __builtin_amdgcn_mfma_f32_16x16x32_bf16(Al[s], bh, acc, 0, 0, 0);
                acc = __builtin_amdgcn_mfma_f32_16x16x32_bf16(Ah[s], bl, acc, 0, 0, 0);
            }
#pragma unroll
            for (int r = 0; r < 4; r++)
                dst[(size_t)(nw + q * 4 + r) * stride + off + t * 16 + l15] = acc[r] * INV_F;
        }
    }
}

// K2a: radial MLP via bf16 MFMA, CSR-sorted order (unchanged from R7).
__global__ __launch_bounds__(256) void k_mlp(
    const float* __restrict__ radial, const unsigned short* __restrict__ frags,
    const int* __restrict__ csr, unsigned short* __restrict__ wbuf, int e_base) {
    __shared__ unsigned short r4lds[16384];
    __shared__ unsigned short act[4][16 * 72];
    int tid = threadIdx.x;
    int lane = tid & 63, w = tid >> 6, quad = lane >> 4, l15 = lane & 15;

    const uint4* r4g = (const uint4*)(frags + 20 * 64 * 8);
    uint4* r4l = (uint4*)r4lds;
    for (int i = tid; i < 2048; i += 256) r4l[i] = r4g[i];
    const bhalf8* fr = (const bhalf8*)frags;
    bhalf8 r1f[4], r2f[2][4], r3f[2][4];
#pragma unroll
    for (int t = 0; t < 4; t++) r1f[t] = fr[t * 64 + lane];
#pragma unroll
    for (int s = 0; s < 2; s++)
#pragma unroll
        for (int t = 0; t < 4; t++) {
            r2f[s][t] = fr[(4 + s * 4 + t) * 64 + lane];
            r3f[s][t] = fr[(12 + s * 4 + t) * 64 + lane];
        }
    __syncthreads();

    const f32x4 z4 = {0.f, 0.f, 0.f, 0.f};
    const bhalf8* r4f = (const bhalf8*)r4lds;
    unsigned short* actw = act[w];

    for (int it = 0; it < 2; it++) {
        int el0 = (blockIdx.x * 2 + it) * 64 + w * 16;   // chunk-local sorted slot base
        bhalf8 af = {0, 0, 0, 0, 0, 0, 0, 0};
        if (quad == 0) {
            int eid = csr[CSR_SEID + e_base + el0 + l15];  // global edge id
            const float* rp = radial + (size_t)eid * 8;
            float4 ra = *(const float4*)rp;
            float4 rb = *(const float4*)(rp + 4);
            af[0] = (short)f2bf(ra.x); af[1] = (short)f2bf(ra.y);
            af[2] = (short)f2bf(ra.z); af[3] = (short)f2bf(ra.w);
            af[4] = (short)f2bf(rb.x); af[5] = (short)f2bf(rb.y);
            af[6] = (short)f2bf(rb.z); af[7] = (short)f2bf(rb.w);
        }
        {
            f32x4 acc[4];
#pragma unroll
            for (int t = 0; t < 4; t++)
                acc[t] = __builtin_amdgcn_mfma_f32_16x16x32_bf16(af, r1f[t], z4, 0, 0, 0);
#pragma unroll
            for (int t = 0; t < 4; t++)
#pragma unroll
                for (int r = 0; r < 4; r++)
                    actw[(quad * 4 + r) * 72 + t * 16 + l15] = f2bf(silu_f(acc[t][r]));
        }
#pragma unroll
        for (int layer = 0; layer < 2; layer++) {
            bhalf8 a0 = *(const bhalf8*)&actw[l15 * 72 + 0 + quad * 8];
            bhalf8 a1 = *(const bhalf8*)&actw[l15 * 72 + 32 + quad * 8];
            f32x4 acc[4];
#pragma unroll
            for (int t = 0; t < 4; t++) {
                bhalf8 b0 = layer == 0 ? r2f[0][t] : r3f[0][t];
                bhalf8 b1 = layer == 0 ? r2f[1][t] : r3f[1][t];
                acc[t] = __builtin_amdgcn_mfma_f32_16x16x32_bf16(
                    a1, b1, __builtin_amdgcn_mfma_f32_16x16x32_bf16(a0, b0, z4, 0, 0, 0), 0, 0, 0);
            }
#pragma unroll
            for (int t = 0; t < 4; t++)
#pragma unroll
                for (int r = 0; r < 4; r++)
                    actw[(quad * 4 + r) * 72 + t * 16 + l15] = f2bf(silu_f(acc[t][r]));
        }
        // ---- layer 4 (N=256): h=0 packed into regs, h=1 -> coalesced uint2 stores ----
        {
            bhalf8 a0 = *(const bhalf8*)&actw[l15 * 72 + 0 + quad * 8];
            bhalf8 a1 = *(const bhalf8*)&actw[l15 * 72 + 32 + quad * 8];
            unsigned int d0[16];
#pragma unroll
            for (int h = 0; h < 2; h++) {
                f32x4 acc8[8];
#pragma unroll
                for (int t8 = 0; t8 < 8; t8++) {
                    int t = h * 8 + t8;
                    acc8[t8] = __builtin_amdgcn_mfma_f32_16x16x32_bf16(
                        a1, r4f[(16 + t) * 64 + lane],
                        __builtin_amdgcn_mfma_f32_16x16x32_bf16(a0, r4f[t * 64 + lane], z4, 0, 0, 0),
                        0, 0, 0);
                }
#pragma unroll
                for (int t4 = 0; t4 < 4; t4++)
#pragma unroll
                    for (int r = 0; r < 4; r++) {
                        unsigned int d = pack_bf2(acc8[t4][r], acc8[t4 + 4][r]);
                        if (h == 0) {
                            d0[t4 * 4 + r] = d;
                        } else {
                            int el = el0 + quad * 4 + r;
                            int f = t4 * 16 + l15;
                            uint2 pk; pk.x = d0[t4 * 4 + r]; pk.y = d;
                            ((uint2*)wbuf)[(size_t)el * 64 + f] = pk;
                        }
                    }
            }
        }
    }
}

// K2b: CSR gather TP with depth-2 software pipeline (loads for edge i+2 issued
// before computing edge i -> ~14 outstanding loads/wave).
__global__ __launch_bounds__(256) void k_tp_gather(
    const unsigned short* __restrict__ wbuf, const int* __restrict__ csr,
    const float4* __restrict__ erec, float* __restrict__ ws,
    int z, int accum) {
    int tid = threadIdx.x, w = tid >> 6, f = tid & 63;
    int n = blockIdx.x * 4 + w;
    const float* hs_up = ws + OFF_HSUP;
    const float* hv_up = ws + OFF_HVUP;
    float* hs_mid = ws + OFF_HSMID;
    float* hv_mid = ws + OFF_HVMID;
    int pb = z ? CSR_PTR1 : CSR_PTR0;
    int beg = csr[pb + n], end = csr[pb + n + 1];
    int e_base = z * CHUNK;
    float ams = 0.f, am0 = 0.f, am1 = 0.f, am2 = 0.f;

    if (beg < end) {
        int last = end - 1;
        // batch A (edge beg)
        float4 rcA = erec[e_base + beg];
        uint2 wrA = ((const uint2*)wbuf)[(size_t)beg * 64 + f];
        int sxA = __float_as_int(rcA.w);
        float esA = hs_up[sxA * 64 + f];
        float eA0 = hv_up[sxA * 192 + f];
        float eA1 = hv_up[sxA * 192 + 64 + f];
        float eA2 = hv_up[sxA * 192 + 128 + f];
        // batch B (edge beg+1, clamped)
        int j1 = (beg + 1 < end) ? beg + 1 : last;
        float4 rcB = erec[e_base + j1];
        uint2 wrB = ((const uint2*)wbuf)[(size_t)j1 * 64 + f];
        int sxB = __float_as_int(rcB.w);
        float esB = hs_up[sxB * 64 + f];
        float eB0 = hv_up[sxB * 192 + f];
        float eB1 = hv_up[sxB * 192 + 64 + f];
        float eB2 = hv_up[sxB * 192 + 128 + f];

        for (int i = beg; i < end; i++) {
            // issue batch C (edge i+2, clamped)
            int j2 = (i + 2 < end) ? i + 2 : last;
            float4 rcC = erec[e_base + j2];
            uint2 wrC = ((const uint2*)wbuf)[(size_t)j2 * 64 + f];
            int sxC = __float_as_int(rcC.w);
            float esC = hs_up[sxC * 64 + f];
            float eC0 = hv_up[sxC * 192 + f];
            float eC1 = hv_up[sxC * 192 + 64 + f];
            float eC2 = hv_up[sxC * 192 + 128 + f];
            // compute batch A
            float w0 = __uint_as_float(wrA.x << 16);
            float w1 = __uint_as_float(wrA.x & 0xFFFF0000u);
            float w2 = __uint_as_float(wrA.y << 16);
            float w3 = __uint_as_float(wrA.y & 0xFFFF0000u);
            float dot = eA0 * rcA.x + eA1 * rcA.y + eA2 * rcA.z;
            ams += w0 * esA + w1 * dot * INV_SQRT3C;
            float t3 = w3 * esA * INV_SQRT3C;
            am0 += w2 * eA0 + t3 * rcA.x;
            am1 += w2 * eA1 + t3 * rcA.y;
            am2 += w2 * eA2 + t3 * rcA.z;
            // shift B->A, C->B
            rcA = rcB; wrA = wrB; esA = esB; eA0 = eB0; eA1 = eB1; eA2 = eB2;
            rcB = rcC; wrB = wrC; esB = esC; eB0 = eC0; eB1 = eC1; eB2 = eC2;
        }
    }
    if (!accum) {
        hs_mid[n * 64 + f] = ams;
        hv_mid[n * 192 + f] = am0;
        hv_mid[n * 192 + 64 + f] = am1;
        hv_mid[n * 192 + 128 + f] = am2;
    } else {
        hs_mid[n * 64 + f] = (hs_mid[n * 64 + f] + ams) * EPSC;
        hv_mid[n * 192 + f] = (hv_mid[n * 192 + f] + am0) * EPSC;
        hv_mid[n * 192 + 64 + f] = (hv_mid[n * 192 + 64 + f] + am1) * EPSC;
        hv_mid[n * 192 + 128 + f] = (hv_mid[n * 192 + 128 + f] + am2) * EPSC;
    }
}

// K3: linear_down + contraction + linear_sc + skip + readout via split-bf16 MFMA.
__global__ __launch_bounds__(256) void k_node_post(
    const int* __restrict__ counts, const unsigned short* __restrict__ wf,
    const float* __restrict__ Wr, float* __restrict__ ws, float* __restrict__ out) {
    __shared__ float T[4][16][68];
    int tid = threadIdx.x, w = tid >> 6, lane = tid & 63;
    int q = lane >> 4, l15 = lane & 15;
    int nw = blockIdx.x * 16;
    int sid = species_of(nw, counts);
    const f32x4 z4 = {0.f, 0.f, 0.f, 0.f};
    const bhalf8* wfv = (const bhalf8*)wf;
    const float* hs_mid = ws + OFF_HSMID;
    const float* hv_mid = ws + OFF_HVMID;
    const float* sks = ws + OFF_SKS;
    const float* skv = ws + OFF_SKV;
    const float* wscp = ws + OFF_WSCP;

    // Phase 1: linear_down
    {
        const float* src = (w == 0) ? hs_mid + (size_t)nw * 64
                                    : hv_mid + (size_t)nw * 192 + (w - 1) * 64;
        int rstride = (w == 0) ? 64 : 192;
        bhalf8 Ah[2], Al[2];
#pragma unroll
        for (int s = 0; s < 2; s++) {
            const float* rp = src + (size_t)l15 * rstride + s * 32 + q * 8;
            float4 a = *(const float4*)rp, b = *(const float4*)(rp + 4);
            float x[8] = {a.x, a.y, a.z, a.w, b.x, b.y, b.z, b.w};
#pragma unroll
            for (int j = 0; j < 8; j++) { short h, l; split_f32(x[j], h, l); Ah[s][j] = h; Al[s][j] = l; }
        }
        int mat = (w == 0) ? 22 : 23;
#pragma unroll
        for (int t = 0; t < 4; t++) {
            f32x4 acc = z4;
#pragma unroll
            for (int s = 0; s < 2; s++) {
                bhalf8 bh = wfv[(size_t)(mat * 16 + 0 + s * 4 + t) * 64 + lane];
                bhalf8 bl = wfv[(size_t)(mat * 16 + 8 + s * 4 + t) * 64 + lane];
                acc = __builtin_amdgcn_mfma_f32_16x16x32_bf16(Ah[s], bh, acc, 0, 0, 0);
                acc = __builtin_amdgcn_mfma_f32_16x16x32_bf16(Al[s], bh, acc, 0, 0, 0);
                acc = __builtin_amdgcn_mfma_f32_16x16x32_bf16(Ah[s], bl, acc, 0, 0, 0);
            }
#pragma unroll
            for (int r = 0; r < 4; r++)
                T[w][q * 4 + r][t * 16 + l15] = acc[r] * INV_F;
        }
    }
    __syncthreads();

    // Phase 2: symmetric contraction
    {
        int col = tid & 63, rg = tid >> 6;
        float wv[9];
#pragma unroll
        for (int b = 0; b < 9; b++) wv[b] = wscp[sid * 576 + b * 64 + col];
#pragma unroll
        for (int rr = 0; rr < 4; rr++) {
            int row = rg * 4 + rr;
            float hs = T[0][row][col];
            float h0 = T[1][row][col], h1 = T[2][row][col], h2 = T[3][row][col];
            float vv = h0 * h0 + h1 * h1 + h2 * h2;
            float cs = wv[0] * hs + wv[1] * hs * hs + wv[2] * vv
                     + wv[3] * hs * hs * hs + wv[4] * hs * vv;
            float fv = wv[5] + wv[6] * hs + wv[7] * hs * hs + wv[8] * vv;
            T[0][row][col] = cs;
            T[1][row][col] = h0 * fv;
            T[2][row][col] = h1 * fv;
            T[3][row][col] = h2 * fv;
        }
    }
    __syncthreads();

    // Phase 3: linear_sc + skip + store (+ readout on w0)
    {
        bhalf8 Ah[2], Al[2];
#pragma unroll
        for (int s = 0; s < 2; s++) {
            const float* rp = &T[w][l15][s * 32 + q * 8];
            float4 a = *(const float4*)rp, b = *(const float4*)(rp + 4);
            float x[8] = {a.x, a.y, a.z, a.w, b.x, b.y, b.z, b.w};
#pragma unroll
            for (int j = 0; j < 8; j++) { short h, l; split_f32(x[j], h, l); Ah[s][j] = h; Al[s][j] = l; }
        }
        int mat = (w == 0) ? 24 : 25;
        float* d_hs = out + N_NODES;
        float* d_hv = out + N_NODES + N_NODES * 64;
        float p[4] = {0.f, 0.f, 0.f, 0.f};
#pragma unroll
        for (int t = 0; t < 4; t++) {
            f32x4 acc = z4;
#pragma unroll
            for (int s = 0; s < 2; s++) {
                bhalf8 bh = wfv[(size_t)(mat * 16 + 0 + s * 4 + t) * 64 + lane];
                bhalf8 bl = wfv[(size_t)(mat * 16 + 8 + s * 4 + t) * 64 + lane];
                acc = __builtin_amdgcn_mfma_f32_16x16x32_bf16(Ah[s], bh, acc, 0, 0, 0);
                acc = __builtin_amdgcn_mfma_f32_16x16x32_bf16(Al[s], bh, acc, 0, 0, 0);
                acc = __builtin_amdgcn_mfma_f32_16x16x32_bf16(Ah[s], bl, acc, 0, 0, 0);
            }
            int col = t * 16 + l15;
            if (w == 0) {
                float wr = Wr[col];
#pragma unroll
                for (int r = 0; r < 4; r++) {
                    int gn = nw + q * 4 + r;
                    float v = acc[r] * INV_F + sks[(size_t)gn * 64 + col];
                    d_hs[(size_t)gn * 64 + col] = v;
                    p[r] += v * wr;
                }
            } else {
                int i = w - 1;
#pragma unroll
                for (int r = 0; r < 4; r++) {
                    int gn = nw + q * 4 + r;
                    float v = acc[r] * INV_F + skv[(size_t)gn * 192 + i * 64 + col];
                    d_hv[(size_t)gn * 192 + col * 3 + i] = v;
                }
            }
        }
        if (w == 0) {
#pragma unroll
            for (int r = 0; r < 4; r++) {
#pragma unroll
                for (int off = 1; off < 16; off <<= 1) p[r] += __shfl_xor(p[r], off, 64);
                if (l15 == 0) out[nw + q * 4 + r] = p[r] * INV_F;
            }
        }
    }
}

extern "C" void kernel_launch(void* const* d_in, const int* in_sizes, int n_in,
                              void* d_out, int out_size, void* d_ws, size_t ws_size,
                              hipStream_t stream) {
    const float* vectors   = (const float*)d_in[0];
    const float* node_s    = (const float*)d_in[1];
    const float* node_v    = (const float*)d_in[2];
    const float* radial    = (const float*)d_in[3];
    const int*   senders   = (const int*)d_in[4];
    const int*   receivers = (const int*)d_in[5];
    const int*   counts    = (const int*)d_in[6];
    const float* Wup0 = (const float*)d_in[7];
    const float* Wup1 = (const float*)d_in[8];
    const float* R1   = (const float*)d_in[9];
    const float* R2   = (const float*)d_in[10];
    const float* R3   = (const float*)d_in[11];
    const float* R4   = (const float*)d_in[12];
    const float* Wd0  = (const float*)d_in[13];
    const float* Wd1  = (const float*)d_in[14];
    const float* Ws0  = (const float*)d_in[15];
    const float* Ws1  = (const float*)d_in[16];
    const float* Wsc  = (const float*)d_in[17];
    const float* Proj = (const float*)d_in[18];
    const float* Wl0  = (const float*)d_in[19];
    const float* Wl1  = (const float*)d_in[20];
    const float* Wr   = (const float*)d_in[21];
    float* ws  = (float*)d_ws;
    float* out = (float*)d_out;
    unsigned short* frags = (unsigned short*)(ws + OFF_FRAGS);
    unsigned short* wbuf  = (unsigned short*)(ws + OFF_WBUF);
    float4* erec = (float4*)(ws + OFF_CSR);
    int* csr = (int*)(ws + OFF_CSR + 2 * CHUNK * 4);
    unsigned short* wf = (unsigned short*)(ws + OFF_WF);

    hipMemsetAsync(csr, 0, 2 * N_NODES * sizeof(int), stream);
    k_setup<<<(SU_HIST + 255) / 256, 256, 0, stream>>>(
        Wsc, Proj, ws + OFF_WSCP, R1, R2, R3, R4, frags,
        Wup0, Wup1, Ws0, Ws1, Wd0, Wd1, Wl0, Wl1, wf, receivers, csr);
    k_scan1<<<dim3(79, 2), 256, 0, stream>>>(csr);
    k_scan2<<<2, 128, 0, stream>>>(csr);
    k_scan3<<<dim3(79, 2), 256, 0, stream>>>(csr);
    k_bucket<<<E_EDGES / 256, 256, 0, stream>>>(vectors, senders, receivers, csr, erec);
    k_node_pre<<<N_NODES / 16, 256, 0, stream>>>(node_s, node_v, counts, wf, ws);
    for (int c = 0; c < 2; c++) {
        k_mlp<<<1250, 256, 0, stream>>>(radial, frags, csr, wbuf, c * CHUNK);
        k_tp_gather<<<N_NODES / 4, 256, 0, stream>>>(wbuf, csr, erec, ws, c, c);
    }
    k_node_post<<<N_NODES / 16, 256, 0, stream>>>(counts, wf, Wr, ws, out);
}

// Round 9
// 333.543 us; speedup vs baseline: 2.2979x; 1.0197x over previous
//
#include <hip/hip_runtime.h>
#include <hip/hip_bf16.h>
#include <math.h>

#define N_NODES 20000
#define FCH 64
#define ZSP 10
#define E_EDGES 320000
#define CHUNK 160000
#define RDIM 8
#define EPSC 0.25f
#define SQRT3C 1.7320508075688772f
#define INV_SQRT3C 0.57735026918962576f
#define INV_F 0.125f  /* 1/sqrt(64) */

// ---- workspace layout (float offsets) ----
#define OFF_HSUP   0                               // (N,64)
#define OFF_HVUP   (N_NODES*64)                    // (N,3,64) planar
#define OFF_SKS    (OFF_HVUP + N_NODES*192)        // (N,64)
#define OFF_SKV    (OFF_SKS + N_NODES*64)          // (N,3,64) planar
#define OFF_HSMID  (OFF_SKV + N_NODES*192)         // (N,64)
#define OFF_HVMID  (OFF_HSMID + N_NODES*64)        // (N,3,64) planar
#define OFF_WSCP   (OFF_HVMID + N_NODES*192)       // (Z,9,64)
#define OFF_FRAGS  (OFF_WSCP + ZSP*576)            // 3328*8 ushort = 13312 floats
#define OFF_WBUF   (OFF_FRAGS + 13312)             // CHUNK*256 ushort = CHUNK*128 floats
#define OFF_CSR    (OFF_WBUF + CHUNK*128)          // erec float4[2*CHUNK], then ints
#define OFF_WF     (OFF_CSR + 2*CHUNK*4 + 400260)  // 416 slots * 512 ushort
// ints relative to csr int base (after erec):
#define CSR_CNT0   0
#define CSR_CNT1   20000
#define CSR_PTR0   40000
#define CSR_PTR1   60001
#define CSR_SEID   80002
#define CSR_AUX    400002   /* 2*128 block totals */

// k_setup gid ranges
#define SU_WSC   5760                  /* 10*576 */
#define SU_PREP  (SU_WSC + 3328)
#define SU_PREP2 (SU_PREP + 26624)     /* 416*64 */
#define SU_HIST  (SU_PREP2 + E_EDGES)

typedef __attribute__((ext_vector_type(8))) short bhalf8;
typedef __attribute__((ext_vector_type(4))) float f32x4;

// fast silu: v_exp_f32 + v_rcp_f32 (err ~1ulp, negligible vs bf16 quantization)
__device__ __forceinline__ float silu_f(float x) {
    float e = __builtin_amdgcn_exp2f(x * -1.442695040888963f);
    return x * __builtin_amdgcn_rcpf(1.0f + e);
}

__device__ __forceinline__ unsigned short f2bf(float x) {
    unsigned int u = __float_as_uint(x);
    unsigned int r = u + 0x7FFFu + ((u >> 16) & 1u);   // RNE
    return (unsigned short)(r >> 16);
}

// packed pair -> one dword (lo in low 16); v_cvt_pk_bf16_f32 on gfx950
__device__ __forceinline__ unsigned int pack_bf2(float lo, float hi) {
    __hip_bfloat162 b = __float22bfloat162_rn(make_float2(lo, hi));
    return *(unsigned int*)&b;
}

__device__ __forceinline__ bhalf8 mk8(unsigned a, unsigned b, unsigned c, unsigned d) {
    uint4 u; u.x = a; u.y = b; u.z = c; u.w = d;
    return *(bhalf8*)&u;
}

// split fp32 -> bf16 hi (trunc) + bf16 lo (trunc of residual); err ~2^-16 rel
__device__ __forceinline__ void split_f32(float x, short& h, short& l) {
    unsigned int u = __float_as_uint(x);
    unsigned int hb = u & 0xFFFF0000u;
    h = (short)(u >> 16);
    float r = x - __uint_as_float(hb);
    l = (short)(__float_as_uint(r) >> 16);
}

__device__ __forceinline__ int species_of(int n, const int* counts) {
    int acc = 0, s = ZSP - 1;
#pragma unroll
    for (int z = 0; z < ZSP; z++) {
        int c = counts[z];
        if (n >= acc && n < acc + c) s = z;
        acc += c;
    }
    return s;
}

// K-setup: fused wscproj + prep(MLP frags) + prep2(node frags) + hist.
__global__ __launch_bounds__(256) void k_setup(
    const float* __restrict__ Wsc, const float* __restrict__ Proj, float* __restrict__ wscp,
    const float* __restrict__ R1, const float* __restrict__ R2,
    const float* __restrict__ R3, const float* __restrict__ R4,
    unsigned short* __restrict__ frags,
    const float* __restrict__ Wup0, const float* __restrict__ Wup1,
    const float* __restrict__ Ws0, const float* __restrict__ Ws1,
    const float* __restrict__ Wd0, const float* __restrict__ Wd1,
    const float* __restrict__ Wl0, const float* __restrict__ Wl1,
    unsigned short* __restrict__ wf,
    const int* __restrict__ receivers, int* __restrict__ csr) {
    int gid = blockIdx.x * 256 + threadIdx.x;
    if (gid < SU_WSC) {
        int z = gid / 576, t = gid % 576;
        int b = t >> 6, u = t & 63;
        float acc = 0.f;
#pragma unroll
        for (int p = 0; p < 9; p++) acc += Wsc[z * 576 + p * 64 + u] * Proj[p * 9 + b];
        wscp[z * 576 + b * 64 + u] = acc;
    } else if (gid < SU_PREP) {
        int id = gid - SU_WSC;
        int lane = id & 63, fi = id >> 6;
        int quad = lane >> 4, l15 = lane & 15;
        const float* W;
        int s, t, N;
        bool r1 = false;
        if (fi < 4)       { W = R1; s = 0; t = fi; N = 64; r1 = true; }
        else if (fi < 12) { W = R2; int x = fi - 4;  s = x >> 2; t = x & 3;  N = 64; }
        else if (fi < 20) { W = R3; int x = fi - 12; s = x >> 2; t = x & 3;  N = 64; }
        else              { W = R4; int x = fi - 20; s = x >> 4; t = x & 15; N = 256; }
        unsigned int v[4];
#pragma unroll
        for (int jj = 0; jj < 4; jj++) {
            unsigned short pk2[2];
#pragma unroll
            for (int o = 0; o < 2; o++) {
                int j = jj * 2 + o;
                int k = s * 32 + quad * 8 + j, n = t * 16 + l15;
                float val = (r1 && k >= RDIM) ? 0.f : W[k * N + n];
                pk2[o] = f2bf(val);
            }
            v[jj] = (unsigned int)pk2[0] | ((unsigned int)pk2[1] << 16);
        }
        uint4 pk; pk.x = v[0]; pk.y = v[1]; pk.z = v[2]; pk.w = v[3];
        ((uint4*)frags)[id] = pk;
    } else if (gid < SU_PREP2) {
        int id = gid - SU_PREP;
        int lane = id & 63, slot = id >> 6;
        int t = slot & 3, s = (slot >> 2) & 1, part = (slot >> 3) & 1, mat = slot >> 4;
        int quad = lane >> 4, l15 = lane & 15;
        const float* W;
        if (mat == 0)       W = Wup0;
        else if (mat == 1)  W = Wup1;
        else if (mat < 12)  W = Ws0 + (mat - 2) * 4096;
        else if (mat < 22)  W = Ws1 + (mat - 12) * 4096;
        else if (mat == 22) W = Wd0;
        else if (mat == 23) W = Wd1;
        else if (mat == 24) W = Wl0;
        else                W = Wl1;
        unsigned int v[4];
#pragma unroll
        for (int jj = 0; jj < 4; jj++) {
            unsigned short pk2[2];
#pragma unroll
            for (int o = 0; o < 2; o++) {
                int j = jj * 2 + o;
                int k = s * 32 + quad * 8 + j, n = t * 16 + l15;
                float x = W[k * 64 + n];
                short h, l;
                split_f32(x, h, l);
                pk2[o] = part == 0 ? (unsigned short)h : (unsigned short)l;
            }
            v[jj] = (unsigned int)pk2[0] | ((unsigned int)pk2[1] << 16);
        }
        uint4 pk; pk.x = v[0]; pk.y = v[1]; pk.z = v[2]; pk.w = v[3];
        ((uint4*)wf)[id] = pk;
    } else if (gid < SU_HIST) {
        int e = gid - SU_PREP2;
        int base = (e < CHUNK) ? CSR_CNT0 : CSR_CNT1;
        atomicAdd(&csr[base + receivers[e]], 1);
    }
}

// 3-phase parallel scan. Phase 1: per-block (256) exclusive scan + block total.
__global__ __launch_bounds__(256) void k_scan1(int* __restrict__ csr) {
    __shared__ int sb[256];
    int z = blockIdx.y, b = blockIdx.x, t = threadIdx.x;
    int i = b * 256 + t;
    int cb = z ? CSR_CNT1 : CSR_CNT0;
    int pb = z ? CSR_PTR1 : CSR_PTR0;
    int x = (i < N_NODES) ? csr[cb + i] : 0;
    sb[t] = x;
    __syncthreads();
#pragma unroll
    for (int off = 1; off < 256; off <<= 1) {
        int v = (t >= off) ? sb[t - off] : 0;
        __syncthreads();
        sb[t] += v;
        __syncthreads();
    }
    if (i < N_NODES) csr[pb + i] = sb[t] - x;      // block-local exclusive
    if (t == 255) csr[CSR_AUX + z * 128 + b] = sb[255];
}

// Phase 2: scan the 79 block totals per chunk.
__global__ __launch_bounds__(128) void k_scan2(int* __restrict__ csr) {
    __shared__ int sb[128];
    int z = blockIdx.x, t = threadIdx.x;
    int pb = z ? CSR_PTR1 : CSR_PTR0;
    int x = (t < 79) ? csr[CSR_AUX + z * 128 + t] : 0;
    sb[t] = x;
    __syncthreads();
#pragma unroll
    for (int off = 1; off < 128; off <<= 1) {
        int v = (t >= off) ? sb[t - off] : 0;
        __syncthreads();
        sb[t] += v;
        __syncthreads();
    }
    csr[CSR_AUX + z * 128 + t] = sb[t] - x;
    if (t == 127) csr[pb + N_NODES] = sb[127];
}

// Phase 3: add block offsets; write final ptr and cursor.
__global__ __launch_bounds__(256) void k_scan3(int* __restrict__ csr) {
    int z = blockIdx.y, b = blockIdx.x, t = threadIdx.x;
    int i = b * 256 + t;
    if (i >= N_NODES) return;
    int cb = z ? CSR_CNT1 : CSR_CNT0;
    int pb = z ? CSR_PTR1 : CSR_PTR0;
    int v = csr[pb + i] + csr[CSR_AUX + z * 128 + b];
    csr[pb + i] = v;
    csr[cb + i] = v;   // cursor for bucketing
}

// CSR build: bucket edges; precompute Y1 + sender per slot.
__global__ __launch_bounds__(256) void k_bucket(
    const float* __restrict__ vectors, const int* __restrict__ senders,
    const int* __restrict__ receivers, int* __restrict__ csr,
    float4* __restrict__ erec) {
    int e = blockIdx.x * 256 + threadIdx.x;
    if (e >= E_EDGES) return;
    int z = (e < CHUNK) ? 0 : 1;
    int base = z ? CSR_CNT1 : CSR_CNT0;
    int pos = atomicAdd(&csr[base + receivers[e]], 1);
    float v0 = vectors[e * 3 + 0], v1 = vectors[e * 3 + 1], v2 = vectors[e * 3 + 2];
    float s = SQRT3C * rsqrtf(v0 * v0 + v1 * v1 + v2 * v2);
    int idx = z * CHUNK + pos;
    csr[CSR_SEID + idx] = e;
    float4 r;
    r.x = v0 * s; r.y = v1 * s; r.z = v2 * s; r.w = __int_as_float(senders[e]);
    erec[idx] = r;
}

// K1: linear_up + species skip via split-bf16 MFMA.
__global__ __launch_bounds__(256) void k_node_pre(
    const float* __restrict__ ns, const float* __restrict__ nv,
    const int* __restrict__ counts, const unsigned short* __restrict__ wf,
    float* __restrict__ ws) {
    int tid = threadIdx.x, w = tid >> 6, lane = tid & 63;
    int q = lane >> 4, l15 = lane & 15;
    int nw = blockIdx.x * 16;
    int sid = species_of(nw, counts);
    const f32x4 z4 = {0.f, 0.f, 0.f, 0.f};

    bhalf8 Ah[2], Al[2];
    if (w == 0) {
#pragma unroll
        for (int s = 0; s < 2; s++) {
            const float* rp = ns + (size_t)(nw + l15) * 64 + s * 32 + q * 8;
            float4 a = *(const float4*)rp, b = *(const float4*)(rp + 4);
            float x[8] = {a.x, a.y, a.z, a.w, b.x, b.y, b.z, b.w};
#pragma unroll
            for (int j = 0; j < 8; j++) { short h, l; split_f32(x[j], h, l); Ah[s][j] = h; Al[s][j] = l; }
        }
    } else {
        int i = w - 1;
#pragma unroll
        for (int s = 0; s < 2; s++) {
            const float* rp = nv + (size_t)(nw + l15) * 192 + i;
#pragma unroll
            for (int j = 0; j < 8; j++) {
                float x = rp[(s * 32 + q * 8 + j) * 3];
                short h, l; split_f32(x, h, l); Ah[s][j] = h; Al[s][j] = l;
            }
        }
    }

    const bhalf8* wfv = (const bhalf8*)wf;
    float* hs_up = ws + OFF_HSUP;
    float* hv_up = ws + OFF_HVUP;
    float* sks   = ws + OFF_SKS;
    float* skv   = ws + OFF_SKV;

#pragma unroll
    for (int m = 0; m < 2; m++) {
        int mat = (w == 0) ? (m == 0 ? 0 : 2 + sid) : (m == 0 ? 1 : 12 + sid);
        float* dst; int stride, off;
        if (w == 0) { dst = m == 0 ? hs_up : sks; stride = 64; off = 0; }
        else        { dst = m == 0 ? hv_up : skv; stride = 192; off = (w - 1) * 64; }
#pragma unroll
        for (int t = 0; t < 4; t++) {
            f32x4 acc = z4;
#pragma unroll
            for (int s = 0; s < 2; s++) {
                bhalf8 bh = wfv[(size_t)(mat * 16 + 0 + s * 4 + t) * 64 + lane];
                bhalf8 bl = wfv[(size_t)(mat * 16 + 8 + s * 4 + t) * 64 + lane];
                acc = __builtin_amdgcn_mfma_f32_16x16x32_bf16(Ah[s], bh, acc, 0, 0, 0);
                acc = __builtin_amdgcn_mfma_f32_16x16x32_bf16(Al[s], bh, acc, 0, 0, 0);
                acc = __builtin_amdgcn_mfma_f32_16x16x32_bf16(Ah[s], bl, acc, 0, 0, 0);
            }
#pragma unroll
            for (int r = 0; r < 4; r++)
                dst[(size_t)(nw + q * 4 + r) * stride + off + t * 16 + l15] = acc[r] * INV_F;
        }
    }
}

// Cross-lane frag builder: from packed silu'd layer output (pkA/pkB per m-tile),
// build the next layer's act fragment for k-half S. Output C[g][e] lives at
// lane (q_src, l15) regs (t, r); receiver (q, l15) needs k = S*32+8q+j, e=l15.
// Derivation: t_src = 2S + (q>>1); src lane = 2(q&1)*16 + 16*(m>>1) + l15;
// dword m parity selects pkA (rows r0,r1) vs pkB (rows r2,r3).
template<int S>
__device__ __forceinline__ bhalf8 xfrag(const unsigned* pkA, const unsigned* pkB,
                                        int q, int l15) {
    int L0 = ((q & 1) << 5) + l15;
    int L1 = L0 + 16;
    bool hi = (q >> 1) != 0;
    unsigned a0 = (unsigned)__shfl((int)pkA[2 * S], L0, 64);
    unsigned a1 = (unsigned)__shfl((int)pkA[2 * S + 1], L0, 64);
    unsigned b0 = (unsigned)__shfl((int)pkB[2 * S], L0, 64);
    unsigned b1 = (unsigned)__shfl((int)pkB[2 * S + 1], L0, 64);
    unsigned c0 = (unsigned)__shfl((int)pkA[2 * S], L1, 64);
    unsigned c1 = (unsigned)__shfl((int)pkA[2 * S + 1], L1, 64);
    unsigned e0 = (unsigned)__shfl((int)pkB[2 * S], L1, 64);
    unsigned e1 = (unsigned)__shfl((int)pkB[2 * S + 1], L1, 64);
    return mk8(hi ? a1 : a0, hi ? b1 : b0, hi ? c1 : c0, hi ? e1 : e0);
}

// K2a: radial MLP via bf16 MFMA, CSR-sorted order. Weights stationary as
// A-operand (A-frag of W^T == B-frag of W, same bytes); activations pass
// layer-to-layer via in-register ds_bpermute shuffles — NO activation LDS,
// no barriers in the body. LDS = 32KB (R4 frags only) -> 4+ blocks/CU.
__global__ __launch_bounds__(256) void k_mlp(
    const float* __restrict__ radial, const unsigned short* __restrict__ frags,
    const int* __restrict__ csr, unsigned short* __restrict__ wbuf, int e_base) {
    __shared__ unsigned short r4lds[16384];   // 32 KB
    int tid = threadIdx.x;
    int lane = tid & 63, w = tid >> 6, quad = lane >> 4, l15 = lane & 15;

    const uint4* r4g = (const uint4*)(frags + 20 * 64 * 8);
    uint4* r4l = (uint4*)r4lds;
    for (int i = tid; i < 2048; i += 256) r4l[i] = r4g[i];
    const bhalf8* fr = (const bhalf8*)frags;
    bhalf8 r1f[4], r2f[2][4], r3f[2][4];
#pragma unroll
    for (int t = 0; t < 4; t++) r1f[t] = fr[t * 64 + lane];
#pragma unroll
    for (int s = 0; s < 2; s++)
#pragma unroll
        for (int t = 0; t < 4; t++) {
            r2f[s][t] = fr[(4 + s * 4 + t) * 64 + lane];
            r3f[s][t] = fr[(12 + s * 4 + t) * 64 + lane];
        }
    __syncthreads();

    const f32x4 z4 = {0.f, 0.f, 0.f, 0.f};
    const bhalf8* r4f = (const bhalf8*)r4lds;

    int el0 = (blockIdx.x * 4 + w) * 16;   // chunk-local sorted slot base

    // ---- layer 1: B = radial^T (quad0 lanes hold k=0..7 of edge l15) ----
    bhalf8 af = {0, 0, 0, 0, 0, 0, 0, 0};
    if (quad == 0) {
        int eid = csr[CSR_SEID + e_base + el0 + l15];  // global edge id
        const float* rp = radial + (size_t)eid * 8;
        float4 ra = *(const float4*)rp;
        float4 rb = *(const float4*)(rp + 4);
        af[0] = (short)f2bf(ra.x); af[1] = (short)f2bf(ra.y);
        af[2] = (short)f2bf(ra.z); af[3] = (short)f2bf(ra.w);
        af[4] = (short)f2bf(rb.x); af[5] = (short)f2bf(rb.y);
        af[6] = (short)f2bf(rb.z); af[7] = (short)f2bf(rb.w);
    }
    unsigned pkA[4], pkB[4];
    {
        f32x4 acc[4];
#pragma unroll
        for (int t = 0; t < 4; t++)
            acc[t] = __builtin_amdgcn_mfma_f32_16x16x32_bf16(r1f[t], af, z4, 0, 0, 0);
#pragma unroll
        for (int t = 0; t < 4; t++) {
            pkA[t] = pack_bf2(silu_f(acc[t][0]), silu_f(acc[t][1]));
            pkB[t] = pack_bf2(silu_f(acc[t][2]), silu_f(acc[t][3]));
        }
    }
    // ---- layers 2, 3 ----
#pragma unroll
    for (int layer = 0; layer < 2; layer++) {
        bhalf8 b0 = xfrag<0>(pkA, pkB, quad, l15);
        bhalf8 b1 = xfrag<1>(pkA, pkB, quad, l15);
        f32x4 acc[4];
#pragma unroll
        for (int t = 0; t < 4; t++) {
            bhalf8 w0 = layer == 0 ? r2f[0][t] : r3f[0][t];
            bhalf8 w1 = layer == 0 ? r2f[1][t] : r3f[1][t];
            acc[t] = __builtin_amdgcn_mfma_f32_16x16x32_bf16(
                w1, b1, __builtin_amdgcn_mfma_f32_16x16x32_bf16(w0, b0, z4, 0, 0, 0), 0, 0, 0);
        }
#pragma unroll
        for (int t = 0; t < 4; t++) {
            pkA[t] = pack_bf2(silu_f(acc[t][0]), silu_f(acc[t][1]));
            pkB[t] = pack_bf2(silu_f(acc[t][2]), silu_f(acc[t][3]));
        }
    }
    // ---- layer 4 (N=256): act as A-operand (same frag bytes), R4 frags as B ----
    {
        bhalf8 a0 = xfrag<0>(pkA, pkB, quad, l15);
        bhalf8 a1 = xfrag<1>(pkA, pkB, quad, l15);
#pragma unroll
        for (int t4 = 0; t4 < 4; t4++) {
            f32x4 p0 = __builtin_amdgcn_mfma_f32_16x16x32_bf16(
                a1, r4f[(16 + t4) * 64 + lane],
                __builtin_amdgcn_mfma_f32_16x16x32_bf16(a0, r4f[t4 * 64 + lane], z4, 0, 0, 0), 0, 0, 0);
            f32x4 p1 = __builtin_amdgcn_mfma_f32_16x16x32_bf16(
                a1, r4f[(20 + t4) * 64 + lane],
                __builtin_amdgcn_mfma_f32_16x16x32_bf16(a0, r4f[(4 + t4) * 64 + lane], z4, 0, 0, 0), 0, 0, 0);
            f32x4 p2 = __builtin_amdgcn_mfma_f32_16x16x32_bf16(
                a1, r4f[(24 + t4) * 64 + lane],
                __builtin_amdgcn_mfma_f32_16x16x32_bf16(a0, r4f[(8 + t4) * 64 + lane], z4, 0, 0, 0), 0, 0, 0);
            f32x4 p3 = __builtin_amdgcn_mfma_f32_16x16x32_bf16(
                a1, r4f[(28 + t4) * 64 + lane],
                __builtin_amdgcn_mfma_f32_16x16x32_bf16(a0, r4f[(12 + t4) * 64 + lane], z4, 0, 0, 0), 0, 0, 0);
#pragma unroll
            for (int r = 0; r < 4; r++) {
                int el = el0 + quad * 4 + r;
                int f = t4 * 16 + l15;
                uint2 pk;
                pk.x = pack_bf2(p0[r], p1[r]);
                pk.y = pack_bf2(p2[r], p3[r]);
                ((uint2*)wbuf)[(size_t)el * 64 + f] = pk;
            }
        }
    }
}

// K2b: CSR gather TP with depth-2 software pipeline.
__global__ __launch_bounds__(256) void k_tp_gather(
    const unsigned short* __restrict__ wbuf, const int* __restrict__ csr,
    const float4* __restrict__ erec, float* __restrict__ ws,
    int z, int accum) {
    int tid = threadIdx.x, w = tid >> 6, f = tid & 63;
    int n = blockIdx.x * 4 + w;
    const float* hs_up = ws + OFF_HSUP;
    const float* hv_up = ws + OFF_HVUP;
    float* hs_mid = ws + OFF_HSMID;
    float* hv_mid = ws + OFF_HVMID;
    int pb = z ? CSR_PTR1 : CSR_PTR0;
    int beg = csr[pb + n], end = csr[pb + n + 1];
    int e_base = z * CHUNK;
    float ams = 0.f, am0 = 0.f, am1 = 0.f, am2 = 0.f;

    if (beg < end) {
        int last = end - 1;
        float4 rcA = erec[e_base + beg];
        uint2 wrA = ((const uint2*)wbuf)[(size_t)beg * 64 + f];
        int sxA = __float_as_int(rcA.w);
        float esA = hs_up[sxA * 64 + f];
        float eA0 = hv_up[sxA * 192 + f];
        float eA1 = hv_up[sxA * 192 + 64 + f];
        float eA2 = hv_up[sxA * 192 + 128 + f];
        int j1 = (beg + 1 < end) ? beg + 1 : last;
        float4 rcB = erec[e_base + j1];
        uint2 wrB = ((const uint2*)wbuf)[(size_t)j1 * 64 + f];
        int sxB = __float_as_int(rcB.w);
        float esB = hs_up[sxB * 64 + f];
        float eB0 = hv_up[sxB * 192 + f];
        float eB1 = hv_up[sxB * 192 + 64 + f];
        float eB2 = hv_up[sxB * 192 + 128 + f];

        for (int i = beg; i < end; i++) {
            int j2 = (i + 2 < end) ? i + 2 : last;
            float4 rcC = erec[e_base + j2];
            uint2 wrC = ((const uint2*)wbuf)[(size_t)j2 * 64 + f];
            int sxC = __float_as_int(rcC.w);
            float esC = hs_up[sxC * 64 + f];
            float eC0 = hv_up[sxC * 192 + f];
            float eC1 = hv_up[sxC * 192 + 64 + f];
            float eC2 = hv_up[sxC * 192 + 128 + f];
            float w0 = __uint_as_float(wrA.x << 16);
            float w1 = __uint_as_float(wrA.x & 0xFFFF0000u);
            float w2 = __uint_as_float(wrA.y << 16);
            float w3 = __uint_as_float(wrA.y & 0xFFFF0000u);
            float dot = eA0 * rcA.x + eA1 * rcA.y + eA2 * rcA.z;
            ams += w0 * esA + w1 * dot * INV_SQRT3C;
            float t3 = w3 * esA * INV_SQRT3C;
            am0 += w2 * eA0 + t3 * rcA.x;
            am1 += w2 * eA1 + t3 * rcA.y;
            am2 += w2 * eA2 + t3 * rcA.z;
            rcA = rcB; wrA = wrB; esA = esB; eA0 = eB0; eA1 = eB1; eA2 = eB2;
            rcB = rcC; wrB = wrC; esB = esC; eB0 = eC0; eB1 = eC1; eB2 = eC2;
        }
    }
    if (!accum) {
        hs_mid[n * 64 + f] = ams;
        hv_mid[n * 192 + f] = am0;
        hv_mid[n * 192 + 64 + f] = am1;
        hv_mid[n * 192 + 128 + f] = am2;
    } else {
        hs_mid[n * 64 + f] = (hs_mid[n * 64 + f] + ams) * EPSC;
        hv_mid[n * 192 + f] = (hv_mid[n * 192 + f] + am0) * EPSC;
        hv_mid[n * 192 + 64 + f] = (hv_mid[n * 192 + 64 + f] + am1) * EPSC;
        hv_mid[n * 192 + 128 + f] = (hv_mid[n * 192 + 128 + f] + am2) * EPSC;
    }
}

// K3: linear_down + contraction + linear_sc + skip + readout via split-bf16 MFMA.
__global__ __launch_bounds__(256) void k_node_post(
    const int* __restrict__ counts, const unsigned short* __restrict__ wf,
    const float* __restrict__ Wr, float* __restrict__ ws, float* __restrict__ out) {
    __shared__ float T[4][16][68];
    int tid = threadIdx.x, w = tid >> 6, lane = tid & 63;
    int q = lane >> 4, l15 = lane & 15;
    int nw = blockIdx.x * 16;
    int sid = species_of(nw, counts);
    const f32x4 z4 = {0.f, 0.f, 0.f, 0.f};
    const bhalf8* wfv = (const bhalf8*)wf;
    const float* hs_mid = ws + OFF_HSMID;
    const float* hv_mid = ws + OFF_HVMID;
    const float* sks = ws + OFF_SKS;
    const float* skv = ws + OFF_SKV;
    const float* wscp = ws + OFF_WSCP;

    // Phase 1: linear_down
    {
        const float* src = (w == 0) ? hs_mid + (size_t)nw * 64
                                    : hv_mid + (size_t)nw * 192 + (w - 1) * 64;
        int rstride = (w == 0) ? 64 : 192;
        bhalf8 Ah[2], Al[2];
#pragma unroll
        for (int s = 0; s < 2; s++) {
            const float* rp = src + (size_t)l15 * rstride + s * 32 + q * 8;
            float4 a = *(const float4*)rp, b = *(const float4*)(rp + 4);
            float x[8] = {a.x, a.y, a.z, a.w, b.x, b.y, b.z, b.w};
#pragma unroll
            for (int j = 0; j < 8; j++) { short h, l; split_f32(x[j], h, l); Ah[s][j] = h; Al[s][j] = l; }
        }
        int mat = (w == 0) ? 22 : 23;
#pragma unroll
        for (int t = 0; t < 4; t++) {
            f32x4 acc = z4;
#pragma unroll
            for (int s = 0; s < 2; s++) {
                bhalf8 bh = wfv[(size_t)(mat * 16 + 0 + s * 4 + t) * 64 + lane];
                bhalf8 bl = wfv[(size_t)(mat * 16 + 8 + s * 4 + t) * 64 + lane];
                acc = __builtin_amdgcn_mfma_f32_16x16x32_bf16(Ah[s], bh, acc, 0, 0, 0);
                acc = __builtin_amdgcn_mfma_f32_16x16x32_bf16(Al[s], bh, acc, 0, 0, 0);
                acc = __builtin_amdgcn_mfma_f32_16x16x32_bf16(Ah[s], bl, acc, 0, 0, 0);
            }
#pragma unroll
            for (int r = 0; r < 4; r++)
                T[w][q * 4 + r][t * 16 + l15] = acc[r] * INV_F;
        }
    }
    __syncthreads();

    // Phase 2: symmetric contraction
    {
        int col = tid & 63, rg = tid >> 6;
        float wv[9];
#pragma unroll
        for (int b = 0; b < 9; b++) wv[b] = wscp[sid * 576 + b * 64 + col];
#pragma unroll
        for (int rr = 0; rr < 4; rr++) {
            int row = rg * 4 + rr;
            float hs = T[0][row][col];
            float h0 = T[1][row][col], h1 = T[2][row][col], h2 = T[3][row][col];
            float vv = h0 * h0 + h1 * h1 + h2 * h2;
            float cs = wv[0] * hs + wv[1] * hs * hs + wv[2] * vv
                     + wv[3] * hs * hs * hs + wv[4] * hs * vv;
            float fv = wv[5] + wv[6] * hs + wv[7] * hs * hs + wv[8] * vv;
            T[0][row][col] = cs;
            T[1][row][col] = h0 * fv;
            T[2][row][col] = h1 * fv;
            T[3][row][col] = h2 * fv;
        }
    }
    __syncthreads();

    // Phase 3: linear_sc + skip + store (+ readout on w0)
    {
        bhalf8 Ah[2], Al[2];
#pragma unroll
        for (int s = 0; s < 2; s++) {
            const float* rp = &T[w][l15][s * 32 + q * 8];
            float4 a = *(const float4*)rp, b = *(const float4*)(rp + 4);
            float x[8] = {a.x, a.y, a.z, a.w, b.x, b.y, b.z, b.w};
#pragma unroll
            for (int j = 0; j < 8; j++) { short h, l; split_f32(x[j], h, l); Ah[s][j] = h; Al[s][j] = l; }
        }
        int mat = (w == 0) ? 24 : 25;
        float* d_hs = out + N_NODES;
        float* d_hv = out + N_NODES + N_NODES * 64;
        float p[4] = {0.f, 0.f, 0.f, 0.f};
#pragma unroll
        for (int t = 0; t < 4; t++) {
            f32x4 acc = z4;
#pragma unroll
            for (int s = 0; s < 2; s++) {
                bhalf8 bh = wfv[(size_t)(mat * 16 + 0 + s * 4 + t) * 64 + lane];
                bhalf8 bl = wfv[(size_t)(mat * 16 + 8 + s * 4 + t) * 64 + lane];
                acc = __builtin_amdgcn_mfma_f32_16x16x32_bf16(Ah[s], bh, acc, 0, 0, 0);
                acc = __builtin_amdgcn_mfma_f32_16x16x32_bf16(Al[s], bh, acc, 0, 0, 0);
                acc = __builtin_amdgcn_mfma_f32_16x16x32_bf16(Ah[s], bl, acc, 0, 0, 0);
            }
            int col = t * 16 + l15;
            if (w == 0) {
                float wr = Wr[col];
#pragma unroll
                for (int r = 0; r < 4; r++) {
                    int gn = nw + q * 4 + r;
                    float v = acc[r] * INV_F + sks[(size_t)gn * 64 + col];
                    d_hs[(size_t)gn * 64 + col] = v;
                    p[r] += v * wr;
                }
            } else {
                int i = w - 1;
#pragma unroll
                for (int r = 0; r < 4; r++) {
                    int gn = nw + q * 4 + r;
                    float v = acc[r] * INV_F + skv[(size_t)gn * 192 + i * 64 + col];
                    d_hv[(size_t)gn * 192 + col * 3 + i] = v;
                }
            }
        }
        if (w == 0) {
#pragma unroll
            for (int r = 0; r < 4; r++) {
#pragma unroll
                for (int off = 1; off < 16; off <<= 1) p[r] += __shfl_xor(p[r], off, 64);
                if (l15 == 0) out[nw + q * 4 + r] = p[r] * INV_F;
            }
        }
    }
}

extern "C" void kernel_launch(void* const* d_in, const int* in_sizes, int n_in,
                              void* d_out, int out_size, void* d_ws, size_t ws_size,
                              hipStream_t stream) {
    const float* vectors   = (const float*)d_in[0];
    const float* node_s    = (const float*)d_in[1];
    const float* node_v    = (const float*)d_in[2];
    const float* radial    = (const float*)d_in[3];
    const int*   senders   = (const int*)d_in[4];
    const int*   receivers = (const int*)d_in[5];
    const int*   counts    = (const int*)d_in[6];
    const float* Wup0 = (const float*)d_in[7];
    const float* Wup1 = (const float*)d_in[8];
    const float* R1   = (const float*)d_in[9];
    const float* R2   = (const float*)d_in[10];
    const float* R3   = (const float*)d_in[11];
    const float* R4   = (const float*)d_in[12];
    const float* Wd0  = (const float*)d_in[13];
    const float* Wd1  = (const float*)d_in[14];
    const float* Ws0  = (const float*)d_in[15];
    const float* Ws1  = (const float*)d_in[16];
    const float* Wsc  = (const float*)d_in[17];
    const float* Proj = (const float*)d_in[18];
    const float* Wl0  = (const float*)d_in[19];
    const float* Wl1  = (const float*)d_in[20];
    const float* Wr   = (const float*)d_in[21];
    float* ws  = (float*)d_ws;
    float* out = (float*)d_out;
    unsigned short* frags = (unsigned short*)(ws + OFF_FRAGS);
    unsigned short* wbuf  = (unsigned short*)(ws + OFF_WBUF);
    float4* erec = (float4*)(ws + OFF_CSR);
    int* csr = (int*)(ws + OFF_CSR + 2 * CHUNK * 4);
    unsigned short* wf = (unsigned short*)(ws + OFF_WF);

    hipMemsetAsync(csr, 0, 2 * N_NODES * sizeof(int), stream);
    k_setup<<<(SU_HIST + 255) / 256, 256, 0, stream>>>(
        Wsc, Proj, ws + OFF_WSCP, R1, R2, R3, R4, frags,
        Wup0, Wup1, Ws0, Ws1, Wd0, Wd1, Wl0, Wl1, wf, receivers, csr);
    k_scan1<<<dim3(79, 2), 256, 0, stream>>>(csr);
    k_scan2<<<2, 128, 0, stream>>>(csr);
    k_scan3<<<dim3(79, 2), 256, 0, stream>>>(csr);
    k_bucket<<<E_EDGES / 256, 256, 0, stream>>>(vectors, senders, receivers, csr, erec);
    k_node_pre<<<N_NODES / 16, 256, 0, stream>>>(node_s, node_v, counts, wf, ws);
    for (int c = 0; c < 2; c++) {
        k_mlp<<<2500, 256, 0, stream>>>(radial, frags, csr, wbuf, c * CHUNK);
        k_tp_gather<<<N_NODES / 4, 256, 0, stream>>>(wbuf, csr, erec, ws, c, c);
    }
    k_node_post<<<N_NODES / 16, 256, 0, stream>>>(counts, wf, Wr, ws, out);
}

// Round 10
// 318.151 us; speedup vs baseline: 2.4091x; 1.0484x over previous
//
#include <hip/hip_runtime.h>
#include <hip/hip_bf16.h>
#include <hip/hip_fp16.h>
#include <math.h>

#define N_NODES 20000
#define FCH 64
#define ZSP 10
#define E_EDGES 320000
#define CHUNK 160000
#define RDIM 8
#define EPSC 0.25f
#define SQRT3C 1.7320508075688772f
#define INV_SQRT3C 0.57735026918962576f
#define INV_F 0.125f  /* 1/sqrt(64) */

// ---- workspace layout (float offsets) ----
#define OFF_EUP    0                               // (N,64) uint2 fp16x4 = N*128 floats
#define OFF_SKS    (N_NODES*256)                   // (N,64)
#define OFF_SKV    (OFF_SKS + N_NODES*64)          // (N,3,64) planar
#define OFF_HSMID  (OFF_SKV + N_NODES*192)         // (N,64)
#define OFF_HVMID  (OFF_HSMID + N_NODES*64)        // (N,3,64) planar
#define OFF_WSCP   (OFF_HVMID + N_NODES*192)       // (Z,9,64)
#define OFF_FRAGS  (OFF_WSCP + ZSP*576)            // 3328*8 ushort = 13312 floats
#define OFF_WBUF   (OFF_FRAGS + 13312)             // CHUNK*256 ushort = CHUNK*128 floats
#define OFF_CSR    (OFF_WBUF + CHUNK*128)          // erec float4[2*CHUNK], then ints
#define OFF_WF     (OFF_CSR + 2*CHUNK*4 + 400260)  // 416 slots * 512 ushort
// ints relative to csr int base (after erec):
#define CSR_CNT0   0
#define CSR_CNT1   20000
#define CSR_PTR0   40000
#define CSR_PTR1   60001
#define CSR_SEID   80002
#define CSR_AUX    400002   /* 2*128 block totals */

// k_setup gid ranges
#define SU_WSC   5760                  /* 10*576 */
#define SU_PREP  (SU_WSC + 3328)
#define SU_PREP2 (SU_PREP + 26624)     /* 416*64 */
#define SU_HIST  (SU_PREP2 + E_EDGES)

typedef __attribute__((ext_vector_type(8))) short bhalf8;
typedef __attribute__((ext_vector_type(4))) float f32x4;

// fast silu: v_exp_f32 + v_rcp_f32 (err ~1ulp, negligible vs bf16 quantization)
__device__ __forceinline__ float silu_f(float x) {
    float e = __builtin_amdgcn_exp2f(x * -1.442695040888963f);
    return x * __builtin_amdgcn_rcpf(1.0f + e);
}

__device__ __forceinline__ unsigned short f2bf(float x) {
    unsigned int u = __float_as_uint(x);
    unsigned int r = u + 0x7FFFu + ((u >> 16) & 1u);   // RNE
    return (unsigned short)(r >> 16);
}

// packed pair -> one dword (lo in low 16); v_cvt_pk_bf16_f32 on gfx950
__device__ __forceinline__ unsigned int pack_bf2(float lo, float hi) {
    __hip_bfloat162 b = __float22bfloat162_rn(make_float2(lo, hi));
    return *(unsigned int*)&b;
}

__device__ __forceinline__ bhalf8 mk8(unsigned a, unsigned b, unsigned c, unsigned d) {
    uint4 u; u.x = a; u.y = b; u.z = c; u.w = d;
    return *(bhalf8*)&u;
}

__device__ __forceinline__ float half_lo(unsigned v) {
    return __half2float(__ushort_as_half((unsigned short)(v & 0xFFFFu)));
}
__device__ __forceinline__ float half_hi(unsigned v) {
    return __half2float(__ushort_as_half((unsigned short)(v >> 16)));
}

// split fp32 -> bf16 hi (trunc) + bf16 lo (trunc of residual); err ~2^-16 rel
__device__ __forceinline__ void split_f32(float x, short& h, short& l) {
    unsigned int u = __float_as_uint(x);
    unsigned int hb = u & 0xFFFF0000u;
    h = (short)(u >> 16);
    float r = x - __uint_as_float(hb);
    l = (short)(__float_as_uint(r) >> 16);
}

__device__ __forceinline__ int species_of(int n, const int* counts) {
    int acc = 0, s = ZSP - 1;
#pragma unroll
    for (int z = 0; z < ZSP; z++) {
        int c = counts[z];
        if (n >= acc && n < acc + c) s = z;
        acc += c;
    }
    return s;
}

// K-setup: fused wscproj + prep(MLP frags) + prep2(node frags) + hist.
__global__ __launch_bounds__(256) void k_setup(
    const float* __restrict__ Wsc, const float* __restrict__ Proj, float* __restrict__ wscp,
    const float* __restrict__ R1, const float* __restrict__ R2,
    const float* __restrict__ R3, const float* __restrict__ R4,
    unsigned short* __restrict__ frags,
    const float* __restrict__ Wup0, const float* __restrict__ Wup1,
    const float* __restrict__ Ws0, const float* __restrict__ Ws1,
    const float* __restrict__ Wd0, const float* __restrict__ Wd1,
    const float* __restrict__ Wl0, const float* __restrict__ Wl1,
    unsigned short* __restrict__ wf,
    const int* __restrict__ receivers, int* __restrict__ csr) {
    int gid = blockIdx.x * 256 + threadIdx.x;
    if (gid < SU_WSC) {
        int z = gid / 576, t = gid % 576;
        int b = t >> 6, u = t & 63;
        float acc = 0.f;
#pragma unroll
        for (int p = 0; p < 9; p++) acc += Wsc[z * 576 + p * 64 + u] * Proj[p * 9 + b];
        wscp[z * 576 + b * 64 + u] = acc;
    } else if (gid < SU_PREP) {
        int id = gid - SU_WSC;
        int lane = id & 63, fi = id >> 6;
        int quad = lane >> 4, l15 = lane & 15;
        const float* W;
        int s, t, N;
        bool r1 = false;
        if (fi < 4)       { W = R1; s = 0; t = fi; N = 64; r1 = true; }
        else if (fi < 12) { W = R2; int x = fi - 4;  s = x >> 2; t = x & 3;  N = 64; }
        else if (fi < 20) { W = R3; int x = fi - 12; s = x >> 2; t = x & 3;  N = 64; }
        else              { W = R4; int x = fi - 20; s = x >> 4; t = x & 15; N = 256; }
        unsigned int v[4];
#pragma unroll
        for (int jj = 0; jj < 4; jj++) {
            unsigned short pk2[2];
#pragma unroll
            for (int o = 0; o < 2; o++) {
                int j = jj * 2 + o;
                int k = s * 32 + quad * 8 + j, n = t * 16 + l15;
                float val = (r1 && k >= RDIM) ? 0.f : W[k * N + n];
                pk2[o] = f2bf(val);
            }
            v[jj] = (unsigned int)pk2[0] | ((unsigned int)pk2[1] << 16);
        }
        uint4 pk; pk.x = v[0]; pk.y = v[1]; pk.z = v[2]; pk.w = v[3];
        ((uint4*)frags)[id] = pk;
    } else if (gid < SU_PREP2) {
        int id = gid - SU_PREP;
        int lane = id & 63, slot = id >> 6;
        int t = slot & 3, s = (slot >> 2) & 1, part = (slot >> 3) & 1, mat = slot >> 4;
        int quad = lane >> 4, l15 = lane & 15;
        const float* W;
        if (mat == 0)       W = Wup0;
        else if (mat == 1)  W = Wup1;
        else if (mat < 12)  W = Ws0 + (mat - 2) * 4096;
        else if (mat < 22)  W = Ws1 + (mat - 12) * 4096;
        else if (mat == 22) W = Wd0;
        else if (mat == 23) W = Wd1;
        else if (mat == 24) W = Wl0;
        else                W = Wl1;
        unsigned int v[4];
#pragma unroll
        for (int jj = 0; jj < 4; jj++) {
            unsigned short pk2[2];
#pragma unroll
            for (int o = 0; o < 2; o++) {
                int j = jj * 2 + o;
                int k = s * 32 + quad * 8 + j, n = t * 16 + l15;
                float x = W[k * 64 + n];
                short h, l;
                split_f32(x, h, l);
                pk2[o] = part == 0 ? (unsigned short)h : (unsigned short)l;
            }
            v[jj] = (unsigned int)pk2[0] | ((unsigned int)pk2[1] << 16);
        }
        uint4 pk; pk.x = v[0]; pk.y = v[1]; pk.z = v[2]; pk.w = v[3];
        ((uint4*)wf)[id] = pk;
    } else if (gid < SU_HIST) {
        int e = gid - SU_PREP2;
        int base = (e < CHUNK) ? CSR_CNT0 : CSR_CNT1;
        atomicAdd(&csr[base + receivers[e]], 1);
    }
}

// 3-phase parallel scan. Phase 1: per-block (256) exclusive scan + block total.
__global__ __launch_bounds__(256) void k_scan1(int* __restrict__ csr) {
    __shared__ int sb[256];
    int z = blockIdx.y, b = blockIdx.x, t = threadIdx.x;
    int i = b * 256 + t;
    int cb = z ? CSR_CNT1 : CSR_CNT0;
    int pb = z ? CSR_PTR1 : CSR_PTR0;
    int x = (i < N_NODES) ? csr[cb + i] : 0;
    sb[t] = x;
    __syncthreads();
#pragma unroll
    for (int off = 1; off < 256; off <<= 1) {
        int v = (t >= off) ? sb[t - off] : 0;
        __syncthreads();
        sb[t] += v;
        __syncthreads();
    }
    if (i < N_NODES) csr[pb + i] = sb[t] - x;      // block-local exclusive
    if (t == 255) csr[CSR_AUX + z * 128 + b] = sb[255];
}

// Phase 2: scan the 79 block totals per chunk.
__global__ __launch_bounds__(128) void k_scan2(int* __restrict__ csr) {
    __shared__ int sb[128];
    int z = blockIdx.x, t = threadIdx.x;
    int pb = z ? CSR_PTR1 : CSR_PTR0;
    int x = (t < 79) ? csr[CSR_AUX + z * 128 + t] : 0;
    sb[t] = x;
    __syncthreads();
#pragma unroll
    for (int off = 1; off < 128; off <<= 1) {
        int v = (t >= off) ? sb[t - off] : 0;
        __syncthreads();
        sb[t] += v;
        __syncthreads();
    }
    csr[CSR_AUX + z * 128 + t] = sb[t] - x;
    if (t == 127) csr[pb + N_NODES] = sb[127];
}

// Phase 3: add block offsets; write final ptr and cursor.
__global__ __launch_bounds__(256) void k_scan3(int* __restrict__ csr) {
    int z = blockIdx.y, b = blockIdx.x, t = threadIdx.x;
    int i = b * 256 + t;
    if (i >= N_NODES) return;
    int cb = z ? CSR_CNT1 : CSR_CNT0;
    int pb = z ? CSR_PTR1 : CSR_PTR0;
    int v = csr[pb + i] + csr[CSR_AUX + z * 128 + b];
    csr[pb + i] = v;
    csr[cb + i] = v;   // cursor for bucketing
}

// CSR build: bucket edges; precompute Y1 + sender per slot.
__global__ __launch_bounds__(256) void k_bucket(
    const float* __restrict__ vectors, const int* __restrict__ senders,
    const int* __restrict__ receivers, int* __restrict__ csr,
    float4* __restrict__ erec) {
    int e = blockIdx.x * 256 + threadIdx.x;
    if (e >= E_EDGES) return;
    int z = (e < CHUNK) ? 0 : 1;
    int base = z ? CSR_CNT1 : CSR_CNT0;
    int pos = atomicAdd(&csr[base + receivers[e]], 1);
    float v0 = vectors[e * 3 + 0], v1 = vectors[e * 3 + 1], v2 = vectors[e * 3 + 2];
    float s = SQRT3C * rsqrtf(v0 * v0 + v1 * v1 + v2 * v2);
    int idx = z * CHUNK + pos;
    csr[CSR_SEID + idx] = e;
    float4 r;
    r.x = v0 * s; r.y = v1 * s; r.z = v2 * s; r.w = __int_as_float(senders[e]);
    erec[idx] = r;
}

// K1: linear_up + species skip via split-bf16 MFMA.
// linear_up outputs packed as fp16x4 (es,e0,e1,e2) per (node,f) via LDS staging
// (all 4 waves of a block produce the 4 components of the same 16 nodes).
__global__ __launch_bounds__(256) void k_node_pre(
    const float* __restrict__ ns, const float* __restrict__ nv,
    const int* __restrict__ counts, const unsigned short* __restrict__ wf,
    float* __restrict__ ws) {
    __shared__ uint2 eup_t[16][64];   // 8 KB
    int tid = threadIdx.x, w = tid >> 6, lane = tid & 63;
    int q = lane >> 4, l15 = lane & 15;
    int nw = blockIdx.x * 16;
    int sid = species_of(nw, counts);
    const f32x4 z4 = {0.f, 0.f, 0.f, 0.f};

    bhalf8 Ah[2], Al[2];
    if (w == 0) {
#pragma unroll
        for (int s = 0; s < 2; s++) {
            const float* rp = ns + (size_t)(nw + l15) * 64 + s * 32 + q * 8;
            float4 a = *(const float4*)rp, b = *(const float4*)(rp + 4);
            float x[8] = {a.x, a.y, a.z, a.w, b.x, b.y, b.z, b.w};
#pragma unroll
            for (int j = 0; j < 8; j++) { short h, l; split_f32(x[j], h, l); Ah[s][j] = h; Al[s][j] = l; }
        }
    } else {
        int i = w - 1;
#pragma unroll
        for (int s = 0; s < 2; s++) {
            const float* rp = nv + (size_t)(nw + l15) * 192 + i;
#pragma unroll
            for (int j = 0; j < 8; j++) {
                float x = rp[(s * 32 + q * 8 + j) * 3];
                short h, l; split_f32(x, h, l); Ah[s][j] = h; Al[s][j] = l;
            }
        }
    }

    const bhalf8* wfv = (const bhalf8*)wf;
    float* sks = ws + OFF_SKS;
    float* skv = ws + OFF_SKV;

    // m=0: linear_up -> fp16 packed LDS tile
    {
        int mat = (w == 0) ? 0 : 1;
#pragma unroll
        for (int t = 0; t < 4; t++) {
            f32x4 acc = z4;
#pragma unroll
            for (int s = 0; s < 2; s++) {
                bhalf8 bh = wfv[(size_t)(mat * 16 + 0 + s * 4 + t) * 64 + lane];
                bhalf8 bl = wfv[(size_t)(mat * 16 + 8 + s * 4 + t) * 64 + lane];
                acc = __builtin_amdgcn_mfma_f32_16x16x32_bf16(Ah[s], bh, acc, 0, 0, 0);
                acc = __builtin_amdgcn_mfma_f32_16x16x32_bf16(Al[s], bh, acc, 0, 0, 0);
                acc = __builtin_amdgcn_mfma_f32_16x16x32_bf16(Ah[s], bl, acc, 0, 0, 0);
            }
#pragma unroll
            for (int r = 0; r < 4; r++) {
                unsigned short us = __half_as_ushort(__float2half_rn(acc[r] * INV_F));
                ((unsigned short*)&eup_t[q * 4 + r][t * 16 + l15])[w] = us;
            }
        }
    }
    // m=1: species skip -> fp32 tables (unchanged)
    {
        int mat = (w == 0) ? 2 + sid : 12 + sid;
        float* dst = (w == 0) ? sks : skv;
        int stride = (w == 0) ? 64 : 192;
        int off = (w == 0) ? 0 : (w - 1) * 64;
#pragma unroll
        for (int t = 0; t < 4; t++) {
            f32x4 acc = z4;
#pragma unroll
            for (int s = 0; s < 2; s++) {
                bhalf8 bh = wfv[(size_t)(mat * 16 + 0 + s * 4 + t) * 64 + lane];
                bhalf8 bl = wfv[(size_t)(mat * 16 + 8 + s * 4 + t) * 64 + lane];
                acc = __builtin_amdgcn_mfma_f32_16x16x32_bf16(Ah[s], bh, acc, 0, 0, 0);
                acc = __builtin_amdgcn_mfma_f32_16x16x32_bf16(Al[s], bh, acc, 0, 0, 0);
                acc = __builtin_amdgcn_mfma_f32_16x16x32_bf16(Ah[s], bl, acc, 0, 0, 0);
            }
#pragma unroll
            for (int r = 0; r < 4; r++)
                dst[(size_t)(nw + q * 4 + r) * stride + off + t * 16 + l15] = acc[r] * INV_F;
        }
    }
    __syncthreads();
    uint2* eup = (uint2*)(ws + OFF_EUP);
    for (int k = tid; k < 1024; k += 256) {
        int n = k >> 6, f = k & 63;
        eup[(size_t)(nw + n) * 64 + f] = eup_t[n][f];
    }
}

// Cross-lane frag builder (see R9 derivation).
template<int S>
__device__ __forceinline__ bhalf8 xfrag(const unsigned* pkA, const unsigned* pkB,
                                        int q, int l15) {
    int L0 = ((q & 1) << 5) + l15;
    int L1 = L0 + 16;
    bool hi = (q >> 1) != 0;
    unsigned a0 = (unsigned)__shfl((int)pkA[2 * S], L0, 64);
    unsigned a1 = (unsigned)__shfl((int)pkA[2 * S + 1], L0, 64);
    unsigned b0 = (unsigned)__shfl((int)pkB[2 * S], L0, 64);
    unsigned b1 = (unsigned)__shfl((int)pkB[2 * S + 1], L0, 64);
    unsigned c0 = (unsigned)__shfl((int)pkA[2 * S], L1, 64);
    unsigned c1 = (unsigned)__shfl((int)pkA[2 * S + 1], L1, 64);
    unsigned e0 = (unsigned)__shfl((int)pkB[2 * S], L1, 64);
    unsigned e1 = (unsigned)__shfl((int)pkB[2 * S + 1], L1, 64);
    return mk8(hi ? a1 : a0, hi ? b1 : b0, hi ? c1 : c0, hi ? e1 : e0);
}

// K2a: radial MLP via bf16 MFMA, CSR-sorted order, register-shuffle act pass.
__global__ __launch_bounds__(256) void k_mlp(
    const float* __restrict__ radial, const unsigned short* __restrict__ frags,
    const int* __restrict__ csr, unsigned short* __restrict__ wbuf, int e_base) {
    __shared__ unsigned short r4lds[16384];   // 32 KB
    int tid = threadIdx.x;
    int lane = tid & 63, w = tid >> 6, quad = lane >> 4, l15 = lane & 15;

    const uint4* r4g = (const uint4*)(frags + 20 * 64 * 8);
    uint4* r4l = (uint4*)r4lds;
    for (int i = tid; i < 2048; i += 256) r4l[i] = r4g[i];
    const bhalf8* fr = (const bhalf8*)frags;
    bhalf8 r1f[4], r2f[2][4], r3f[2][4];
#pragma unroll
    for (int t = 0; t < 4; t++) r1f[t] = fr[t * 64 + lane];
#pragma unroll
    for (int s = 0; s < 2; s++)
#pragma unroll
        for (int t = 0; t < 4; t++) {
            r2f[s][t] = fr[(4 + s * 4 + t) * 64 + lane];
            r3f[s][t] = fr[(12 + s * 4 + t) * 64 + lane];
        }
    __syncthreads();

    const f32x4 z4 = {0.f, 0.f, 0.f, 0.f};
    const bhalf8* r4f = (const bhalf8*)r4lds;

    int el0 = (blockIdx.x * 4 + w) * 16;   // chunk-local sorted slot base

    bhalf8 af = {0, 0, 0, 0, 0, 0, 0, 0};
    if (quad == 0) {
        int eid = csr[CSR_SEID + e_base + el0 + l15];  // global edge id
        const float* rp = radial + (size_t)eid * 8;
        float4 ra = *(const float4*)rp;
        float4 rb = *(const float4*)(rp + 4);
        af[0] = (short)f2bf(ra.x); af[1] = (short)f2bf(ra.y);
        af[2] = (short)f2bf(ra.z); af[3] = (short)f2bf(ra.w);
        af[4] = (short)f2bf(rb.x); af[5] = (short)f2bf(rb.y);
        af[6] = (short)f2bf(rb.z); af[7] = (short)f2bf(rb.w);
    }
    unsigned pkA[4], pkB[4];
    {
        f32x4 acc[4];
#pragma unroll
        for (int t = 0; t < 4; t++)
            acc[t] = __builtin_amdgcn_mfma_f32_16x16x32_bf16(r1f[t], af, z4, 0, 0, 0);
#pragma unroll
        for (int t = 0; t < 4; t++) {
            pkA[t] = pack_bf2(silu_f(acc[t][0]), silu_f(acc[t][1]));
            pkB[t] = pack_bf2(silu_f(acc[t][2]), silu_f(acc[t][3]));
        }
    }
#pragma unroll
    for (int layer = 0; layer < 2; layer++) {
        bhalf8 b0 = xfrag<0>(pkA, pkB, quad, l15);
        bhalf8 b1 = xfrag<1>(pkA, pkB, quad, l15);
        f32x4 acc[4];
#pragma unroll
        for (int t = 0; t < 4; t++) {
            bhalf8 w0 = layer == 0 ? r2f[0][t] : r3f[0][t];
            bhalf8 w1 = layer == 0 ? r2f[1][t] : r3f[1][t];
            acc[t] = __builtin_amdgcn_mfma_f32_16x16x32_bf16(
                w1, b1, __builtin_amdgcn_mfma_f32_16x16x32_bf16(w0, b0, z4, 0, 0, 0), 0, 0, 0);
        }
#pragma unroll
        for (int t = 0; t < 4; t++) {
            pkA[t] = pack_bf2(silu_f(acc[t][0]), silu_f(acc[t][1]));
            pkB[t] = pack_bf2(silu_f(acc[t][2]), silu_f(acc[t][3]));
        }
    }
    {
        bhalf8 a0 = xfrag<0>(pkA, pkB, quad, l15);
        bhalf8 a1 = xfrag<1>(pkA, pkB, quad, l15);
#pragma unroll
        for (int t4 = 0; t4 < 4; t4++) {
            f32x4 p0 = __builtin_amdgcn_mfma_f32_16x16x32_bf16(
                a1, r4f[(16 + t4) * 64 + lane],
                __builtin_amdgcn_mfma_f32_16x16x32_bf16(a0, r4f[t4 * 64 + lane], z4, 0, 0, 0), 0, 0, 0);
            f32x4 p1 = __builtin_amdgcn_mfma_f32_16x16x32_bf16(
                a1, r4f[(20 + t4) * 64 + lane],
                __builtin_amdgcn_mfma_f32_16x16x32_bf16(a0, r4f[(4 + t4) * 64 + lane], z4, 0, 0, 0), 0, 0, 0);
            f32x4 p2 = __builtin_amdgcn_mfma_f32_16x16x32_bf16(
                a1, r4f[(24 + t4) * 64 + lane],
                __builtin_amdgcn_mfma_f32_16x16x32_bf16(a0, r4f[(8 + t4) * 64 + lane], z4, 0, 0, 0), 0, 0, 0);
            f32x4 p3 = __builtin_amdgcn_mfma_f32_16x16x32_bf16(
                a1, r4f[(28 + t4) * 64 + lane],
                __builtin_amdgcn_mfma_f32_16x16x32_bf16(a0, r4f[(12 + t4) * 64 + lane], z4, 0, 0, 0), 0, 0, 0);
#pragma unroll
            for (int r = 0; r < 4; r++) {
                int el = el0 + quad * 4 + r;
                int f = t4 * 16 + l15;
                uint2 pk;
                pk.x = pack_bf2(p0[r], p1[r]);
                pk.y = pack_bf2(p2[r], p3[r]);
                ((uint2*)wbuf)[(size_t)el * 64 + f] = pk;
            }
        }
    }
}

// K2b: CSR gather TP; packed fp16x4 eup table (1 gather load/edge), depth-2 pipeline.
__global__ __launch_bounds__(256) void k_tp_gather(
    const unsigned short* __restrict__ wbuf, const int* __restrict__ csr,
    const float4* __restrict__ erec, float* __restrict__ ws,
    int z, int accum) {
    int tid = threadIdx.x, w = tid >> 6, f = tid & 63;
    int n = blockIdx.x * 4 + w;
    const uint2* eup = (const uint2*)(ws + OFF_EUP);
    float* hs_mid = ws + OFF_HSMID;
    float* hv_mid = ws + OFF_HVMID;
    int pb = z ? CSR_PTR1 : CSR_PTR0;
    int beg = csr[pb + n], end = csr[pb + n + 1];
    int e_base = z * CHUNK;
    float ams = 0.f, am0 = 0.f, am1 = 0.f, am2 = 0.f;

    if (beg < end) {
        int last = end - 1;
        float4 rcA = erec[e_base + beg];
        uint2 wrA = ((const uint2*)wbuf)[(size_t)beg * 64 + f];
        uint2 evA = eup[(size_t)__float_as_int(rcA.w) * 64 + f];
        int j1 = (beg + 1 < end) ? beg + 1 : last;
        float4 rcB = erec[e_base + j1];
        uint2 wrB = ((const uint2*)wbuf)[(size_t)j1 * 64 + f];
        uint2 evB = eup[(size_t)__float_as_int(rcB.w) * 64 + f];

        for (int i = beg; i < end; i++) {
            int j2 = (i + 2 < end) ? i + 2 : last;
            float4 rcC = erec[e_base + j2];
            uint2 wrC = ((const uint2*)wbuf)[(size_t)j2 * 64 + f];
            uint2 evC = eup[(size_t)__float_as_int(rcC.w) * 64 + f];
            // compute batch A
            float esA = half_lo(evA.x), eA0 = half_hi(evA.x);
            float eA1 = half_lo(evA.y), eA2 = half_hi(evA.y);
            float w0 = __uint_as_float(wrA.x << 16);
            float w1 = __uint_as_float(wrA.x & 0xFFFF0000u);
            float w2 = __uint_as_float(wrA.y << 16);
            float w3 = __uint_as_float(wrA.y & 0xFFFF0000u);
            float dot = eA0 * rcA.x + eA1 * rcA.y + eA2 * rcA.z;
            ams += w0 * esA + w1 * dot * INV_SQRT3C;
            float t3 = w3 * esA * INV_SQRT3C;
            am0 += w2 * eA0 + t3 * rcA.x;
            am1 += w2 * eA1 + t3 * rcA.y;
            am2 += w2 * eA2 + t3 * rcA.z;
            rcA = rcB; wrA = wrB; evA = evB;
            rcB = rcC; wrB = wrC; evB = evC;
        }
    }
    if (!accum) {
        hs_mid[n * 64 + f] = ams;
        hv_mid[n * 192 + f] = am0;
        hv_mid[n * 192 + 64 + f] = am1;
        hv_mid[n * 192 + 128 + f] = am2;
    } else {
        hs_mid[n * 64 + f] = (hs_mid[n * 64 + f] + ams) * EPSC;
        hv_mid[n * 192 + f] = (hv_mid[n * 192 + f] + am0) * EPSC;
        hv_mid[n * 192 + 64 + f] = (hv_mid[n * 192 + 64 + f] + am1) * EPSC;
        hv_mid[n * 192 + 128 + f] = (hv_mid[n * 192 + 128 + f] + am2) * EPSC;
    }
}

// K3: linear_down + contraction + linear_sc + skip + readout via split-bf16 MFMA.
__global__ __launch_bounds__(256) void k_node_post(
    const int* __restrict__ counts, const unsigned short* __restrict__ wf,
    const float* __restrict__ Wr, float* __restrict__ ws, float* __restrict__ out) {
    __shared__ float T[4][16][68];
    int tid = threadIdx.x, w = tid >> 6, lane = tid & 63;
    int q = lane >> 4, l15 = lane & 15;
    int nw = blockIdx.x * 16;
    int sid = species_of(nw, counts);
    const f32x4 z4 = {0.f, 0.f, 0.f, 0.f};
    const bhalf8* wfv = (const bhalf8*)wf;
    const float* hs_mid = ws + OFF_HSMID;
    const float* hv_mid = ws + OFF_HVMID;
    const float* sks = ws + OFF_SKS;
    const float* skv = ws + OFF_SKV;
    const float* wscp = ws + OFF_WSCP;

    // Phase 1: linear_down
    {
        const float* src = (w == 0) ? hs_mid + (size_t)nw * 64
                                    : hv_mid + (size_t)nw * 192 + (w - 1) * 64;
        int rstride = (w == 0) ? 64 : 192;
        bhalf8 Ah[2], Al[2];
#pragma unroll
        for (int s = 0; s < 2; s++) {
            const float* rp = src + (size_t)l15 * rstride + s * 32 + q * 8;
            float4 a = *(const float4*)rp, b = *(const float4*)(rp + 4);
            float x[8] = {a.x, a.y, a.z, a.w, b.x, b.y, b.z, b.w};
#pragma unroll
            for (int j = 0; j < 8; j++) { short h, l; split_f32(x[j], h, l); Ah[s][j] = h; Al[s][j] = l; }
        }
        int mat = (w == 0) ? 22 : 23;
#pragma unroll
        for (int t = 0; t < 4; t++) {
            f32x4 acc = z4;
#pragma unroll
            for (int s = 0; s < 2; s++) {
                bhalf8 bh = wfv[(size_t)(mat * 16 + 0 + s * 4 + t) * 64 + lane];
                bhalf8 bl = wfv[(size_t)(mat * 16 + 8 + s * 4 + t) * 64 + lane];
                acc = __builtin_amdgcn_mfma_f32_16x16x32_bf16(Ah[s], bh, acc, 0, 0, 0);
                acc = __builtin_amdgcn_mfma_f32_16x16x32_bf16(Al[s], bh, acc, 0, 0, 0);
                acc = __builtin_amdgcn_mfma_f32_16x16x32_bf16(Ah[s], bl, acc, 0, 0, 0);
            }
#pragma unroll
            for (int r = 0; r < 4; r++)
                T[w][q * 4 + r][t * 16 + l15] = acc[r] * INV_F;
        }
    }
    __syncthreads();

    // Phase 2: symmetric contraction
    {
        int col = tid & 63, rg = tid >> 6;
        float wv[9];
#pragma unroll
        for (int b = 0; b < 9; b++) wv[b] = wscp[sid * 576 + b * 64 + col];
#pragma unroll
        for (int rr = 0; rr < 4; rr++) {
            int row = rg * 4 + rr;
            float hs = T[0][row][col];
            float h0 = T[1][row][col], h1 = T[2][row][col], h2 = T[3][row][col];
            float vv = h0 * h0 + h1 * h1 + h2 * h2;
            float cs = wv[0] * hs + wv[1] * hs * hs + wv[2] * vv
                     + wv[3] * hs * hs * hs + wv[4] * hs * vv;
            float fv = wv[5] + wv[6] * hs + wv[7] * hs * hs + wv[8] * vv;
            T[0][row][col] = cs;
            T[1][row][col] = h0 * fv;
            T[2][row][col] = h1 * fv;
            T[3][row][col] = h2 * fv;
        }
    }
    __syncthreads();

    // Phase 3: linear_sc + skip + store (+ readout on w0)
    {
        bhalf8 Ah[2], Al[2];
#pragma unroll
        for (int s = 0; s < 2; s++) {
            const float* rp = &T[w][l15][s * 32 + q * 8];
            float4 a = *(const float4*)rp, b = *(const float4*)(rp + 4);
            float x[8] = {a.x, a.y, a.z, a.w, b.x, b.y, b.z, b.w};
#pragma unroll
            for (int j = 0; j < 8; j++) { short h, l; split_f32(x[j], h, l); Ah[s][j] = h; Al[s][j] = l; }
        }
        int mat = (w == 0) ? 24 : 25;
        float* d_hs = out + N_NODES;
        float* d_hv = out + N_NODES + N_NODES * 64;
        float p[4] = {0.f, 0.f, 0.f, 0.f};
#pragma unroll
        for (int t = 0; t < 4; t++) {
            f32x4 acc = z4;
#pragma unroll
            for (int s = 0; s < 2; s++) {
                bhalf8 bh = wfv[(size_t)(mat * 16 + 0 + s * 4 + t) * 64 + lane];
                bhalf8 bl = wfv[(size_t)(mat * 16 + 8 + s * 4 + t) * 64 + lane];
                acc = __builtin_amdgcn_mfma_f32_16x16x32_bf16(Ah[s], bh, acc, 0, 0, 0);
                acc = __builtin_amdgcn_mfma_f32_16x16x32_bf16(Al[s], bh, acc, 0, 0, 0);
                acc = __builtin_amdgcn_mfma_f32_16x16x32_bf16(Ah[s], bl, acc, 0, 0, 0);
            }
            int col = t * 16 + l15;
            if (w == 0) {
                float wr = Wr[col];
#pragma unroll
                for (int r = 0; r < 4; r++) {
                    int gn = nw + q * 4 + r;
                    float v = acc[r] * INV_F + sks[(size_t)gn * 64 + col];
                    d_hs[(size_t)gn * 64 + col] = v;
                    p[r] += v * wr;
                }
            } else {
                int i = w - 1;
#pragma unroll
                for (int r = 0; r < 4; r++) {
                    int gn = nw + q * 4 + r;
                    float v = acc[r] * INV_F + skv[(size_t)gn * 192 + i * 64 + col];
                    d_hv[(size_t)gn * 192 + col * 3 + i] = v;
                }
            }
        }
        if (w == 0) {
#pragma unroll
            for (int r = 0; r < 4; r++) {
#pragma unroll
                for (int off = 1; off < 16; off <<= 1) p[r] += __shfl_xor(p[r], off, 64);
                if (l15 == 0) out[nw + q * 4 + r] = p[r] * INV_F;
            }
        }
    }
}

extern "C" void kernel_launch(void* const* d_in, const int* in_sizes, int n_in,
                              void* d_out, int out_size, void* d_ws, size_t ws_size,
                              hipStream_t stream) {
    const float* vectors   = (const float*)d_in[0];
    const float* node_s    = (const float*)d_in[1];
    const float* node_v    = (const float*)d_in[2];
    const float* radial    = (const float*)d_in[3];
    const int*   senders   = (const int*)d_in[4];
    const int*   receivers = (const int*)d_in[5];
    const int*   counts    = (const int*)d_in[6];
    const float* Wup0 = (const float*)d_in[7];
    const float* Wup1 = (const float*)d_in[8];
    const float* R1   = (const float*)d_in[9];
    const float* R2   = (const float*)d_in[10];
    const float* R3   = (const float*)d_in[11];
    const float* R4   = (const float*)d_in[12];
    const float* Wd0  = (const float*)d_in[13];
    const float* Wd1  = (const float*)d_in[14];
    const float* Ws0  = (const float*)d_in[15];
    const float* Ws1  = (const float*)d_in[16];
    const float* Wsc  = (const float*)d_in[17];
    const float* Proj = (const float*)d_in[18];
    const float* Wl0  = (const float*)d_in[19];
    const float* Wl1  = (const float*)d_in[20];
    const float* Wr   = (const float*)d_in[21];
    float* ws  = (float*)d_ws;
    float* out = (float*)d_out;
    unsigned short* frags = (unsigned short*)(ws + OFF_FRAGS);
    unsigned short* wbuf  = (unsigned short*)(ws + OFF_WBUF);
    float4* erec = (float4*)(ws + OFF_CSR);
    int* csr = (int*)(ws + OFF_CSR + 2 * CHUNK * 4);
    unsigned short* wf = (unsigned short*)(ws + OFF_WF);

    hipMemsetAsync(csr, 0, 2 * N_NODES * sizeof(int), stream);
    k_setup<<<(SU_HIST + 255) / 256, 256, 0, stream>>>(
        Wsc, Proj, ws + OFF_WSCP, R1, R2, R3, R4, frags,
        Wup0, Wup1, Ws0, Ws1, Wd0, Wd1, Wl0, Wl1, wf, receivers, csr);
    k_scan1<<<dim3(79, 2), 256, 0, stream>>>(csr);
    k_scan2<<<2, 128, 0, stream>>>(csr);
    k_scan3<<<dim3(79, 2), 256, 0, stream>>>(csr);
    k_bucket<<<E_EDGES / 256, 256, 0, stream>>>(vectors, senders, receivers, csr, erec);
    k_node_pre<<<N_NODES / 16, 256, 0, stream>>>(node_s, node_v, counts, wf, ws);
    for (int c = 0; c < 2; c++) {
        k_mlp<<<2500, 256, 0, stream>>>(radial, frags, csr, wbuf, c * CHUNK);
        k_tp_gather<<<N_NODES / 4, 256, 0, stream>>>(wbuf, csr, erec, ws, c, c);
    }
    k_node_post<<<N_NODES / 16, 256, 0, stream>>>(counts, wf, Wr, ws, out);
}

// Round 12
// 301.517 us; speedup vs baseline: 2.5420x; 1.0552x over previous
//
#include <hip/hip_runtime.h>
#include <hip/hip_bf16.h>
#include <hip/hip_fp16.h>
#include <math.h>

#define N_NODES 20000
#define FCH 64
#define ZSP 10
#define E_EDGES 320000
#define RDIM 8
#define EPSC 0.25f
#define SQRT3C 1.7320508075688772f
#define INV_SQRT3C 0.57735026918962576f
#define INV_F 0.125f  /* 1/sqrt(64) */

// ---- workspace layout (float offsets) ----
#define OFF_EUP    0                               // (N,64) uint2 fp16x4 = N*128 floats
#define OFF_SKS    (N_NODES*128)                   // (N,64)
#define OFF_SKV    (OFF_SKS + N_NODES*64)          // (N,3,64) planar
#define OFF_HSMID  (OFF_SKV + N_NODES*192)         // (N,64)
#define OFF_HVMID  (OFF_HSMID + N_NODES*64)        // (N,3,64) planar
#define OFF_WSCP   (OFF_HVMID + N_NODES*192)       // (Z,9,64)
#define OFF_FRAGS  (OFF_WSCP + ZSP*576)            // 3328*8 ushort = 13312 floats
#define OFF_WBUF   (OFF_FRAGS + 13312)             // E*64 uint2 = E*128 floats (fp16 w)
#define OFF_CSR    (OFF_WBUF + E_EDGES*128)        // erec float4[E], then ints
#define OFF_WF     (OFF_CSR + E_EDGES*4 + 360132)  // 416 slots * 512 ushort
// ints relative to csr int base (after erec):
#define CSR_CNT    0        /* 20000, becomes cursor after scan */
#define CSR_PTR    20000    /* 20001 */
#define CSR_SEID   40001    /* E */
#define CSR_AUX    360001   /* 128 block totals */

// k_setup gid ranges
#define SU_WSC   5760                  /* 10*576 */
#define SU_PREP  (SU_WSC + 3328)
#define SU_PREP2 (SU_PREP + 26624)     /* 416*64 */
#define SU_HIST  (SU_PREP2 + E_EDGES)

typedef __attribute__((ext_vector_type(8))) short bhalf8;
typedef __attribute__((ext_vector_type(4))) float f32x4;

// fast silu: v_exp_f32 + v_rcp_f32 (err ~1ulp, negligible vs bf16 quantization)
__device__ __forceinline__ float silu_f(float x) {
    float e = __builtin_amdgcn_exp2f(x * -1.442695040888963f);
    return x * __builtin_amdgcn_rcpf(1.0f + e);
}

__device__ __forceinline__ unsigned short f2bf(float x) {
    unsigned int u = __float_as_uint(x);
    unsigned int r = u + 0x7FFFu + ((u >> 16) & 1u);   // RNE
    return (unsigned short)(r >> 16);
}

// packed pair -> one dword (lo in low 16); v_cvt_pk_bf16_f32 on gfx950
__device__ __forceinline__ unsigned int pack_bf2(float lo, float hi) {
    __hip_bfloat162 b = __float22bfloat162_rn(make_float2(lo, hi));
    return *(unsigned int*)&b;
}

// fp16 pair pack (lo in low 16)
__device__ __forceinline__ unsigned int pack_h2(float lo, float hi) {
    __half2 h = __floats2half2_rn(lo, hi);
    return *(unsigned int*)&h;
}

__device__ __forceinline__ bhalf8 mk8(unsigned a, unsigned b, unsigned c, unsigned d) {
    uint4 u; u.x = a; u.y = b; u.z = c; u.w = d;
    return *(bhalf8*)&u;
}

__device__ __forceinline__ float half_lo(unsigned v) {
    return __half2float(__ushort_as_half((unsigned short)(v & 0xFFFFu)));
}
__device__ __forceinline__ float half_hi(unsigned v) {
    return __half2float(__ushort_as_half((unsigned short)(v >> 16)));
}

// split fp32 -> bf16 hi (trunc) + bf16 lo (trunc of residual); err ~2^-16 rel
__device__ __forceinline__ void split_f32(float x, short& h, short& l) {
    unsigned int u = __float_as_uint(x);
    unsigned int hb = u & 0xFFFF0000u;
    h = (short)(u >> 16);
    float r = x - __uint_as_float(hb);
    l = (short)(__float_as_uint(r) >> 16);
}

__device__ __forceinline__ int species_of(int n, const int* counts) {
    int acc = 0, s = ZSP - 1;
#pragma unroll
    for (int z = 0; z < ZSP; z++) {
        int c = counts[z];
        if (n >= acc && n < acc + c) s = z;
        acc += c;
    }
    return s;
}

// K-setup: fused wscproj + prep(MLP frags) + prep2(node frags) + hist.
__global__ __launch_bounds__(256) void k_setup(
    const float* __restrict__ Wsc, const float* __restrict__ Proj, float* __restrict__ wscp,
    const float* __restrict__ R1, const float* __restrict__ R2,
    const float* __restrict__ R3, const float* __restrict__ R4,
    unsigned short* __restrict__ frags,
    const float* __restrict__ Wup0, const float* __restrict__ Wup1,
    const float* __restrict__ Ws0, const float* __restrict__ Ws1,
    const float* __restrict__ Wd0, const float* __restrict__ Wd1,
    const float* __restrict__ Wl0, const float* __restrict__ Wl1,
    unsigned short* __restrict__ wf,
    const int* __restrict__ receivers, int* __restrict__ csr) {
    int gid = blockIdx.x * 256 + threadIdx.x;
    if (gid < SU_WSC) {
        int z = gid / 576, t = gid % 576;
        int b = t >> 6, u = t & 63;
        float acc = 0.f;
#pragma unroll
        for (int p = 0; p < 9; p++) acc += Wsc[z * 576 + p * 64 + u] * Proj[p * 9 + b];
        wscp[z * 576 + b * 64 + u] = acc;
    } else if (gid < SU_PREP) {
        int id = gid - SU_WSC;
        int lane = id & 63, fi = id >> 6;
        int quad = lane >> 4, l15 = lane & 15;
        const float* W;
        int s, t, N;
        bool r1 = false;
        if (fi < 4)       { W = R1; s = 0; t = fi; N = 64; r1 = true; }
        else if (fi < 12) { W = R2; int x = fi - 4;  s = x >> 2; t = x & 3;  N = 64; }
        else if (fi < 20) { W = R3; int x = fi - 12; s = x >> 2; t = x & 3;  N = 64; }
        else              { W = R4; int x = fi - 20; s = x >> 4; t = x & 15; N = 256; }
        unsigned int v[4];
#pragma unroll
        for (int jj = 0; jj < 4; jj++) {
            unsigned short pk2[2];
#pragma unroll
            for (int o = 0; o < 2; o++) {
                int j = jj * 2 + o;
                int k = s * 32 + quad * 8 + j, n = t * 16 + l15;
                float val = (r1 && k >= RDIM) ? 0.f : W[k * N + n];
                pk2[o] = f2bf(val);
            }
            v[jj] = (unsigned int)pk2[0] | ((unsigned int)pk2[1] << 16);
        }
        uint4 pk; pk.x = v[0]; pk.y = v[1]; pk.z = v[2]; pk.w = v[3];
        ((uint4*)frags)[id] = pk;
    } else if (gid < SU_PREP2) {
        int id = gid - SU_PREP;
        int lane = id & 63, slot = id >> 6;
        int t = slot & 3, s = (slot >> 2) & 1, part = (slot >> 3) & 1, mat = slot >> 4;
        int quad = lane >> 4, l15 = lane & 15;
        const float* W;
        if (mat == 0)       W = Wup0;
        else if (mat == 1)  W = Wup1;
        else if (mat < 12)  W = Ws0 + (mat - 2) * 4096;
        else if (mat < 22)  W = Ws1 + (mat - 12) * 4096;
        else if (mat == 22) W = Wd0;
        else if (mat == 23) W = Wd1;
        else if (mat == 24) W = Wl0;
        else                W = Wl1;
        unsigned int v[4];
#pragma unroll
        for (int jj = 0; jj < 4; jj++) {
            unsigned short pk2[2];
#pragma unroll
            for (int o = 0; o < 2; o++) {
                int j = jj * 2 + o;
                int k = s * 32 + quad * 8 + j, n = t * 16 + l15;
                float x = W[k * 64 + n];
                short h, l;
                split_f32(x, h, l);
                pk2[o] = part == 0 ? (unsigned short)h : (unsigned short)l;
            }
            v[jj] = (unsigned int)pk2[0] | ((unsigned int)pk2[1] << 16);
        }
        uint4 pk; pk.x = v[0]; pk.y = v[1]; pk.z = v[2]; pk.w = v[3];
        ((uint4*)wf)[id] = pk;
    } else if (gid < SU_HIST) {
        int e = gid - SU_PREP2;
        atomicAdd(&csr[CSR_CNT + receivers[e]], 1);
    }
}

// 3-phase parallel scan over the single 20000-entry histogram.
__global__ __launch_bounds__(256) void k_scan1(int* __restrict__ csr) {
    __shared__ int sb[256];
    int b = blockIdx.x, t = threadIdx.x;
    int i = b * 256 + t;
    int x = (i < N_NODES) ? csr[CSR_CNT + i] : 0;
    sb[t] = x;
    __syncthreads();
#pragma unroll
    for (int off = 1; off < 256; off <<= 1) {
        int v = (t >= off) ? sb[t - off] : 0;
        __syncthreads();
        sb[t] += v;
        __syncthreads();
    }
    if (i < N_NODES) csr[CSR_PTR + i] = sb[t] - x;   // block-local exclusive
    if (t == 255) csr[CSR_AUX + b] = sb[255];
}

__global__ __launch_bounds__(128) void k_scan2(int* __restrict__ csr) {
    __shared__ int sb[128];
    int t = threadIdx.x;
    int x = (t < 79) ? csr[CSR_AUX + t] : 0;
    sb[t] = x;
    __syncthreads();
#pragma unroll
    for (int off = 1; off < 128; off <<= 1) {
        int v = (t >= off) ? sb[t - off] : 0;
        __syncthreads();
        sb[t] += v;
        __syncthreads();
    }
    csr[CSR_AUX + t] = sb[t] - x;
    if (t == 127) csr[CSR_PTR + N_NODES] = sb[127];
}

__global__ __launch_bounds__(256) void k_scan3(int* __restrict__ csr) {
    int b = blockIdx.x, t = threadIdx.x;
    int i = b * 256 + t;
    if (i >= N_NODES) return;
    int v = csr[CSR_PTR + i] + csr[CSR_AUX + b];
    csr[CSR_PTR + i] = v;
    csr[CSR_CNT + i] = v;   // cursor for bucketing
}

// Merged: blocks 0..1249 = node_pre (linear_up fp16-packed + species skip),
//         blocks 1250..2499 = bucket (CSR fill + Y1/sender precompute).
__global__ __launch_bounds__(256) void k_pre_bucket(
    const float* __restrict__ ns, const float* __restrict__ nv,
    const int* __restrict__ counts, const unsigned short* __restrict__ wf,
    const float* __restrict__ vectors, const int* __restrict__ senders,
    const int* __restrict__ receivers, int* __restrict__ csr,
    float4* __restrict__ erec, float* __restrict__ ws) {
    __shared__ uint2 eup_t[16][64];   // 8 KB (node_pre blocks only)
    int tid = threadIdx.x;
    if (blockIdx.x >= 1250) {
        // ---- bucket ----
        int e = (blockIdx.x - 1250) * 256 + tid;   // 1250*256 == E exactly
        int pos = atomicAdd(&csr[CSR_CNT + receivers[e]], 1);
        float v0 = vectors[e * 3 + 0], v1 = vectors[e * 3 + 1], v2 = vectors[e * 3 + 2];
        float s = SQRT3C * rsqrtf(v0 * v0 + v1 * v1 + v2 * v2);
        csr[CSR_SEID + pos] = e;
        float4 r;
        r.x = v0 * s; r.y = v1 * s; r.z = v2 * s; r.w = __int_as_float(senders[e]);
        erec[pos] = r;
        return;
    }
    // ---- node_pre ----
    int w = tid >> 6, lane = tid & 63;
    int q = lane >> 4, l15 = lane & 15;
    int nw = blockIdx.x * 16;
    int sid = species_of(nw, counts);
    const f32x4 z4 = {0.f, 0.f, 0.f, 0.f};

    bhalf8 Ah[2], Al[2];
    if (w == 0) {
#pragma unroll
        for (int s = 0; s < 2; s++) {
            const float* rp = ns + (size_t)(nw + l15) * 64 + s * 32 + q * 8;
            float4 a = *(const float4*)rp, b = *(const float4*)(rp + 4);
            float x[8] = {a.x, a.y, a.z, a.w, b.x, b.y, b.z, b.w};
#pragma unroll
            for (int j = 0; j < 8; j++) { short h, l; split_f32(x[j], h, l); Ah[s][j] = h; Al[s][j] = l; }
        }
    } else {
        int i = w - 1;
#pragma unroll
        for (int s = 0; s < 2; s++) {
            const float* rp = nv + (size_t)(nw + l15) * 192 + i;
#pragma unroll
            for (int j = 0; j < 8; j++) {
                float x = rp[(s * 32 + q * 8 + j) * 3];
                short h, l; split_f32(x, h, l); Ah[s][j] = h; Al[s][j] = l;
            }
        }
    }

    const bhalf8* wfv = (const bhalf8*)wf;
    float* sks = ws + OFF_SKS;
    float* skv = ws + OFF_SKV;

    // m=0: linear_up -> fp16 packed LDS tile
    {
        int mat = (w == 0) ? 0 : 1;
#pragma unroll
        for (int t = 0; t < 4; t++) {
            f32x4 acc = z4;
#pragma unroll
            for (int s = 0; s < 2; s++) {
                bhalf8 bh = wfv[(size_t)(mat * 16 + 0 + s * 4 + t) * 64 + lane];
                bhalf8 bl = wfv[(size_t)(mat * 16 + 8 + s * 4 + t) * 64 + lane];
                acc = __builtin_amdgcn_mfma_f32_16x16x32_bf16(Ah[s], bh, acc, 0, 0, 0);
                acc = __builtin_amdgcn_mfma_f32_16x16x32_bf16(Al[s], bh, acc, 0, 0, 0);
                acc = __builtin_amdgcn_mfma_f32_16x16x32_bf16(Ah[s], bl, acc, 0, 0, 0);
            }
#pragma unroll
            for (int r = 0; r < 4; r++) {
                unsigned short us = __half_as_ushort(__float2half_rn(acc[r] * INV_F));
                ((unsigned short*)&eup_t[q * 4 + r][t * 16 + l15])[w] = us;
            }
        }
    }
    // m=1: species skip -> fp32 tables
    {
        int mat = (w == 0) ? 2 + sid : 12 + sid;
        float* dst = (w == 0) ? sks : skv;
        int stride = (w == 0) ? 64 : 192;
        int off = (w == 0) ? 0 : (w - 1) * 64;
#pragma unroll
        for (int t = 0; t < 4; t++) {
            f32x4 acc = z4;
#pragma unroll
            for (int s = 0; s < 2; s++) {
                bhalf8 bh = wfv[(size_t)(mat * 16 + 0 + s * 4 + t) * 64 + lane];
                bhalf8 bl = wfv[(size_t)(mat * 16 + 8 + s * 4 + t) * 64 + lane];
                acc = __builtin_amdgcn_mfma_f32_16x16x32_bf16(Ah[s], bh, acc, 0, 0, 0);
                acc = __builtin_amdgcn_mfma_f32_16x16x32_bf16(Al[s], bh, acc, 0, 0, 0);
                acc = __builtin_amdgcn_mfma_f32_16x16x32_bf16(Ah[s], bl, acc, 0, 0, 0);
            }
#pragma unroll
            for (int r = 0; r < 4; r++)
                dst[(size_t)(nw + q * 4 + r) * stride + off + t * 16 + l15] = acc[r] * INV_F;
        }
    }
    __syncthreads();
    uint2* eup = (uint2*)(ws + OFF_EUP);
    for (int k = tid; k < 1024; k += 256) {
        int n = k >> 6, f = k & 63;
        eup[(size_t)(nw + n) * 64 + f] = eup_t[n][f];
    }
}

// Cross-lane frag builder (see R9 derivation).
template<int S>
__device__ __forceinline__ bhalf8 xfrag(const unsigned* pkA, const unsigned* pkB,
                                        int q, int l15) {
    int L0 = ((q & 1) << 5) + l15;
    int L1 = L0 + 16;
    bool hi = (q >> 1) != 0;
    unsigned a0 = (unsigned)__shfl((int)pkA[2 * S], L0, 64);
    unsigned a1 = (unsigned)__shfl((int)pkA[2 * S + 1], L0, 64);
    unsigned b0 = (unsigned)__shfl((int)pkB[2 * S], L0, 64);
    unsigned b1 = (unsigned)__shfl((int)pkB[2 * S + 1], L0, 64);
    unsigned c0 = (unsigned)__shfl((int)pkA[2 * S], L1, 64);
    unsigned c1 = (unsigned)__shfl((int)pkA[2 * S + 1], L1, 64);
    unsigned e0 = (unsigned)__shfl((int)pkB[2 * S], L1, 64);
    unsigned e1 = (unsigned)__shfl((int)pkB[2 * S + 1], L1, 64);
    return mk8(hi ? a1 : a0, hi ? b1 : b0, hi ? c1 : c0, hi ? e1 : e0);
}

// K2a: radial MLP via bf16 MFMA, CSR-sorted order, register-shuffle act pass.
// Single dispatch over all E edges; wbuf now stores fp16 weights (8x less
// quantization noise than bf16 at identical bytes).
__global__ __launch_bounds__(256) void k_mlp(
    const float* __restrict__ radial, const unsigned short* __restrict__ frags,
    const int* __restrict__ csr, unsigned short* __restrict__ wbuf) {
    __shared__ unsigned short r4lds[16384];   // 32 KB
    int tid = threadIdx.x;
    int lane = tid & 63, w = tid >> 6, quad = lane >> 4, l15 = lane & 15;

    const uint4* r4g = (const uint4*)(frags + 20 * 64 * 8);
    uint4* r4l = (uint4*)r4lds;
    for (int i = tid; i < 2048; i += 256) r4l[i] = r4g[i];
    const bhalf8* fr = (const bhalf8*)frags;
    bhalf8 r1f[4], r2f[2][4], r3f[2][4];
#pragma unroll
    for (int t = 0; t < 4; t++) r1f[t] = fr[t * 64 + lane];
#pragma unroll
    for (int s = 0; s < 2; s++)
#pragma unroll
        for (int t = 0; t < 4; t++) {
            r2f[s][t] = fr[(4 + s * 4 + t) * 64 + lane];
            r3f[s][t] = fr[(12 + s * 4 + t) * 64 + lane];
        }
    __syncthreads();

    const f32x4 z4 = {0.f, 0.f, 0.f, 0.f};
    const bhalf8* r4f = (const bhalf8*)r4lds;

    int el0 = (blockIdx.x * 4 + w) * 16;   // global sorted slot base

    bhalf8 af = {0, 0, 0, 0, 0, 0, 0, 0};
    if (quad == 0) {
        int eid = csr[CSR_SEID + el0 + l15];  // global edge id
        const float* rp = radial + (size_t)eid * 8;
        float4 ra = *(const float4*)rp;
        float4 rb = *(const float4*)(rp + 4);
        af[0] = (short)f2bf(ra.x); af[1] = (short)f2bf(ra.y);
        af[2] = (short)f2bf(ra.z); af[3] = (short)f2bf(ra.w);
        af[4] = (short)f2bf(rb.x); af[5] = (short)f2bf(rb.y);
        af[6] = (short)f2bf(rb.z); af[7] = (short)f2bf(rb.w);
    }
    unsigned pkA[4], pkB[4];
    {
        f32x4 acc[4];
#pragma unroll
        for (int t = 0; t < 4; t++)
            acc[t] = __builtin_amdgcn_mfma_f32_16x16x32_bf16(r1f[t], af, z4, 0, 0, 0);
#pragma unroll
        for (int t = 0; t < 4; t++) {
            pkA[t] = pack_bf2(silu_f(acc[t][0]), silu_f(acc[t][1]));
            pkB[t] = pack_bf2(silu_f(acc[t][2]), silu_f(acc[t][3]));
        }
    }
#pragma unroll
    for (int layer = 0; layer < 2; layer++) {
        bhalf8 b0 = xfrag<0>(pkA, pkB, quad, l15);
        bhalf8 b1 = xfrag<1>(pkA, pkB, quad, l15);
        f32x4 acc[4];
#pragma unroll
        for (int t = 0; t < 4; t++) {
            bhalf8 w0 = layer == 0 ? r2f[0][t] : r3f[0][t];
            bhalf8 w1 = layer == 0 ? r2f[1][t] : r3f[1][t];
            acc[t] = __builtin_amdgcn_mfma_f32_16x16x32_bf16(
                w1, b1, __builtin_amdgcn_mfma_f32_16x16x32_bf16(w0, b0, z4, 0, 0, 0), 0, 0, 0);
        }
#pragma unroll
        for (int t = 0; t < 4; t++) {
            pkA[t] = pack_bf2(silu_f(acc[t][0]), silu_f(acc[t][1]));
            pkB[t] = pack_bf2(silu_f(acc[t][2]), silu_f(acc[t][3]));
        }
    }
    {
        bhalf8 a0 = xfrag<0>(pkA, pkB, quad, l15);
        bhalf8 a1 = xfrag<1>(pkA, pkB, quad, l15);
#pragma unroll
        for (int t4 = 0; t4 < 4; t4++) {
            f32x4 p0 = __builtin_amdgcn_mfma_f32_16x16x32_bf16(
                a1, r4f[(16 + t4) * 64 + lane],
                __builtin_amdgcn_mfma_f32_16x16x32_bf16(a0, r4f[t4 * 64 + lane], z4, 0, 0, 0), 0, 0, 0);
            f32x4 p1 = __builtin_amdgcn_mfma_f32_16x16x32_bf16(
                a1, r4f[(20 + t4) * 64 + lane],
                __builtin_amdgcn_mfma_f32_16x16x32_bf16(a0, r4f[(4 + t4) * 64 + lane], z4, 0, 0, 0), 0, 0, 0);
            f32x4 p2 = __builtin_amdgcn_mfma_f32_16x16x32_bf16(
                a1, r4f[(24 + t4) * 64 + lane],
                __builtin_amdgcn_mfma_f32_16x16x32_bf16(a0, r4f[(8 + t4) * 64 + lane], z4, 0, 0, 0), 0, 0, 0);
            f32x4 p3 = __builtin_amdgcn_mfma_f32_16x16x32_bf16(
                a1, r4f[(28 + t4) * 64 + lane],
                __builtin_amdgcn_mfma_f32_16x16x32_bf16(a0, r4f[(12 + t4) * 64 + lane], z4, 0, 0, 0), 0, 0, 0);
#pragma unroll
            for (int r = 0; r < 4; r++) {
                int el = el0 + quad * 4 + r;
                int f = t4 * 16 + l15;
                uint2 pk;
                pk.x = pack_h2(p0[r], p1[r]);   // fp16 weights
                pk.y = pack_h2(p2[r], p3[r]);
                ((uint2*)wbuf)[(size_t)el * 64 + f] = pk;
            }
        }
    }
}

// K2b: CSR gather TP (single pass, fp16 w + fp16 eup), depth-2 pipeline.
// EPS applied exactly once at the store.
__global__ __launch_bounds__(256) void k_tp_gather(
    const unsigned short* __restrict__ wbuf, const int* __restrict__ csr,
    const float4* __restrict__ erec, float* __restrict__ ws) {
    int tid = threadIdx.x, w = tid >> 6, f = tid & 63;
    int n = blockIdx.x * 4 + w;
    const uint2* eup = (const uint2*)(ws + OFF_EUP);
    float* hs_mid = ws + OFF_HSMID;
    float* hv_mid = ws + OFF_HVMID;
    int beg = csr[CSR_PTR + n], end = csr[CSR_PTR + n + 1];
    float ams = 0.f, am0 = 0.f, am1 = 0.f, am2 = 0.f;

    if (beg < end) {
        int last = end - 1;
        float4 rcA = erec[beg];
        uint2 wrA = ((const uint2*)wbuf)[(size_t)beg * 64 + f];
        uint2 evA = eup[(size_t)__float_as_int(rcA.w) * 64 + f];
        int j1 = (beg + 1 < end) ? beg + 1 : last;
        float4 rcB = erec[j1];
        uint2 wrB = ((const uint2*)wbuf)[(size_t)j1 * 64 + f];
        uint2 evB = eup[(size_t)__float_as_int(rcB.w) * 64 + f];

        for (int i = beg; i < end; i++) {
            int j2 = (i + 2 < end) ? i + 2 : last;
            float4 rcC = erec[j2];
            uint2 wrC = ((const uint2*)wbuf)[(size_t)j2 * 64 + f];
            uint2 evC = eup[(size_t)__float_as_int(rcC.w) * 64 + f];
            float esA = half_lo(evA.x), eA0 = half_hi(evA.x);
            float eA1 = half_lo(evA.y), eA2 = half_hi(evA.y);
            float w0 = half_lo(wrA.x), w1 = half_hi(wrA.x);
            float w2 = half_lo(wrA.y), w3 = half_hi(wrA.y);
            float dot = eA0 * rcA.x + eA1 * rcA.y + eA2 * rcA.z;
            ams += w0 * esA + w1 * dot * INV_SQRT3C;
            float t3 = w3 * esA * INV_SQRT3C;
            am0 += w2 * eA0 + t3 * rcA.x;
            am1 += w2 * eA1 + t3 * rcA.y;
            am2 += w2 * eA2 + t3 * rcA.z;
            rcA = rcB; wrA = wrB; evA = evB;
            rcB = rcC; wrB = wrC; evB = evC;
        }
    }
    hs_mid[n * 64 + f] = ams * EPSC;
    hv_mid[n * 192 + f] = am0 * EPSC;
    hv_mid[n * 192 + 64 + f] = am1 * EPSC;
    hv_mid[n * 192 + 128 + f] = am2 * EPSC;
}

// K3: linear_down + contraction + linear_sc + skip + readout via split-bf16 MFMA.
// (R10-proven structure: reads hs_mid/hv_mid from global.)
__global__ __launch_bounds__(256) void k_node_post(
    const int* __restrict__ counts, const unsigned short* __restrict__ wf,
    const float* __restrict__ Wr, float* __restrict__ ws, float* __restrict__ out) {
    __shared__ float T[4][16][68];
    int tid = threadIdx.x, w = tid >> 6, lane = tid & 63;
    int q = lane >> 4, l15 = lane & 15;
    int nw = blockIdx.x * 16;
    int sid = species_of(nw, counts);
    const f32x4 z4 = {0.f, 0.f, 0.f, 0.f};
    const bhalf8* wfv = (const bhalf8*)wf;
    const float* hs_mid = ws + OFF_HSMID;
    const float* hv_mid = ws + OFF_HVMID;
    const float* sks = ws + OFF_SKS;
    const float* skv = ws + OFF_SKV;
    const float* wscp = ws + OFF_WSCP;

    // Phase 1: linear_down (EPS already applied in k_tp_gather's store)
    {
        const float* src = (w == 0) ? hs_mid + (size_t)nw * 64
                                    : hv_mid + (size_t)nw * 192 + (w - 1) * 64;
        int rstride = (w == 0) ? 64 : 192;
        bhalf8 Ah[2], Al[2];
#pragma unroll
        for (int s = 0; s < 2; s++) {
            const float* rp = src + (size_t)l15 * rstride + s * 32 + q * 8;
            float4 a = *(const float4*)rp, b = *(const float4*)(rp + 4);
            float x[8] = {a.x, a.y, a.z, a.w, b.x, b.y, b.z, b.w};
#pragma unroll
            for (int j = 0; j < 8; j++) { short h, l; split_f32(x[j], h, l); Ah[s][j] = h; Al[s][j] = l; }
        }
        int mat = (w == 0) ? 22 : 23;
#pragma unroll
        for (int t = 0; t < 4; t++) {
            f32x4 acc = z4;
#pragma unroll
            for (int s = 0; s < 2; s++) {
                bhalf8 bh = wfv[(size_t)(mat * 16 + 0 + s * 4 + t) * 64 + lane];
                bhalf8 bl = wfv[(size_t)(mat * 16 + 8 + s * 4 + t) * 64 + lane];
                acc = __builtin_amdgcn_mfma_f32_16x16x32_bf16(Ah[s], bh, acc, 0, 0, 0);
                acc = __builtin_amdgcn_mfma_f32_16x16x32_bf16(Al[s], bh, acc, 0, 0, 0);
                acc = __builtin_amdgcn_mfma_f32_16x16x32_bf16(Ah[s], bl, acc, 0, 0, 0);
            }
#pragma unroll
            for (int r = 0; r < 4; r++)
                T[w][q * 4 + r][t * 16 + l15] = acc[r] * INV_F;
        }
    }
    __syncthreads();

    // Phase 2: symmetric contraction
    {
        int col = tid & 63, rg = tid >> 6;
        float wv[9];
#pragma unroll
        for (int b = 0; b < 9; b++) wv[b] = wscp[sid * 576 + b * 64 + col];
#pragma unroll
        for (int rr = 0; rr < 4; rr++) {
            int row = rg * 4 + rr;
            float hs = T[0][row][col];
            float h0 = T[1][row][col], h1 = T[2][row][col], h2 = T[3][row][col];
            float vv = h0 * h0 + h1 * h1 + h2 * h2;
            float cs = wv[0] * hs + wv[1] * hs * hs + wv[2] * vv
                     + wv[3] * hs * hs * hs + wv[4] * hs * vv;
            float fv = wv[5] + wv[6] * hs + wv[7] * hs * hs + wv[8] * vv;
            T[0][row][col] = cs;
            T[1][row][col] = h0 * fv;
            T[2][row][col] = h1 * fv;
            T[3][row][col] = h2 * fv;
        }
    }
    __syncthreads();

    // Phase 3: linear_sc + skip + store (+ readout on w0)
    {
        bhalf8 Ah[2], Al[2];
#pragma unroll
        for (int s = 0; s < 2; s++) {
            const float* rp = &T[w][l15][s * 32 + q * 8];
            float4 a = *(const float4*)rp, b = *(const float4*)(rp + 4);
            float x[8] = {a.x, a.y, a.z, a.w, b.x, b.y, b.z, b.w};
#pragma unroll
            for (int j = 0; j < 8; j++) { short h, l; split_f32(x[j], h, l); Ah[s][j] = h; Al[s][j] = l; }
        }
        int mat = (w == 0) ? 24 : 25;
        float* d_hs = out + N_NODES;
        float* d_hv = out + N_NODES + N_NODES * 64;
        float p[4] = {0.f, 0.f, 0.f, 0.f};
#pragma unroll
        for (int t = 0; t < 4; t++) {
            f32x4 acc = z4;
#pragma unroll
            for (int s = 0; s < 2; s++) {
                bhalf8 bh = wfv[(size_t)(mat * 16 + 0 + s * 4 + t) * 64 + lane];
                bhalf8 bl = wfv[(size_t)(mat * 16 + 8 + s * 4 + t) * 64 + lane];
                acc = __builtin_amdgcn_mfma_f32_16x16x32_bf16(Ah[s], bh, acc, 0, 0, 0);
                acc = __builtin_amdgcn_mfma_f32_16x16x32_bf16(Al[s], bh, acc, 0, 0, 0);
                acc = __builtin_amdgcn_mfma_f32_16x16x32_bf16(Ah[s], bl, acc, 0, 0, 0);
            }
            int col = t * 16 + l15;
            if (w == 0) {
                float wr = Wr[col];
#pragma unroll
                for (int r = 0; r < 4; r++) {
                    int gn = nw + q * 4 + r;
                    float v = acc[r] * INV_F + sks[(size_t)gn * 64 + col];
                    d_hs[(size_t)gn * 64 + col] = v;
                    p[r] += v * wr;
                }
            } else {
                int i = w - 1;
#pragma unroll
                for (int r = 0; r < 4; r++) {
                    int gn = nw + q * 4 + r;
                    float v = acc[r] * INV_F + skv[(size_t)gn * 192 + i * 64 + col];
                    d_hv[(size_t)gn * 192 + col * 3 + i] = v;
                }
            }
        }
        if (w == 0) {
#pragma unroll
            for (int r = 0; r < 4; r++) {
#pragma unroll
                for (int off = 1; off < 16; off <<= 1) p[r] += __shfl_xor(p[r], off, 64);
                if (l15 == 0) out[nw + q * 4 + r] = p[r] * INV_F;
            }
        }
    }
}

extern "C" void kernel_launch(void* const* d_in, const int* in_sizes, int n_in,
                              void* d_out, int out_size, void* d_ws, size_t ws_size,
                              hipStream_t stream) {
    const float* vectors   = (const float*)d_in[0];
    const float* node_s    = (const float*)d_in[1];
    const float* node_v    = (const float*)d_in[2];
    const float* radial    = (const float*)d_in[3];
    const int*   senders   = (const int*)d_in[4];
    const int*   receivers = (const int*)d_in[5];
    const int*   counts    = (const int*)d_in[6];
    const float* Wup0 = (const float*)d_in[7];
    const float* Wup1 = (const float*)d_in[8];
    const float* R1   = (const float*)d_in[9];
    const float* R2   = (const float*)d_in[10];
    const float* R3   = (const float*)d_in[11];
    const float* R4   = (const float*)d_in[12];
    const float* Wd0  = (const float*)d_in[13];
    const float* Wd1  = (const float*)d_in[14];
    const float* Ws0  = (const float*)d_in[15];
    const float* Ws1  = (const float*)d_in[16];
    const float* Wsc  = (const float*)d_in[17];
    const float* Proj = (const float*)d_in[18];
    const float* Wl0  = (const float*)d_in[19];
    const float* Wl1  = (const float*)d_in[20];
    const float* Wr   = (const float*)d_in[21];
    float* ws  = (float*)d_ws;
    float* out = (float*)d_out;
    unsigned short* frags = (unsigned short*)(ws + OFF_FRAGS);
    unsigned short* wbuf  = (unsigned short*)(ws + OFF_WBUF);
    float4* erec = (float4*)(ws + OFF_CSR);
    int* csr = (int*)(ws + OFF_CSR + (size_t)E_EDGES * 4);
    unsigned short* wf = (unsigned short*)(ws + OFF_WF);

    hipMemsetAsync(csr + CSR_CNT, 0, N_NODES * sizeof(int), stream);
    k_setup<<<(SU_HIST + 255) / 256, 256, 0, stream>>>(
        Wsc, Proj, ws + OFF_WSCP, R1, R2, R3, R4, frags,
        Wup0, Wup1, Ws0, Ws1, Wd0, Wd1, Wl0, Wl1, wf, receivers, csr);
    k_scan1<<<79, 256, 0, stream>>>(csr);
    k_scan2<<<1, 128, 0, stream>>>(csr);
    k_scan3<<<79, 256, 0, stream>>>(csr);
    k_pre_bucket<<<2500, 256, 0, stream>>>(node_s, node_v, counts, wf,
                                           vectors, senders, receivers, csr, erec, ws);
    k_mlp<<<5000, 256, 0, stream>>>(radial, frags, csr, wbuf);
    k_tp_gather<<<N_NODES / 4, 256, 0, stream>>>(wbuf, csr, erec, ws);
    k_node_post<<<N_NODES / 16, 256, 0, stream>>>(counts, wf, Wr, ws, out);
}

// Round 13
// 300.546 us; speedup vs baseline: 2.5502x; 1.0032x over previous
//
#include <hip/hip_runtime.h>
#include <hip/hip_bf16.h>
#include <hip/hip_fp16.h>
#include <math.h>

#define N_NODES 20000
#define FCH 64
#define ZSP 10
#define E_EDGES 320000
#define RDIM 8
#define EPSC 0.25f
#define SQRT3C 1.7320508075688772f
#define INV_SQRT3C 0.57735026918962576f
#define INV_F 0.125f  /* 1/sqrt(64) */

// ---- workspace layout (float offsets) ----
#define OFF_EUP    0                               // (N,64) uint2 fp16x4 = N*128 floats
#define OFF_SKS    (N_NODES*128)                   // (N,64)
#define OFF_SKV    (OFF_SKS + N_NODES*64)          // (N,3,64) planar
#define OFF_HSMID  (OFF_SKV + N_NODES*192)         // (N,64)
#define OFF_HVMID  (OFF_HSMID + N_NODES*64)        // (N,3,64) planar
#define OFF_WSCP   (OFF_HVMID + N_NODES*192)       // (Z,9,64)
#define OFF_FRAGS  (OFF_WSCP + ZSP*576)            // 3328*8 ushort = 13312 floats
#define OFF_WBUF   (OFF_FRAGS + 13312)             // E*64 uint2 (fp16x4 MESSAGES)
#define OFF_CSR    (OFF_WBUF + E_EDGES*128)        // erec float4[E], then ints
#define OFF_WF     (OFF_CSR + E_EDGES*4 + 360132)  // 416 slots * 512 ushort
// ints relative to csr int base (after erec):
#define CSR_CNT    0        /* 20000, becomes cursor after scan */
#define CSR_PTR    20000    /* 20001 */
#define CSR_SEID   40001    /* E */

// k_setup gid ranges
#define SU_WSC   5760                  /* 10*576 */
#define SU_PREP  (SU_WSC + 3328)
#define SU_PREP2 (SU_PREP + 26624)     /* 416*64 */
#define SU_HIST  (SU_PREP2 + E_EDGES)

typedef __attribute__((ext_vector_type(8))) short bhalf8;
typedef __attribute__((ext_vector_type(4))) float f32x4;

// fast silu: v_exp_f32 + v_rcp_f32 (err ~1ulp, negligible vs bf16 quantization)
__device__ __forceinline__ float silu_f(float x) {
    float e = __builtin_amdgcn_exp2f(x * -1.442695040888963f);
    return x * __builtin_amdgcn_rcpf(1.0f + e);
}

__device__ __forceinline__ unsigned short f2bf(float x) {
    unsigned int u = __float_as_uint(x);
    unsigned int r = u + 0x7FFFu + ((u >> 16) & 1u);   // RNE
    return (unsigned short)(r >> 16);
}

// packed pair -> one dword (lo in low 16); v_cvt_pk_bf16_f32 on gfx950
__device__ __forceinline__ unsigned int pack_bf2(float lo, float hi) {
    __hip_bfloat162 b = __float22bfloat162_rn(make_float2(lo, hi));
    return *(unsigned int*)&b;
}

// fp16 pair pack (lo in low 16)
__device__ __forceinline__ unsigned int pack_h2(float lo, float hi) {
    __half2 h = __floats2half2_rn(lo, hi);
    return *(unsigned int*)&h;
}

__device__ __forceinline__ bhalf8 mk8(unsigned a, unsigned b, unsigned c, unsigned d) {
    uint4 u; u.x = a; u.y = b; u.z = c; u.w = d;
    return *(bhalf8*)&u;
}

__device__ __forceinline__ float half_lo(unsigned v) {
    return __half2float(__ushort_as_half((unsigned short)(v & 0xFFFFu)));
}
__device__ __forceinline__ float half_hi(unsigned v) {
    return __half2float(__ushort_as_half((unsigned short)(v >> 16)));
}

// split fp32 -> bf16 hi (trunc) + bf16 lo (trunc of residual); err ~2^-16 rel
__device__ __forceinline__ void split_f32(float x, short& h, short& l) {
    unsigned int u = __float_as_uint(x);
    unsigned int hb = u & 0xFFFF0000u;
    h = (short)(u >> 16);
    float r = x - __uint_as_float(hb);
    l = (short)(__float_as_uint(r) >> 16);
}

__device__ __forceinline__ int species_of(int n, const int* counts) {
    int acc = 0, s = ZSP - 1;
#pragma unroll
    for (int z = 0; z < ZSP; z++) {
        int c = counts[z];
        if (n >= acc && n < acc + c) s = z;
        acc += c;
    }
    return s;
}

// K-setup: fused wscproj + prep(MLP frags) + prep2(node frags) + hist.
__global__ __launch_bounds__(256) void k_setup(
    const float* __restrict__ Wsc, const float* __restrict__ Proj, float* __restrict__ wscp,
    const float* __restrict__ R1, const float* __restrict__ R2,
    const float* __restrict__ R3, const float* __restrict__ R4,
    unsigned short* __restrict__ frags,
    const float* __restrict__ Wup0, const float* __restrict__ Wup1,
    const float* __restrict__ Ws0, const float* __restrict__ Ws1,
    const float* __restrict__ Wd0, const float* __restrict__ Wd1,
    const float* __restrict__ Wl0, const float* __restrict__ Wl1,
    unsigned short* __restrict__ wf,
    const int* __restrict__ receivers, int* __restrict__ csr) {
    int gid = blockIdx.x * 256 + threadIdx.x;
    if (gid < SU_WSC) {
        int z = gid / 576, t = gid % 576;
        int b = t >> 6, u = t & 63;
        float acc = 0.f;
#pragma unroll
        for (int p = 0; p < 9; p++) acc += Wsc[z * 576 + p * 64 + u] * Proj[p * 9 + b];
        wscp[z * 576 + b * 64 + u] = acc;
    } else if (gid < SU_PREP) {
        int id = gid - SU_WSC;
        int lane = id & 63, fi = id >> 6;
        int quad = lane >> 4, l15 = lane & 15;
        const float* W;
        int s, t, N;
        bool r1 = false;
        if (fi < 4)       { W = R1; s = 0; t = fi; N = 64; r1 = true; }
        else if (fi < 12) { W = R2; int x = fi - 4;  s = x >> 2; t = x & 3;  N = 64; }
        else if (fi < 20) { W = R3; int x = fi - 12; s = x >> 2; t = x & 3;  N = 64; }
        else              { W = R4; int x = fi - 20; s = x >> 4; t = x & 15; N = 256; }
        unsigned int v[4];
#pragma unroll
        for (int jj = 0; jj < 4; jj++) {
            unsigned short pk2[2];
#pragma unroll
            for (int o = 0; o < 2; o++) {
                int j = jj * 2 + o;
                int k = s * 32 + quad * 8 + j, n = t * 16 + l15;
                float val = (r1 && k >= RDIM) ? 0.f : W[k * N + n];
                pk2[o] = f2bf(val);
            }
            v[jj] = (unsigned int)pk2[0] | ((unsigned int)pk2[1] << 16);
        }
        uint4 pk; pk.x = v[0]; pk.y = v[1]; pk.z = v[2]; pk.w = v[3];
        ((uint4*)frags)[id] = pk;
    } else if (gid < SU_PREP2) {
        int id = gid - SU_PREP;
        int lane = id & 63, slot = id >> 6;
        int t = slot & 3, s = (slot >> 2) & 1, part = (slot >> 3) & 1, mat = slot >> 4;
        int quad = lane >> 4, l15 = lane & 15;
        const float* W;
        if (mat == 0)       W = Wup0;
        else if (mat == 1)  W = Wup1;
        else if (mat < 12)  W = Ws0 + (mat - 2) * 4096;
        else if (mat < 22)  W = Ws1 + (mat - 12) * 4096;
        else if (mat == 22) W = Wd0;
        else if (mat == 23) W = Wd1;
        else if (mat == 24) W = Wl0;
        else                W = Wl1;
        unsigned int v[4];
#pragma unroll
        for (int jj = 0; jj < 4; jj++) {
            unsigned short pk2[2];
#pragma unroll
            for (int o = 0; o < 2; o++) {
                int j = jj * 2 + o;
                int k = s * 32 + quad * 8 + j, n = t * 16 + l15;
                float x = W[k * 64 + n];
                short h, l;
                split_f32(x, h, l);
                pk2[o] = part == 0 ? (unsigned short)h : (unsigned short)l;
            }
            v[jj] = (unsigned int)pk2[0] | ((unsigned int)pk2[1] << 16);
        }
        uint4 pk; pk.x = v[0]; pk.y = v[1]; pk.z = v[2]; pk.w = v[3];
        ((uint4*)wf)[id] = pk;
    } else if (gid < SU_HIST) {
        int e = gid - SU_PREP2;
        atomicAdd(&csr[CSR_CNT + receivers[e]], 1);
    }
}

// Single-dispatch scan: one block, 1024 threads, shuffle-based (3 barriers/iter).
__global__ __launch_bounds__(1024) void k_scan_all(int* __restrict__ csr) {
    __shared__ int wsum[16];
    __shared__ int carry;
    int t = threadIdx.x, lane = t & 63, wv = t >> 6;
    int running = 0;
    for (int i0 = 0; i0 < N_NODES; i0 += 1024) {
        int i = i0 + t;
        int x = (i < N_NODES) ? csr[CSR_CNT + i] : 0;
        int s = x;
#pragma unroll
        for (int off = 1; off < 64; off <<= 1) {
            int v = __shfl_up(s, off, 64);
            if (lane >= off) s += v;
        }
        if (lane == 63) wsum[wv] = s;
        __syncthreads();
        if (wv == 0 && lane < 16) {
            int v = wsum[lane];
            int sc = v;
#pragma unroll
            for (int off = 1; off < 16; off <<= 1) {
                int u = __shfl_up(sc, off, 64);
                if (lane >= off) sc += u;
            }
            wsum[lane] = sc - v;       // exclusive wave offset
            if (lane == 15) carry = sc; // iteration total
        }
        __syncthreads();
        int excl = s - x + wsum[wv];
        if (i < N_NODES) {
            int val = running + excl;
            csr[CSR_PTR + i] = val;
            csr[CSR_CNT + i] = val;     // cursor for bucketing
        }
        running += carry;
        __syncthreads();               // protect wsum/carry before next iter
    }
    if (t == 0) csr[CSR_PTR + N_NODES] = running;
}

// Merged: blocks 0..1249 = node_pre (linear_up fp16-packed + species skip),
//         blocks 1250..2499 = bucket (CSR fill + Y1/sender precompute).
__global__ __launch_bounds__(256) void k_pre_bucket(
    const float* __restrict__ ns, const float* __restrict__ nv,
    const int* __restrict__ counts, const unsigned short* __restrict__ wf,
    const float* __restrict__ vectors, const int* __restrict__ senders,
    const int* __restrict__ receivers, int* __restrict__ csr,
    float4* __restrict__ erec, float* __restrict__ ws) {
    __shared__ uint2 eup_t[16][64];   // 8 KB (node_pre blocks only)
    int tid = threadIdx.x;
    if (blockIdx.x >= 1250) {
        // ---- bucket ----
        int e = (blockIdx.x - 1250) * 256 + tid;   // 1250*256 == E exactly
        int pos = atomicAdd(&csr[CSR_CNT + receivers[e]], 1);
        float v0 = vectors[e * 3 + 0], v1 = vectors[e * 3 + 1], v2 = vectors[e * 3 + 2];
        float s = SQRT3C * rsqrtf(v0 * v0 + v1 * v1 + v2 * v2);
        csr[CSR_SEID + pos] = e;
        float4 r;
        r.x = v0 * s; r.y = v1 * s; r.z = v2 * s; r.w = __int_as_float(senders[e]);
        erec[pos] = r;
        return;
    }
    // ---- node_pre ----
    int w = tid >> 6, lane = tid & 63;
    int q = lane >> 4, l15 = lane & 15;
    int nw = blockIdx.x * 16;
    int sid = species_of(nw, counts);
    const f32x4 z4 = {0.f, 0.f, 0.f, 0.f};

    bhalf8 Ah[2], Al[2];
    if (w == 0) {
#pragma unroll
        for (int s = 0; s < 2; s++) {
            const float* rp = ns + (size_t)(nw + l15) * 64 + s * 32 + q * 8;
            float4 a = *(const float4*)rp, b = *(const float4*)(rp + 4);
            float x[8] = {a.x, a.y, a.z, a.w, b.x, b.y, b.z, b.w};
#pragma unroll
            for (int j = 0; j < 8; j++) { short h, l; split_f32(x[j], h, l); Ah[s][j] = h; Al[s][j] = l; }
        }
    } else {
        int i = w - 1;
#pragma unroll
        for (int s = 0; s < 2; s++) {
            const float* rp = nv + (size_t)(nw + l15) * 192 + i;
#pragma unroll
            for (int j = 0; j < 8; j++) {
                float x = rp[(s * 32 + q * 8 + j) * 3];
                short h, l; split_f32(x, h, l); Ah[s][j] = h; Al[s][j] = l;
            }
        }
    }

    const bhalf8* wfv = (const bhalf8*)wf;
    float* sks = ws + OFF_SKS;
    float* skv = ws + OFF_SKV;

    // m=0: linear_up -> fp16 packed LDS tile
    {
        int mat = (w == 0) ? 0 : 1;
#pragma unroll
        for (int t = 0; t < 4; t++) {
            f32x4 acc = z4;
#pragma unroll
            for (int s = 0; s < 2; s++) {
                bhalf8 bh = wfv[(size_t)(mat * 16 + 0 + s * 4 + t) * 64 + lane];
                bhalf8 bl = wfv[(size_t)(mat * 16 + 8 + s * 4 + t) * 64 + lane];
                acc = __builtin_amdgcn_mfma_f32_16x16x32_bf16(Ah[s], bh, acc, 0, 0, 0);
                acc = __builtin_amdgcn_mfma_f32_16x16x32_bf16(Al[s], bh, acc, 0, 0, 0);
                acc = __builtin_amdgcn_mfma_f32_16x16x32_bf16(Ah[s], bl, acc, 0, 0, 0);
            }
#pragma unroll
            for (int r = 0; r < 4; r++) {
                unsigned short us = __half_as_ushort(__float2half_rn(acc[r] * INV_F));
                ((unsigned short*)&eup_t[q * 4 + r][t * 16 + l15])[w] = us;
            }
        }
    }
    // m=1: species skip -> fp32 tables
    {
        int mat = (w == 0) ? 2 + sid : 12 + sid;
        float* dst = (w == 0) ? sks : skv;
        int stride = (w == 0) ? 64 : 192;
        int off = (w == 0) ? 0 : (w - 1) * 64;
#pragma unroll
        for (int t = 0; t < 4; t++) {
            f32x4 acc = z4;
#pragma unroll
            for (int s = 0; s < 2; s++) {
                bhalf8 bh = wfv[(size_t)(mat * 16 + 0 + s * 4 + t) * 64 + lane];
                bhalf8 bl = wfv[(size_t)(mat * 16 + 8 + s * 4 + t) * 64 + lane];
                acc = __builtin_amdgcn_mfma_f32_16x16x32_bf16(Ah[s], bh, acc, 0, 0, 0);
                acc = __builtin_amdgcn_mfma_f32_16x16x32_bf16(Al[s], bh, acc, 0, 0, 0);
                acc = __builtin_amdgcn_mfma_f32_16x16x32_bf16(Ah[s], bl, acc, 0, 0, 0);
            }
#pragma unroll
            for (int r = 0; r < 4; r++)
                dst[(size_t)(nw + q * 4 + r) * stride + off + t * 16 + l15] = acc[r] * INV_F;
        }
    }
    __syncthreads();
    uint2* eup = (uint2*)(ws + OFF_EUP);
    for (int k = tid; k < 1024; k += 256) {
        int n = k >> 6, f = k & 63;
        eup[(size_t)(nw + n) * 64 + f] = eup_t[n][f];
    }
}

// Cross-lane frag builder (see R9 derivation).
template<int S>
__device__ __forceinline__ bhalf8 xfrag(const unsigned* pkA, const unsigned* pkB,
                                        int q, int l15) {
    int L0 = ((q & 1) << 5) + l15;
    int L1 = L0 + 16;
    bool hi = (q >> 1) != 0;
    unsigned a0 = (unsigned)__shfl((int)pkA[2 * S], L0, 64);
    unsigned a1 = (unsigned)__shfl((int)pkA[2 * S + 1], L0, 64);
    unsigned b0 = (unsigned)__shfl((int)pkB[2 * S], L0, 64);
    unsigned b1 = (unsigned)__shfl((int)pkB[2 * S + 1], L0, 64);
    unsigned c0 = (unsigned)__shfl((int)pkA[2 * S], L1, 64);
    unsigned c1 = (unsigned)__shfl((int)pkA[2 * S + 1], L1, 64);
    unsigned e0 = (unsigned)__shfl((int)pkB[2 * S], L1, 64);
    unsigned e1 = (unsigned)__shfl((int)pkB[2 * S + 1], L1, 64);
    return mk8(hi ? a1 : a0, hi ? b1 : b0, hi ? c1 : c0, hi ? e1 : e0);
}

// K2a: radial MLP via bf16 MFMA + FULL message computation. After layer-4,
// each lane holds (el, f, w0..w3); it gathers eup[sender] / erec (latency
// hidden behind MFMA chains) and stores the finished TP message
// (ms, mv0, mv1, mv2) as fp16x4. The consumer becomes pure-stream.
__global__ __launch_bounds__(256) void k_mlp(
    const float* __restrict__ radial, const unsigned short* __restrict__ frags,
    const int* __restrict__ csr, const float4* __restrict__ erec,
    unsigned short* __restrict__ wbuf, const float* __restrict__ ws) {
    __shared__ unsigned short r4lds[16384];   // 32 KB
    int tid = threadIdx.x;
    int lane = tid & 63, w = tid >> 6, quad = lane >> 4, l15 = lane & 15;

    const uint4* r4g = (const uint4*)(frags + 20 * 64 * 8);
    uint4* r4l = (uint4*)r4lds;
    for (int i = tid; i < 2048; i += 256) r4l[i] = r4g[i];
    const bhalf8* fr = (const bhalf8*)frags;
    bhalf8 r1f[4], r2f[2][4], r3f[2][4];
#pragma unroll
    for (int t = 0; t < 4; t++) r1f[t] = fr[t * 64 + lane];
#pragma unroll
    for (int s = 0; s < 2; s++)
#pragma unroll
        for (int t = 0; t < 4; t++) {
            r2f[s][t] = fr[(4 + s * 4 + t) * 64 + lane];
            r3f[s][t] = fr[(12 + s * 4 + t) * 64 + lane];
        }
    __syncthreads();

    const f32x4 z4 = {0.f, 0.f, 0.f, 0.f};
    const bhalf8* r4f = (const bhalf8*)r4lds;
    const uint2* eup = (const uint2*)(ws + OFF_EUP);

    int el0 = (blockIdx.x * 4 + w) * 16;   // global sorted slot base

    bhalf8 af = {0, 0, 0, 0, 0, 0, 0, 0};
    if (quad == 0) {
        int eid = csr[CSR_SEID + el0 + l15];  // global edge id
        const float* rp = radial + (size_t)eid * 8;
        float4 ra = *(const float4*)rp;
        float4 rb = *(const float4*)(rp + 4);
        af[0] = (short)f2bf(ra.x); af[1] = (short)f2bf(ra.y);
        af[2] = (short)f2bf(ra.z); af[3] = (short)f2bf(ra.w);
        af[4] = (short)f2bf(rb.x); af[5] = (short)f2bf(rb.y);
        af[6] = (short)f2bf(rb.z); af[7] = (short)f2bf(rb.w);
    }
    unsigned pkA[4], pkB[4];
    {
        f32x4 acc[4];
#pragma unroll
        for (int t = 0; t < 4; t++)
            acc[t] = __builtin_amdgcn_mfma_f32_16x16x32_bf16(r1f[t], af, z4, 0, 0, 0);
#pragma unroll
        for (int t = 0; t < 4; t++) {
            pkA[t] = pack_bf2(silu_f(acc[t][0]), silu_f(acc[t][1]));
            pkB[t] = pack_bf2(silu_f(acc[t][2]), silu_f(acc[t][3]));
        }
    }
#pragma unroll
    for (int layer = 0; layer < 2; layer++) {
        bhalf8 b0 = xfrag<0>(pkA, pkB, quad, l15);
        bhalf8 b1 = xfrag<1>(pkA, pkB, quad, l15);
        f32x4 acc[4];
#pragma unroll
        for (int t = 0; t < 4; t++) {
            bhalf8 w0 = layer == 0 ? r2f[0][t] : r3f[0][t];
            bhalf8 w1 = layer == 0 ? r2f[1][t] : r3f[1][t];
            acc[t] = __builtin_amdgcn_mfma_f32_16x16x32_bf16(
                w1, b1, __builtin_amdgcn_mfma_f32_16x16x32_bf16(w0, b0, z4, 0, 0, 0), 0, 0, 0);
        }
#pragma unroll
        for (int t = 0; t < 4; t++) {
            pkA[t] = pack_bf2(silu_f(acc[t][0]), silu_f(acc[t][1]));
            pkB[t] = pack_bf2(silu_f(acc[t][2]), silu_f(acc[t][3]));
        }
    }
    {
        bhalf8 a0 = xfrag<0>(pkA, pkB, quad, l15);
        bhalf8 a1 = xfrag<1>(pkA, pkB, quad, l15);
        // per-r edge records (same across the 16 l15 lanes -> broadcast loads)
        float4 rc[4];
        int sx[4];
#pragma unroll
        for (int r = 0; r < 4; r++) {
            rc[r] = erec[el0 + quad * 4 + r];
            sx[r] = __float_as_int(rc[r].w);
        }
#pragma unroll
        for (int t4 = 0; t4 < 4; t4++) {
            int f = t4 * 16 + l15;
            // issue gathers first; MFMA chains below cover their latency
            uint2 ev[4];
#pragma unroll
            for (int r = 0; r < 4; r++)
                ev[r] = eup[(size_t)sx[r] * 64 + f];
            f32x4 p0 = __builtin_amdgcn_mfma_f32_16x16x32_bf16(
                a1, r4f[(16 + t4) * 64 + lane],
                __builtin_amdgcn_mfma_f32_16x16x32_bf16(a0, r4f[t4 * 64 + lane], z4, 0, 0, 0), 0, 0, 0);
            f32x4 p1 = __builtin_amdgcn_mfma_f32_16x16x32_bf16(
                a1, r4f[(20 + t4) * 64 + lane],
                __builtin_amdgcn_mfma_f32_16x16x32_bf16(a0, r4f[(4 + t4) * 64 + lane], z4, 0, 0, 0), 0, 0, 0);
            f32x4 p2 = __builtin_amdgcn_mfma_f32_16x16x32_bf16(
                a1, r4f[(24 + t4) * 64 + lane],
                __builtin_amdgcn_mfma_f32_16x16x32_bf16(a0, r4f[(8 + t4) * 64 + lane], z4, 0, 0, 0), 0, 0, 0);
            f32x4 p3 = __builtin_amdgcn_mfma_f32_16x16x32_bf16(
                a1, r4f[(28 + t4) * 64 + lane],
                __builtin_amdgcn_mfma_f32_16x16x32_bf16(a0, r4f[(12 + t4) * 64 + lane], z4, 0, 0, 0), 0, 0, 0);
#pragma unroll
            for (int r = 0; r < 4; r++) {
                float es = half_lo(ev[r].x), e0 = half_hi(ev[r].x);
                float e1 = half_lo(ev[r].y), e2 = half_hi(ev[r].y);
                float dot = e0 * rc[r].x + e1 * rc[r].y + e2 * rc[r].z;
                float ms = p0[r] * es + p1[r] * dot * INV_SQRT3C;
                float t3 = p3[r] * es * INV_SQRT3C;
                float m0 = p2[r] * e0 + t3 * rc[r].x;
                float m1 = p2[r] * e1 + t3 * rc[r].y;
                float m2 = p2[r] * e2 + t3 * rc[r].z;
                int el = el0 + quad * 4 + r;
                uint2 pk;
                pk.x = pack_h2(ms, m0);
                pk.y = pack_h2(m1, m2);
                ((uint2*)wbuf)[(size_t)el * 64 + f] = pk;
            }
        }
    }
}

// K2b: pure-stream message reduction per node. No random reads at all.
__global__ __launch_bounds__(256) void k_tp_gather(
    const unsigned short* __restrict__ wbuf, const int* __restrict__ csr,
    float* __restrict__ ws) {
    int tid = threadIdx.x, w = tid >> 6, f = tid & 63;
    int n = blockIdx.x * 4 + w;
    float* hs_mid = ws + OFF_HSMID;
    float* hv_mid = ws + OFF_HVMID;
    int beg = csr[CSR_PTR + n], end = csr[CSR_PTR + n + 1];
    float ams = 0.f, am0 = 0.f, am1 = 0.f, am2 = 0.f;
    if (beg < end) {
        int last = end - 1;
        uint2 mA = ((const uint2*)wbuf)[(size_t)beg * 64 + f];
        for (int i = beg; i < end; i++) {
            int j1 = (i + 1 < end) ? i + 1 : last;
            uint2 mB = ((const uint2*)wbuf)[(size_t)j1 * 64 + f];
            ams += half_lo(mA.x); am0 += half_hi(mA.x);
            am1 += half_lo(mA.y); am2 += half_hi(mA.y);
            mA = mB;
        }
    }
    hs_mid[n * 64 + f] = ams * EPSC;
    hv_mid[n * 192 + f] = am0 * EPSC;
    hv_mid[n * 192 + 64 + f] = am1 * EPSC;
    hv_mid[n * 192 + 128 + f] = am2 * EPSC;
}

// K3: linear_down + contraction + linear_sc + skip + readout via split-bf16 MFMA.
__global__ __launch_bounds__(256) void k_node_post(
    const int* __restrict__ counts, const unsigned short* __restrict__ wf,
    const float* __restrict__ Wr, float* __restrict__ ws, float* __restrict__ out) {
    __shared__ float T[4][16][68];
    int tid = threadIdx.x, w = tid >> 6, lane = tid & 63;
    int q = lane >> 4, l15 = lane & 15;
    int nw = blockIdx.x * 16;
    int sid = species_of(nw, counts);
    const f32x4 z4 = {0.f, 0.f, 0.f, 0.f};
    const bhalf8* wfv = (const bhalf8*)wf;
    const float* hs_mid = ws + OFF_HSMID;
    const float* hv_mid = ws + OFF_HVMID;
    const float* sks = ws + OFF_SKS;
    const float* skv = ws + OFF_SKV;
    const float* wscp = ws + OFF_WSCP;

    // Phase 1: linear_down (EPS already applied in k_tp_gather's store)
    {
        const float* src = (w == 0) ? hs_mid + (size_t)nw * 64
                                    : hv_mid + (size_t)nw * 192 + (w - 1) * 64;
        int rstride = (w == 0) ? 64 : 192;
        bhalf8 Ah[2], Al[2];
#pragma unroll
        for (int s = 0; s < 2; s++) {
            const float* rp = src + (size_t)l15 * rstride + s * 32 + q * 8;
            float4 a = *(const float4*)rp, b = *(const float4*)(rp + 4);
            float x[8] = {a.x, a.y, a.z, a.w, b.x, b.y, b.z, b.w};
#pragma unroll
            for (int j = 0; j < 8; j++) { short h, l; split_f32(x[j], h, l); Ah[s][j] = h; Al[s][j] = l; }
        }
        int mat = (w == 0) ? 22 : 23;
#pragma unroll
        for (int t = 0; t < 4; t++) {
            f32x4 acc = z4;
#pragma unroll
            for (int s = 0; s < 2; s++) {
                bhalf8 bh = wfv[(size_t)(mat * 16 + 0 + s * 4 + t) * 64 + lane];
                bhalf8 bl = wfv[(size_t)(mat * 16 + 8 + s * 4 + t) * 64 + lane];
                acc = __builtin_amdgcn_mfma_f32_16x16x32_bf16(Ah[s], bh, acc, 0, 0, 0);
                acc = __builtin_amdgcn_mfma_f32_16x16x32_bf16(Al[s], bh, acc, 0, 0, 0);
                acc = __builtin_amdgcn_mfma_f32_16x16x32_bf16(Ah[s], bl, acc, 0, 0, 0);
            }
#pragma unroll
            for (int r = 0; r < 4; r++)
                T[w][q * 4 + r][t * 16 + l15] = acc[r] * INV_F;
        }
    }
    __syncthreads();

    // Phase 2: symmetric contraction
    {
        int col = tid & 63, rg = tid >> 6;
        float wv[9];
#pragma unroll
        for (int b = 0; b < 9; b++) wv[b] = wscp[sid * 576 + b * 64 + col];
#pragma unroll
        for (int rr = 0; rr < 4; rr++) {
            int row = rg * 4 + rr;
            float hs = T[0][row][col];
            float h0 = T[1][row][col], h1 = T[2][row][col], h2 = T[3][row][col];
            float vv = h0 * h0 + h1 * h1 + h2 * h2;
            float cs = wv[0] * hs + wv[1] * hs * hs + wv[2] * vv
                     + wv[3] * hs * hs * hs + wv[4] * hs * vv;
            float fv = wv[5] + wv[6] * hs + wv[7] * hs * hs + wv[8] * vv;
            T[0][row][col] = cs;
            T[1][row][col] = h0 * fv;
            T[2][row][col] = h1 * fv;
            T[3][row][col] = h2 * fv;
        }
    }
    __syncthreads();

    // Phase 3: linear_sc + skip + store (+ readout on w0)
    {
        bhalf8 Ah[2], Al[2];
#pragma unroll
        for (int s = 0; s < 2; s++) {
            const float* rp = &T[w][l15][s * 32 + q * 8];
            float4 a = *(const float4*)rp, b = *(const float4*)(rp + 4);
            float x[8] = {a.x, a.y, a.z, a.w, b.x, b.y, b.z, b.w};
#pragma unroll
            for (int j = 0; j < 8; j++) { short h, l; split_f32(x[j], h, l); Ah[s][j] = h; Al[s][j] = l; }
        }
        int mat = (w == 0) ? 24 : 25;
        float* d_hs = out + N_NODES;
        float* d_hv = out + N_NODES + N_NODES * 64;
        float p[4] = {0.f, 0.f, 0.f, 0.f};
#pragma unroll
        for (int t = 0; t < 4; t++) {
            f32x4 acc = z4;
#pragma unroll
            for (int s = 0; s < 2; s++) {
                bhalf8 bh = wfv[(size_t)(mat * 16 + 0 + s * 4 + t) * 64 + lane];
                bhalf8 bl = wfv[(size_t)(mat * 16 + 8 + s * 4 + t) * 64 + lane];
                acc = __builtin_amdgcn_mfma_f32_16x16x32_bf16(Ah[s], bh, acc, 0, 0, 0);
                acc = __builtin_amdgcn_mfma_f32_16x16x32_bf16(Al[s], bh, acc, 0, 0, 0);
                acc = __builtin_amdgcn_mfma_f32_16x16x32_bf16(Ah[s], bl, acc, 0, 0, 0);
            }
            int col = t * 16 + l15;
            if (w == 0) {
                float wr = Wr[col];
#pragma unroll
                for (int r = 0; r < 4; r++) {
                    int gn = nw + q * 4 + r;
                    float v = acc[r] * INV_F + sks[(size_t)gn * 64 + col];
                    d_hs[(size_t)gn * 64 + col] = v;
                    p[r] += v * wr;
                }
            } else {
                int i = w - 1;
#pragma unroll
                for (int r = 0; r < 4; r++) {
                    int gn = nw + q * 4 + r;
                    float v = acc[r] * INV_F + skv[(size_t)gn * 192 + i * 64 + col];
                    d_hv[(size_t)gn * 192 + col * 3 + i] = v;
                }
            }
        }
        if (w == 0) {
#pragma unroll
            for (int r = 0; r < 4; r++) {
#pragma unroll
                for (int off = 1; off < 16; off <<= 1) p[r] += __shfl_xor(p[r], off, 64);
                if (l15 == 0) out[nw + q * 4 + r] = p[r] * INV_F;
            }
        }
    }
}

extern "C" void kernel_launch(void* const* d_in, const int* in_sizes, int n_in,
                              void* d_out, int out_size, void* d_ws, size_t ws_size,
                              hipStream_t stream) {
    const float* vectors   = (const float*)d_in[0];
    const float* node_s    = (const float*)d_in[1];
    const float* node_v    = (const float*)d_in[2];
    const float* radial    = (const float*)d_in[3];
    const int*   senders   = (const int*)d_in[4];
    const int*   receivers = (const int*)d_in[5];
    const int*   counts    = (const int*)d_in[6];
    const float* Wup0 = (const float*)d_in[7];
    const float* Wup1 = (const float*)d_in[8];
    const float* R1   = (const float*)d_in[9];
    const float* R2   = (const float*)d_in[10];
    const float* R3   = (const float*)d_in[11];
    const float* R4   = (const float*)d_in[12];
    const float* Wd0  = (const float*)d_in[13];
    const float* Wd1  = (const float*)d_in[14];
    const float* Ws0  = (const float*)d_in[15];
    const float* Ws1  = (const float*)d_in[16];
    const float* Wsc  = (const float*)d_in[17];
    const float* Proj = (const float*)d_in[18];
    const float* Wl0  = (const float*)d_in[19];
    const float* Wl1  = (const float*)d_in[20];
    const float* Wr   = (const float*)d_in[21];
    float* ws  = (float*)d_ws;
    float* out = (float*)d_out;
    unsigned short* frags = (unsigned short*)(ws + OFF_FRAGS);
    unsigned short* wbuf  = (unsigned short*)(ws + OFF_WBUF);
    float4* erec = (float4*)(ws + OFF_CSR);
    int* csr = (int*)(ws + OFF_CSR + (size_t)E_EDGES * 4);
    unsigned short* wf = (unsigned short*)(ws + OFF_WF);

    hipMemsetAsync(csr + CSR_CNT, 0, N_NODES * sizeof(int), stream);
    k_setup<<<(SU_HIST + 255) / 256, 256, 0, stream>>>(
        Wsc, Proj, ws + OFF_WSCP, R1, R2, R3, R4, frags,
        Wup0, Wup1, Ws0, Ws1, Wd0, Wd1, Wl0, Wl1, wf, receivers, csr);
    k_scan_all<<<1, 1024, 0, stream>>>(csr);
    k_pre_bucket<<<2500, 256, 0, stream>>>(node_s, node_v, counts, wf,
                                           vectors, senders, receivers, csr, erec, ws);
    k_mlp<<<5000, 256, 0, stream>>>(radial, frags, csr, erec, wbuf, ws);
    k_tp_gather<<<N_NODES / 4, 256, 0, stream>>>(wbuf, csr, ws);
    k_node_post<<<N_NODES / 16, 256, 0, stream>>>(counts, wf, Wr, ws, out);
}